// Round 3
// baseline (1971.814 us; speedup 1.0000x reference)
//
#include <hip/hip_runtime.h>
#include <hip/hip_bf16.h>
#include <math.h>

#define NN 100000      // nodes per type
#define EE 200000      // edges per relation
#define HH 4
#define DD 128
#define HD 512         // H*D
#define KIN 256        // input feature dim
#define LN_EPS 1e-5f
#define SLOPE 0.2f

// ---------------- tiled fp32 GEMM: C[M,N] = X[M,256] @ W[:, c0:c0+N]
// W has row stride ldW; output C is M x N contiguous.
__global__ __launch_bounds__(256) void gemm_f32(
    const float* __restrict__ X, const float* __restrict__ W, int ldW, int c0,
    float* __restrict__ C, int M, int N) {
  const int K = KIN;
  __shared__ float Xs[32][68];
  __shared__ float Ws[32][68];
  int tid = threadIdx.x;
  int row0 = blockIdx.x * 64;
  int col0 = blockIdx.y * 64;
  int tx = tid & 15, ty = tid >> 4;
  float acc[4][4];
#pragma unroll
  for (int i = 0; i < 4; i++)
#pragma unroll
    for (int j = 0; j < 4; j++) acc[i][j] = 0.f;

  int lr = tid >> 2;        // 0..63 : X row within tile
  int lk = (tid & 3) * 8;   // k offset (8 consecutive)
  int wk = tid >> 3;        // 0..31 : W k within tile
  int wc = (tid & 7) * 8;   // col offset (8 consecutive)

  for (int k0 = 0; k0 < K; k0 += 32) {
    float4 xa, xb;
    if (row0 + lr < M) {
      const float* xp = X + (size_t)(row0 + lr) * K + k0 + lk;
      xa = *(const float4*)xp;
      xb = *(const float4*)(xp + 4);
    } else {
      xa = make_float4(0.f, 0.f, 0.f, 0.f);
      xb = xa;
    }
    const float* wp = W + (size_t)(k0 + wk) * ldW + c0 + col0 + wc;
    float4 wa = *(const float4*)wp;
    float4 wb = *(const float4*)(wp + 4);
    __syncthreads();
    Xs[lk + 0][lr] = xa.x; Xs[lk + 1][lr] = xa.y; Xs[lk + 2][lr] = xa.z; Xs[lk + 3][lr] = xa.w;
    Xs[lk + 4][lr] = xb.x; Xs[lk + 5][lr] = xb.y; Xs[lk + 6][lr] = xb.z; Xs[lk + 7][lr] = xb.w;
    *(float4*)&Ws[wk][wc] = wa;
    *(float4*)&Ws[wk][wc + 4] = wb;
    __syncthreads();
#pragma unroll
    for (int kk = 0; kk < 32; kk++) {
      float4 av = *(const float4*)&Xs[kk][ty << 2];
      float4 bv = *(const float4*)&Ws[kk][tx << 2];
      float a[4] = {av.x, av.y, av.z, av.w};
      float b[4] = {bv.x, bv.y, bv.z, bv.w};
#pragma unroll
      for (int i = 0; i < 4; i++)
#pragma unroll
        for (int j = 0; j < 4; j++) acc[i][j] = fmaf(a[i], b[j], acc[i][j]);
    }
  }
#pragma unroll
  for (int i = 0; i < 4; i++) {
    int r = row0 + (ty << 2) + i;
    if (r < M) {
      float4 v = make_float4(acc[i][0], acc[i][1], acc[i][2], acc[i][3]);
      *(float4*)(C + (size_t)r * N + col0 + (tx << 2)) = v;
    }
  }
}

// ---------------- build C[k,h] = sum_d W[k, h*128+d] * a[h*128+d]  (4 matrices)
__global__ __launch_bounds__(256) void make_c(
    const float* __restrict__ W1, const float* __restrict__ al1, const float* __restrict__ ar1,
    const float* __restrict__ W2, const float* __restrict__ al2, const float* __restrict__ ar2,
    float* __restrict__ Cout) {
  int which = blockIdx.y;  // 0:W1*al1 1:W1*ar1 2:W2*al2 3:W2*ar2
  const float* W = (which < 2) ? W1 : W2;
  const float* a = (which == 0) ? al1 : (which == 1) ? ar1 : (which == 2) ? al2 : ar2;
  int k = threadIdx.x;  // 0..255
  float* C = Cout + (size_t)which * 1024;
#pragma unroll
  for (int h = 0; h < HH; h++) {
    float s = 0.f;
    for (int d = 0; d < DD; d++) s = fmaf(W[(size_t)k * HD + h * DD + d], a[h * DD + d], s);
    C[k * HH + h] = s;
  }
}

// ---------------- skinny: out[n,h] = sum_k X[n,k] * C[k,h]  (one wave per row)
__global__ __launch_bounds__(256) void skinny4(
    const float* __restrict__ X, const float* __restrict__ C,
    float* __restrict__ out, int M) {
  __shared__ float Cs[KIN * HH];
  int tid = threadIdx.x;
  for (int i = tid; i < KIN * HH; i += 256) Cs[i] = C[i];
  __syncthreads();
  int wave = tid >> 6, lane = tid & 63;
  int n = blockIdx.x * 4 + wave;
  if (n >= M) return;
  float4 xv = ((const float4*)(X + (size_t)n * KIN))[lane];
  float xs[4] = {xv.x, xv.y, xv.z, xv.w};
  float acc[HH] = {0.f, 0.f, 0.f, 0.f};
#pragma unroll
  for (int j = 0; j < 4; j++) {
    int k = lane * 4 + j;
#pragma unroll
    for (int h = 0; h < HH; h++) acc[h] = fmaf(xs[j], Cs[k * HH + h], acc[h]);
  }
#pragma unroll
  for (int off = 32; off >= 1; off >>= 1)
#pragma unroll
    for (int h = 0; h < HH; h++) acc[h] += __shfl_xor(acc[h], off);
  if (lane == 0) {
#pragma unroll
    for (int h = 0; h < HH; h++) out[(size_t)n * HH + h] = acc[h];
  }
}

// ---------------- edge pass A: w = exp(leaky(el[src]+er[dst])); s[dst] += w
__global__ __launch_bounds__(256) void edge_a(
    const int* __restrict__ src, const int* __restrict__ dst,
    const float* __restrict__ el, const float* __restrict__ er,
    float* __restrict__ wbuf, float* __restrict__ s, int E) {
  int e = blockIdx.x * 256 + threadIdx.x;
  if (e >= E) return;
  int si = src[e], di = dst[e];
  float4 l = *(const float4*)(el + (size_t)si * HH);
  float4 r = *(const float4*)(er + (size_t)di * HH);
  float lv[4] = {l.x, l.y, l.z, l.w};
  float rv[4] = {r.x, r.y, r.z, r.w};
#pragma unroll
  for (int h = 0; h < HH; h++) {
    float v = lv[h] + rv[h];
    v = v > 0.f ? v : SLOPE * v;
    float w = __expf(v);
    wbuf[(size_t)e * HH + h] = w;
    atomicAdd(&s[(size_t)di * HH + h], w);
  }
}

// ---------------- edge pass B (head pair hp): one wave per edge
// c[dst, d] += 0.25*(a_{2hp} * fs2[src, d] + a_{2hp+1} * fs2[src, 128+d])
__global__ __launch_bounds__(256) void edge_hp(
    const int* __restrict__ src, const int* __restrict__ dst,
    const float* __restrict__ wbuf, const float* __restrict__ s,
    const float* __restrict__ fs2, float* __restrict__ c, int E, int hp) {
  int gid = blockIdx.x * 256 + threadIdx.x;
  int e = gid >> 6, lane = gid & 63;
  if (e >= E) return;
  int si = src[e], di = dst[e];
  int h0 = hp * 2;
  float a0 = 0.25f * wbuf[(size_t)e * HH + h0]     / s[(size_t)di * HH + h0];
  float a1 = 0.25f * wbuf[(size_t)e * HH + h0 + 1] / s[(size_t)di * HH + h0 + 1];
  const float2* f0 = (const float2*)(fs2 + (size_t)si * 256);
  float2 v0 = f0[lane];        // head h0,   d = 2*lane, 2*lane+1
  float2 v1 = f0[64 + lane];   // head h0+1, same d
  float* cp = c + (size_t)di * DD + lane * 2;
  atomicAdd(cp,     a0 * v0.x + a1 * v1.x);
  atomicAdd(cp + 1, a0 * v0.y + a1 * v1.y);
}

// ---------------- tail: c (in out slot) + pb + mean(b) -> LN -> GELU, in place
__global__ __launch_bounds__(256) void tail2(
    const float* __restrict__ b, const float* __restrict__ pb,
    const float* __restrict__ g, const float* __restrict__ be,
    float* __restrict__ out, int M) {
  int wave = threadIdx.x >> 6, lane = threadIdx.x & 63;
  int n = blockIdx.x * 4 + wave;
  if (n >= M) return;
  float2 cv = ((const float2*)(out + (size_t)n * DD))[lane];
  const float2* bb = (const float2*)b;
  float bx = 0.f, by = 0.f;
#pragma unroll
  for (int h = 0; h < HH; h++) {
    float2 bv = bb[h * 64 + lane];
    bx += bv.x; by += bv.y;
  }
  float2 pbv = ((const float2*)pb)[lane];
  float cx = cv.x + 0.25f * bx + pbv.x;
  float cy = cv.y + 0.25f * by + pbv.y;
  // LayerNorm over 128
  float ssum = cx + cy;
#pragma unroll
  for (int off = 32; off >= 1; off >>= 1) ssum += __shfl_xor(ssum, off);
  float mu = ssum * (1.f / 128.f);
  float dx = cx - mu, dy = cy - mu;
  float v2 = dx * dx + dy * dy;
#pragma unroll
  for (int off = 32; off >= 1; off >>= 1) v2 += __shfl_xor(v2, off);
  float inv = rsqrtf(v2 * (1.f / 128.f) + LN_EPS);
  float2 gv = ((const float2*)g)[lane];
  float2 bev = ((const float2*)be)[lane];
  float yx = dx * inv * gv.x + bev.x;
  float yy = dy * inv * gv.y + bev.y;
  float ox = 0.5f * yx * (1.f + erff(yx * 0.70710678118f));
  float oy = 0.5f * yy * (1.f + erff(yy * 0.70710678118f));
  ((float2*)(out + (size_t)n * DD))[lane] = make_float2(ox, oy);
}

extern "C" void kernel_launch(void* const* d_in, const int* in_sizes, int n_in,
                              void* d_out, int out_size, void* d_ws, size_t ws_size,
                              hipStream_t stream) {
  const float* feat_host = (const float*)d_in[0];
  const float* feat_flow = (const float*)d_in[1];
  const float* W1  = (const float*)d_in[2];
  const float* al1 = (const float*)d_in[3];
  const float* ar1 = (const float*)d_in[4];
  const float* b1  = (const float*)d_in[5];
  const float* W2  = (const float*)d_in[6];
  const float* al2 = (const float*)d_in[7];
  const float* ar2 = (const float*)d_in[8];
  const float* b2  = (const float*)d_in[9];
  const float* pWh = (const float*)d_in[10];
  const float* pbh = (const float*)d_in[11];
  const float* pWf = (const float*)d_in[12];
  const float* pbf = (const float*)d_in[13];
  const float* gh  = (const float*)d_in[14];
  const float* beh = (const float*)d_in[15];
  const float* gf  = (const float*)d_in[16];
  const float* bef = (const float*)d_in[17];
  const int* e1s = (const int*)d_in[18];
  const int* e1d = (const int*)d_in[19];
  const int* e2s = (const int*)d_in[20];
  const int* e2d = (const int*)d_in[21];

  float* out = (float*)d_out;
  float* host_out = out;                       // [NN, 128]
  float* flow_out = out + (size_t)NN * DD;     // [NN, 128]

  // workspace: ~114 MB total
  float* ws = (float*)d_ws;
  size_t off = 0;
  float* fsbuf = ws + off; off += (size_t)NN * 256;  // 25.6M floats (head-pair fs)
  float* el1b  = ws + off; off += (size_t)NN * HH;
  float* er1b  = ws + off; off += (size_t)NN * HH;
  float* el2b  = ws + off; off += (size_t)NN * HH;
  float* er2b  = ws + off; off += (size_t)NN * HH;
  float* sbuf  = ws + off; off += (size_t)NN * HH;
  float* wbuf  = ws + off; off += (size_t)EE * HH;
  float* Cbuf  = ws + off; off += 4096;

  dim3 blk(256);
  int gemm_gx = (NN + 63) / 64;
  int sk_g = (NN + 3) / 4;
  int eA_g = (EE + 255) / 256;
  int eB_g = (EE * 64 + 255) / 256;

  // attention-vector collapse matrices + el/er for both relations
  make_c<<<dim3(1, 4), blk, 0, stream>>>(W1, al1, ar1, W2, al2, ar2, Cbuf);
  skinny4<<<sk_g, blk, 0, stream>>>(feat_host, Cbuf + 0,    el1b, NN);  // el1 (src=host)
  skinny4<<<sk_g, blk, 0, stream>>>(feat_flow, Cbuf + 1024, er1b, NN);  // er1 (dst=flow)
  skinny4<<<sk_g, blk, 0, stream>>>(feat_flow, Cbuf + 2048, el2b, NN);  // el2 (src=flow)
  skinny4<<<sk_g, blk, 0, stream>>>(feat_host, Cbuf + 3072, er2b, NN);  // er2 (dst=host)

  // ---- relation 1: host -> flow  (dst = flow, output = flow_out)
  hipMemsetAsync(sbuf, 0, (size_t)NN * HH * sizeof(float), stream);
  edge_a<<<eA_g, blk, 0, stream>>>(e1s, e1d, el1b, er1b, wbuf, sbuf, EE);
  // residual projection straight into the output slot (fully overwrites)
  gemm_f32<<<dim3(gemm_gx, DD / 64), blk, 0, stream>>>(feat_flow, pWf, DD, 0, flow_out, NN, DD);
  // head pair 0
  gemm_f32<<<dim3(gemm_gx, 4), blk, 0, stream>>>(feat_host, W1, HD, 0, fsbuf, NN, 256);
  edge_hp<<<eB_g, blk, 0, stream>>>(e1s, e1d, wbuf, sbuf, fsbuf, flow_out, EE, 0);
  // head pair 1
  gemm_f32<<<dim3(gemm_gx, 4), blk, 0, stream>>>(feat_host, W1, HD, 256, fsbuf, NN, 256);
  edge_hp<<<eB_g, blk, 0, stream>>>(e1s, e1d, wbuf, sbuf, fsbuf, flow_out, EE, 1);
  tail2<<<sk_g, blk, 0, stream>>>(b1, pbf, gf, bef, flow_out, NN);

  // ---- relation 2: flow -> host  (dst = host, output = host_out)
  hipMemsetAsync(sbuf, 0, (size_t)NN * HH * sizeof(float), stream);
  edge_a<<<eA_g, blk, 0, stream>>>(e2s, e2d, el2b, er2b, wbuf, sbuf, EE);
  gemm_f32<<<dim3(gemm_gx, DD / 64), blk, 0, stream>>>(feat_host, pWh, DD, 0, host_out, NN, DD);
  gemm_f32<<<dim3(gemm_gx, 4), blk, 0, stream>>>(feat_flow, W2, HD, 0, fsbuf, NN, 256);
  edge_hp<<<eB_g, blk, 0, stream>>>(e2s, e2d, wbuf, sbuf, fsbuf, host_out, EE, 0);
  gemm_f32<<<dim3(gemm_gx, 4), blk, 0, stream>>>(feat_flow, W2, HD, 256, fsbuf, NN, 256);
  edge_hp<<<eB_g, blk, 0, stream>>>(e2s, e2d, wbuf, sbuf, fsbuf, host_out, EE, 1);
  tail2<<<sk_g, blk, 0, stream>>>(b2, pbh, gh, beh, host_out, NN);
}

// Round 4
// 1021.366 us; speedup vs baseline: 1.9306x; 1.9306x over previous
//
#include <hip/hip_runtime.h>
#include <math.h>

#define NN 100000      // nodes per type
#define EE 200000      // edges per relation
#define HH 4
#define DD 128
#define HD 512         // H*D
#define KIN 256        // input feature dim
#define LN_EPS 1e-5f
#define SLOPE 0.2f

typedef short bf16x8 __attribute__((ext_vector_type(8)));
typedef float f32x4 __attribute__((ext_vector_type(4)));

static __device__ __forceinline__ unsigned short f2bf(float x) {
  unsigned int u = __float_as_uint(x);
  u += 0x7fffu + ((u >> 16) & 1u);   // RNE
  return (unsigned short)(u >> 16);
}
static __device__ __forceinline__ float bf2f(unsigned short h) {
  return __uint_as_float(((unsigned int)h) << 16);
}

// ---------------- convert + transpose weights to bf16 [N][K]
__global__ __launch_bounds__(256) void convw(
    const float* __restrict__ W1, const float* __restrict__ W2,
    const float* __restrict__ pWh, const float* __restrict__ pWf,
    short* __restrict__ W1t, short* __restrict__ W2t,
    short* __restrict__ pWht, short* __restrict__ pWft) {
  int idx = blockIdx.x * 256 + threadIdx.x;   // up to 512*256
  if (idx < 512 * 256) {
    int n = idx >> 8, k = idx & 255;
    W1t[idx] = (short)f2bf(W1[(size_t)k * HD + n]);
    W2t[idx] = (short)f2bf(W2[(size_t)k * HD + n]);
  }
  if (idx < 128 * 256) {
    int n = idx >> 8, k = idx & 255;
    pWht[idx] = (short)f2bf(pWh[(size_t)k * DD + n]);
    pWft[idx] = (short)f2bf(pWf[(size_t)k * DD + n]);
  }
}

// ---------------- build C[k,h] = sum_d W[k, h*128+d] * a[h*128+d]  (4 matrices)
__global__ __launch_bounds__(256) void make_c(
    const float* __restrict__ W1, const float* __restrict__ al1, const float* __restrict__ ar1,
    const float* __restrict__ W2, const float* __restrict__ al2, const float* __restrict__ ar2,
    float* __restrict__ Cout) {
  int which = blockIdx.y;
  const float* W = (which < 2) ? W1 : W2;
  const float* a = (which == 0) ? al1 : (which == 1) ? ar1 : (which == 2) ? al2 : ar2;
  int k = threadIdx.x;
  float* C = Cout + (size_t)which * 1024;
#pragma unroll
  for (int h = 0; h < HH; h++) {
    float s = 0.f;
    for (int d = 0; d < DD; d++) s = fmaf(W[(size_t)k * HD + h * DD + d], a[h * DD + d], s);
    C[k * HH + h] = s;
  }
}

// ---------------- skinny x2: o1[n,h]=X[n,:]@C1[:,h], o2 likewise (one wave/row)
__global__ __launch_bounds__(256) void skinny8(
    const float* __restrict__ X, const float* __restrict__ C1, const float* __restrict__ C2,
    float* __restrict__ o1, float* __restrict__ o2, int M) {
  __shared__ float Cs[KIN * 8];
  int tid = threadIdx.x;
  for (int i = tid; i < KIN * 4; i += 256) {
    int k = i >> 2, h = i & 3;
    Cs[k * 8 + h] = C1[i];
    Cs[k * 8 + 4 + h] = C2[i];
  }
  __syncthreads();
  int wave = tid >> 6, lane = tid & 63;
  int n = blockIdx.x * 4 + wave;
  if (n >= M) return;
  float4 xv = ((const float4*)(X + (size_t)n * KIN))[lane];
  float xs[4] = {xv.x, xv.y, xv.z, xv.w};
  float acc[8] = {0.f, 0.f, 0.f, 0.f, 0.f, 0.f, 0.f, 0.f};
#pragma unroll
  for (int j = 0; j < 4; j++) {
    int k = lane * 4 + j;
#pragma unroll
    for (int t = 0; t < 8; t++) acc[t] = fmaf(xs[j], Cs[k * 8 + t], acc[t]);
  }
#pragma unroll
  for (int off = 32; off >= 1; off >>= 1)
#pragma unroll
    for (int t = 0; t < 8; t++) acc[t] += __shfl_xor(acc[t], off);
  if (lane == 0) {
#pragma unroll
    for (int h = 0; h < HH; h++) {
      o1[(size_t)n * HH + h] = acc[h];
      o2[(size_t)n * HH + h] = acc[4 + h];
    }
  }
}

// ---------------- MFMA GEMM: C[M x N] = bf16(X[M x 256]) @ Wt[N x 256]^T
// Wt is bf16 row-major [N][256]. Output: bf16 (write_bf=1) or f32, ld = ldC.
__global__ __launch_bounds__(256) void mfma_gemm(
    const float* __restrict__ X, const short* __restrict__ Wt,
    void* __restrict__ Cout, int ldC, int M, int write_bf) {
  __shared__ short As[128 * 64];
  __shared__ short Bs[128 * 64];
  int tid = threadIdx.x;
  int lane = tid & 63, wid = tid >> 6;
  int wm = wid >> 1, wn = wid & 1;           // 2x2 waves, 64x64 out each
  int row0 = blockIdx.x * 128;
  int col0 = blockIdx.y * 128;

  f32x4 acc[4][4];
#pragma unroll
  for (int i = 0; i < 4; i++)
#pragma unroll
    for (int j = 0; j < 4; j++) acc[i][j] = (f32x4){0.f, 0.f, 0.f, 0.f};

  int am = tid >> 1;                // A row within tile (0..127)
  int akh = (tid & 1) * 32;         // k half within BK=64
  bool arow_ok = (row0 + am) < M;

  for (int k0 = 0; k0 < KIN; k0 += 64) {
    __syncthreads();
    // ---- A stage: 32 f32 -> 32 bf16, swizzled ds_write_b128 x4
    {
      const float* xp = X + (size_t)(row0 + am) * KIN + k0 + akh;
#pragma unroll
      for (int c = 0; c < 4; c++) {
        float4 v0, v1;
        if (arow_ok) {
          v0 = *(const float4*)(xp + c * 8);
          v1 = *(const float4*)(xp + c * 8 + 4);
        } else {
          v0 = make_float4(0.f, 0.f, 0.f, 0.f);
          v1 = v0;
        }
        bf16x8 pk;
        pk[0] = (short)f2bf(v0.x); pk[1] = (short)f2bf(v0.y);
        pk[2] = (short)f2bf(v0.z); pk[3] = (short)f2bf(v0.w);
        pk[4] = (short)f2bf(v1.x); pk[5] = (short)f2bf(v1.y);
        pk[6] = (short)f2bf(v1.z); pk[7] = (short)f2bf(v1.w);
        int kc = akh + c * 8;
        int ad = (am * 128 + kc * 2) ^ ((am & 7) << 4);
        *(bf16x8*)((char*)As + ad) = pk;
      }
    }
    // ---- B stage: bf16 copy, swizzled
    {
      int bn = tid >> 1;
      int bkh = (tid & 1) * 32;
      const short* wp = Wt + (size_t)(col0 + bn) * KIN + k0 + bkh;
#pragma unroll
      for (int c = 0; c < 4; c++) {
        bf16x8 pv = *(const bf16x8*)(wp + c * 8);
        int kc = bkh + c * 8;
        int bd = (bn * 128 + kc * 2) ^ ((bn & 7) << 4);
        *(bf16x8*)((char*)Bs + bd) = pv;
      }
    }
    __syncthreads();
    // ---- compute: 2 k-steps of 32
#pragma unroll
    for (int ks = 0; ks < 2; ks++) {
      int kb = ks * 32 + (lane >> 4) * 8;
      bf16x8 af[4], bfv[4];
#pragma unroll
      for (int mf = 0; mf < 4; mf++) {
        int r = wm * 64 + mf * 16 + (lane & 15);
        int ad = (r * 128 + kb * 2) ^ ((r & 7) << 4);
        af[mf] = *(bf16x8*)((char*)As + ad);
      }
#pragma unroll
      for (int nf = 0; nf < 4; nf++) {
        int cc = wn * 64 + nf * 16 + (lane & 15);
        int bd = (cc * 128 + kb * 2) ^ ((cc & 7) << 4);
        bfv[nf] = *(bf16x8*)((char*)Bs + bd);
      }
#pragma unroll
      for (int mf = 0; mf < 4; mf++)
#pragma unroll
        for (int nf = 0; nf < 4; nf++)
          acc[mf][nf] = __builtin_amdgcn_mfma_f32_16x16x32_bf16(af[mf], bfv[nf], acc[mf][nf], 0, 0, 0);
    }
  }
  // ---- epilogue: D row=(lane>>4)*4+r, col=lane&15
  int lr = lane >> 4, lc = lane & 15;
#pragma unroll
  for (int mf = 0; mf < 4; mf++) {
#pragma unroll
    for (int r4 = 0; r4 < 4; r4++) {
      int row = row0 + wm * 64 + mf * 16 + lr * 4 + r4;
      if (row < M) {
#pragma unroll
        for (int nf = 0; nf < 4; nf++) {
          int col = col0 + wn * 64 + nf * 16 + lc;
          float v = acc[mf][nf][r4];
          if (write_bf) ((unsigned short*)Cout)[(size_t)row * ldC + col] = f2bf(v);
          else ((float*)Cout)[(size_t)row * ldC + col] = v;
        }
      }
    }
  }
}

// ---------------- edge pass A: w = exp(leaky(el[src]+er[dst])); s[dst] += w
__global__ __launch_bounds__(256) void edge_a(
    const int* __restrict__ src, const int* __restrict__ dst,
    const float* __restrict__ el, const float* __restrict__ er,
    float* __restrict__ wbuf, float* __restrict__ s, int E) {
  int e = blockIdx.x * 256 + threadIdx.x;
  if (e >= E) return;
  int si = src[e], di = dst[e];
  float4 l = *(const float4*)(el + (size_t)si * HH);
  float4 r = *(const float4*)(er + (size_t)di * HH);
  float lv[4] = {l.x, l.y, l.z, l.w};
  float rv[4] = {r.x, r.y, r.z, r.w};
#pragma unroll
  for (int h = 0; h < HH; h++) {
    float v = lv[h] + rv[h];
    v = v > 0.f ? v : SLOPE * v;
    float w = __expf(v);
    wbuf[(size_t)e * HH + h] = w;
    atomicAdd(&s[(size_t)di * HH + h], w);
  }
}

// ---------------- edge pass B: all 4 heads, one wave/edge, bf16 fs
// c[dst,d] += 0.25 * sum_h (w_h/s_h) * fs[src, h*128+d]
__global__ __launch_bounds__(256) void edge_full(
    const int* __restrict__ src, const int* __restrict__ dst,
    const float* __restrict__ wbuf, const float* __restrict__ s,
    const unsigned short* __restrict__ fsb, float* __restrict__ c, int E) {
  int gid = blockIdx.x * 256 + threadIdx.x;
  int e = gid >> 6, lane = gid & 63;
  if (e >= E) return;
  int si = src[e], di = dst[e];
  float4 wv = *(const float4*)(wbuf + (size_t)e * HH);
  float4 sv = *(const float4*)(s + (size_t)di * HH);
  float aa[4] = {0.25f * wv.x / sv.x, 0.25f * wv.y / sv.y,
                 0.25f * wv.z / sv.z, 0.25f * wv.w / sv.w};
  const unsigned int* f = (const unsigned int*)(fsb + (size_t)si * HD);
  float m0 = 0.f, m1 = 0.f;
#pragma unroll
  for (int h = 0; h < HH; h++) {
    unsigned int u = f[h * 64 + lane];
    m0 = fmaf(aa[h], bf2f((unsigned short)(u & 0xffffu)), m0);
    m1 = fmaf(aa[h], bf2f((unsigned short)(u >> 16)), m1);
  }
  float* cp = c + (size_t)di * DD + lane * 2;
  atomicAdd(cp, m0);
  atomicAdd(cp + 1, m1);
}

// ---------------- tail: c (in out slot) + pb + mean(b) -> LN -> GELU, in place
__global__ __launch_bounds__(256) void tail2(
    const float* __restrict__ b, const float* __restrict__ pb,
    const float* __restrict__ g, const float* __restrict__ be,
    float* __restrict__ out, int M) {
  int wave = threadIdx.x >> 6, lane = threadIdx.x & 63;
  int n = blockIdx.x * 4 + wave;
  if (n >= M) return;
  float2 cv = ((const float2*)(out + (size_t)n * DD))[lane];
  const float2* bb = (const float2*)b;
  float bx = 0.f, by = 0.f;
#pragma unroll
  for (int h = 0; h < HH; h++) {
    float2 bv = bb[h * 64 + lane];
    bx += bv.x; by += bv.y;
  }
  float2 pbv = ((const float2*)pb)[lane];
  float cx = cv.x + 0.25f * bx + pbv.x;
  float cy = cv.y + 0.25f * by + pbv.y;
  float ssum = cx + cy;
#pragma unroll
  for (int off = 32; off >= 1; off >>= 1) ssum += __shfl_xor(ssum, off);
  float mu = ssum * (1.f / 128.f);
  float dx = cx - mu, dy = cy - mu;
  float v2 = dx * dx + dy * dy;
#pragma unroll
  for (int off = 32; off >= 1; off >>= 1) v2 += __shfl_xor(v2, off);
  float inv = rsqrtf(v2 * (1.f / 128.f) + LN_EPS);
  float2 gv = ((const float2*)g)[lane];
  float2 bev = ((const float2*)be)[lane];
  float yx = dx * inv * gv.x + bev.x;
  float yy = dy * inv * gv.y + bev.y;
  float ox = 0.5f * yx * (1.f + erff(yx * 0.70710678118f));
  float oy = 0.5f * yy * (1.f + erff(yy * 0.70710678118f));
  ((float2*)(out + (size_t)n * DD))[lane] = make_float2(ox, oy);
}

extern "C" void kernel_launch(void* const* d_in, const int* in_sizes, int n_in,
                              void* d_out, int out_size, void* d_ws, size_t ws_size,
                              hipStream_t stream) {
  const float* feat_host = (const float*)d_in[0];
  const float* feat_flow = (const float*)d_in[1];
  const float* W1  = (const float*)d_in[2];
  const float* al1 = (const float*)d_in[3];
  const float* ar1 = (const float*)d_in[4];
  const float* b1  = (const float*)d_in[5];
  const float* W2  = (const float*)d_in[6];
  const float* al2 = (const float*)d_in[7];
  const float* ar2 = (const float*)d_in[8];
  const float* b2  = (const float*)d_in[9];
  const float* pWh = (const float*)d_in[10];
  const float* pbh = (const float*)d_in[11];
  const float* pWf = (const float*)d_in[12];
  const float* pbf = (const float*)d_in[13];
  const float* gh  = (const float*)d_in[14];
  const float* beh = (const float*)d_in[15];
  const float* gf  = (const float*)d_in[16];
  const float* bef = (const float*)d_in[17];
  const int* e1s = (const int*)d_in[18];
  const int* e1d = (const int*)d_in[19];
  const int* e2s = (const int*)d_in[20];
  const int* e2d = (const int*)d_in[21];

  float* out = (float*)d_out;
  float* host_out = out;                       // [NN,128]
  float* flow_out = out + (size_t)NN * DD;     // [NN,128]

  // workspace (~114 MB)
  float* ws = (float*)d_ws;
  size_t off = 0;
  unsigned short* fsb = (unsigned short*)(ws + off); off += (size_t)NN * 256;  // NN x 512 bf16
  short* W1t  = (short*)(ws + off); off += (512 * 256) / 2;
  short* W2t  = (short*)(ws + off); off += (512 * 256) / 2;
  short* pWht = (short*)(ws + off); off += (128 * 256) / 2;
  short* pWft = (short*)(ws + off); off += (128 * 256) / 2;
  float* el1b = ws + off; off += (size_t)NN * HH;
  float* er1b = ws + off; off += (size_t)NN * HH;
  float* el2b = ws + off; off += (size_t)NN * HH;
  float* er2b = ws + off; off += (size_t)NN * HH;
  float* sbuf = ws + off; off += (size_t)NN * HH;
  float* wbuf = ws + off; off += (size_t)EE * HH;
  float* Cbuf = ws + off; off += 4096;

  dim3 blk(256);
  int gx = (NN + 127) / 128;            // 782 row tiles
  int sk_g = (NN + 3) / 4;
  int eA_g = (EE + 255) / 256;
  int eF_g = (EE * 64 + 255) / 256;

  convw<<<512, blk, 0, stream>>>(W1, W2, pWh, pWf, W1t, W2t, pWht, pWft);
  make_c<<<dim3(1, 4), blk, 0, stream>>>(W1, al1, ar1, W2, al2, ar2, Cbuf);
  // el1 (src r1 = host), er2 (dst r2 = host) from feat_host; er1/el2 from feat_flow
  skinny8<<<sk_g, blk, 0, stream>>>(feat_host, Cbuf + 0,    Cbuf + 3072, el1b, er2b, NN);
  skinny8<<<sk_g, blk, 0, stream>>>(feat_flow, Cbuf + 1024, Cbuf + 2048, er1b, el2b, NN);

  // ---- relation 1: host -> flow (dst = flow, out = flow_out)
  hipMemsetAsync(sbuf, 0, (size_t)NN * HH * sizeof(float), stream);
  edge_a<<<eA_g, blk, 0, stream>>>(e1s, e1d, el1b, er1b, wbuf, sbuf, EE);
  mfma_gemm<<<dim3(gx, 1), blk, 0, stream>>>(feat_flow, pWft, flow_out, DD, NN, 0);
  mfma_gemm<<<dim3(gx, 4), blk, 0, stream>>>(feat_host, W1t, fsb, HD, NN, 1);
  edge_full<<<eF_g, blk, 0, stream>>>(e1s, e1d, wbuf, sbuf, fsb, flow_out, EE);
  tail2<<<sk_g, blk, 0, stream>>>(b1, pbf, gf, bef, flow_out, NN);

  // ---- relation 2: flow -> host (dst = host, out = host_out)
  hipMemsetAsync(sbuf, 0, (size_t)NN * HH * sizeof(float), stream);
  edge_a<<<eA_g, blk, 0, stream>>>(e2s, e2d, el2b, er2b, wbuf, sbuf, EE);
  mfma_gemm<<<dim3(gx, 1), blk, 0, stream>>>(feat_host, pWht, host_out, DD, NN, 0);
  mfma_gemm<<<dim3(gx, 4), blk, 0, stream>>>(feat_flow, W2t, fsb, HD, NN, 1);
  edge_full<<<eF_g, blk, 0, stream>>>(e2s, e2d, wbuf, sbuf, fsb, host_out, EE);
  tail2<<<sk_g, blk, 0, stream>>>(b2, pbh, gh, beh, host_out, NN);
}

// Round 5
// 768.388 us; speedup vs baseline: 2.5662x; 1.3292x over previous
//
#include <hip/hip_runtime.h>
#include <math.h>

#define NN 100000      // nodes per type
#define EE 200000      // edges per relation
#define HH 4
#define DD 128
#define HD 512         // H*D
#define KIN 256        // input feature dim
#define LN_EPS 1e-5f
#define SLOPE 0.2f
#define NB_SCAN 98     // ceil(NN/1024)

typedef short bf16x8 __attribute__((ext_vector_type(8)));
typedef float f32x4 __attribute__((ext_vector_type(4)));

static __device__ __forceinline__ unsigned short f2bf(float x) {
  unsigned int u = __float_as_uint(x);
  u += 0x7fffu + ((u >> 16) & 1u);   // RNE
  return (unsigned short)(u >> 16);
}
static __device__ __forceinline__ float bf2f(unsigned short h) {
  return __uint_as_float(((unsigned int)h) << 16);
}

// ---------------- convert + transpose weights to bf16 [N][K]
__global__ __launch_bounds__(256) void convw(
    const float* __restrict__ W1, const float* __restrict__ W2,
    const float* __restrict__ pWh, const float* __restrict__ pWf,
    short* __restrict__ W1t, short* __restrict__ W2t,
    short* __restrict__ pWht, short* __restrict__ pWft) {
  int idx = blockIdx.x * 256 + threadIdx.x;
  if (idx < 512 * 256) {
    int n = idx >> 8, k = idx & 255;
    W1t[idx] = (short)f2bf(W1[(size_t)k * HD + n]);
    W2t[idx] = (short)f2bf(W2[(size_t)k * HD + n]);
  }
  if (idx < 128 * 256) {
    int n = idx >> 8, k = idx & 255;
    pWht[idx] = (short)f2bf(pWh[(size_t)k * DD + n]);
    pWft[idx] = (short)f2bf(pWf[(size_t)k * DD + n]);
  }
}

// ---------------- convert features to bf16 (row-major [M][256])
__global__ __launch_bounds__(256) void convf(
    const float* __restrict__ X, short* __restrict__ Xb, int n8) {
  int i = blockIdx.x * 256 + threadIdx.x;   // handles 8 elems
  if (i >= n8) return;
  const float4* p = (const float4*)(X + (size_t)i * 8);
  float4 v0 = p[0], v1 = p[1];
  bf16x8 pk;
  pk[0] = (short)f2bf(v0.x); pk[1] = (short)f2bf(v0.y);
  pk[2] = (short)f2bf(v0.z); pk[3] = (short)f2bf(v0.w);
  pk[4] = (short)f2bf(v1.x); pk[5] = (short)f2bf(v1.y);
  pk[6] = (short)f2bf(v1.z); pk[7] = (short)f2bf(v1.w);
  *(bf16x8*)(Xb + (size_t)i * 8) = pk;
}

// ---------------- build C[k,h] = sum_d W[k, h*128+d] * a[h*128+d]
__global__ __launch_bounds__(256) void make_c(
    const float* __restrict__ W1, const float* __restrict__ al1, const float* __restrict__ ar1,
    const float* __restrict__ W2, const float* __restrict__ al2, const float* __restrict__ ar2,
    float* __restrict__ Cout) {
  int which = blockIdx.y;
  const float* W = (which < 2) ? W1 : W2;
  const float* a = (which == 0) ? al1 : (which == 1) ? ar1 : (which == 2) ? al2 : ar2;
  int k = threadIdx.x;
  float* C = Cout + (size_t)which * 1024;
#pragma unroll
  for (int h = 0; h < HH; h++) {
    float s = 0.f;
    for (int d = 0; d < DD; d++) s = fmaf(W[(size_t)k * HD + h * DD + d], a[h * DD + d], s);
    C[k * HH + h] = s;
  }
}

// ---------------- skinny x2: o1[n,h]=X[n,:]@C1[:,h], o2 likewise (one wave/row)
__global__ __launch_bounds__(256) void skinny8(
    const float* __restrict__ X, const float* __restrict__ C1, const float* __restrict__ C2,
    float* __restrict__ o1, float* __restrict__ o2, int M) {
  __shared__ float Cs[KIN * 8];
  int tid = threadIdx.x;
  for (int i = tid; i < KIN * 4; i += 256) {
    int k = i >> 2, h = i & 3;
    Cs[k * 8 + h] = C1[i];
    Cs[k * 8 + 4 + h] = C2[i];
  }
  __syncthreads();
  int wave = tid >> 6, lane = tid & 63;
  int n = blockIdx.x * 4 + wave;
  if (n >= M) return;
  float4 xv = ((const float4*)(X + (size_t)n * KIN))[lane];
  float xs[4] = {xv.x, xv.y, xv.z, xv.w};
  float acc[8] = {0.f, 0.f, 0.f, 0.f, 0.f, 0.f, 0.f, 0.f};
#pragma unroll
  for (int j = 0; j < 4; j++) {
    int k = lane * 4 + j;
#pragma unroll
    for (int t = 0; t < 8; t++) acc[t] = fmaf(xs[j], Cs[k * 8 + t], acc[t]);
  }
#pragma unroll
  for (int off = 32; off >= 1; off >>= 1)
#pragma unroll
    for (int t = 0; t < 8; t++) acc[t] += __shfl_xor(acc[t], off);
  if (lane == 0) {
#pragma unroll
    for (int h = 0; h < HH; h++) {
      o1[(size_t)n * HH + h] = acc[h];
      o2[(size_t)n * HH + h] = acc[4 + h];
    }
  }
}

// ---------------- CSR build (batched over 2 relations) ----------------
__global__ __launch_bounds__(256) void hist2(
    const int* __restrict__ d1, const int* __restrict__ d2,
    int* __restrict__ c1, int* __restrict__ c2) {
  int gid = blockIdx.x * 256 + threadIdx.x;
  if (gid < EE) atomicAdd(&c1[d1[gid]], 1);
  else if (gid < 2 * EE) atomicAdd(&c2[d2[gid - EE]], 1);
}

__global__ __launch_bounds__(256) void scan_chunk(
    const int* __restrict__ c1, const int* __restrict__ c2,
    int* __restrict__ rp1, int* __restrict__ rp2, int* __restrict__ bsum) {
  int rel = blockIdx.y;
  const int* counts = rel ? c2 : c1;
  int* rowptr = rel ? rp2 : rp1;
  int* bs = bsum + rel * 128;
  __shared__ int sd[256];
  int tid = threadIdx.x;
  int base = blockIdx.x * 1024 + tid * 4;
  int c[4];
#pragma unroll
  for (int j = 0; j < 4; j++) c[j] = (base + j < NN) ? counts[base + j] : 0;
  int tot = c[0] + c[1] + c[2] + c[3];
  sd[tid] = tot; __syncthreads();
  for (int o = 1; o < 256; o <<= 1) {
    int v = (tid >= o) ? sd[tid - o] : 0;
    __syncthreads();
    sd[tid] += v;
    __syncthreads();
  }
  int excl = sd[tid] - tot;
  int run = excl;
#pragma unroll
  for (int j = 0; j < 4; j++) {
    if (base + j < NN) rowptr[base + j] = run;
    run += c[j];
  }
  if (tid == 255) bs[blockIdx.x] = sd[255];
}

__global__ __launch_bounds__(128) void scan_bsum(int* __restrict__ bsum) {
  int rel = blockIdx.y;
  int* bs = bsum + rel * 128;
  __shared__ int sd[128];
  int tid = threadIdx.x;
  int v = (tid < NB_SCAN) ? bs[tid] : 0;
  sd[tid] = v; __syncthreads();
  for (int o = 1; o < 128; o <<= 1) {
    int t = (tid >= o) ? sd[tid - o] : 0;
    __syncthreads();
    sd[tid] += t;
    __syncthreads();
  }
  bs[tid] = sd[tid] - v;   // exclusive
}

__global__ __launch_bounds__(256) void addoff2(
    int* __restrict__ rp1, int* __restrict__ rp2,
    int* __restrict__ cur1, int* __restrict__ cur2,
    const int* __restrict__ bsum) {
  int rel = blockIdx.y;
  int* rowptr = rel ? rp2 : rp1;
  int* cur = rel ? cur2 : cur1;
  const int* bs = bsum + rel * 128;
  int i = blockIdx.x * 256 + threadIdx.x;
  if (i < NN) {
    int r = rowptr[i] + bs[i >> 10];
    rowptr[i] = r;
    cur[i] = r;
  }
  if (i == 0) rowptr[NN] = EE;
}

__global__ __launch_bounds__(256) void fill2(
    const int* __restrict__ d1, const int* __restrict__ d2,
    int* __restrict__ cur1, int* __restrict__ cur2,
    int* __restrict__ eid1, int* __restrict__ eid2) {
  int gid = blockIdx.x * 256 + threadIdx.x;
  if (gid < EE) {
    int p = atomicAdd(&cur1[d1[gid]], 1);
    eid1[p] = gid;
  } else if (gid < 2 * EE) {
    int e = gid - EE;
    int p = atomicAdd(&cur2[d2[e]], 1);
    eid2[p] = e;
  }
}

// ---------------- MFMA GEMM: C[M x N] = A[M x 256] @ Wt[N x 256]^T
// ABF=1: A is bf16 [M][256]; ABF=0: A is f32 [M][256] (converted on the fly).
template <int ABF>
__global__ __launch_bounds__(256) void mfma_gemm(
    const void* __restrict__ Av, const short* __restrict__ Wt,
    void* __restrict__ Cout, int ldC, int M, int write_bf) {
  __shared__ short As[128 * 64];
  __shared__ short Bs[128 * 64];
  int tid = threadIdx.x;
  int lane = tid & 63, wid = tid >> 6;
  int wm = wid >> 1, wn = wid & 1;
  int row0 = blockIdx.x * 128;
  int col0 = blockIdx.y * 128;

  f32x4 acc[4][4];
#pragma unroll
  for (int i = 0; i < 4; i++)
#pragma unroll
    for (int j = 0; j < 4; j++) acc[i][j] = (f32x4){0.f, 0.f, 0.f, 0.f};

  int am = tid >> 1;
  int akh = (tid & 1) * 32;
  bool arow_ok = (row0 + am) < M;

  for (int k0 = 0; k0 < KIN; k0 += 64) {
    __syncthreads();
    // ---- A stage
    if (ABF) {
      const short* xp = (const short*)Av + (size_t)(row0 + am) * KIN + k0 + akh;
#pragma unroll
      for (int c = 0; c < 4; c++) {
        bf16x8 pv;
        if (arow_ok) pv = *(const bf16x8*)(xp + c * 8);
        else pv = (bf16x8){0, 0, 0, 0, 0, 0, 0, 0};
        int kc = akh + c * 8;
        int ad = (am * 128 + kc * 2) ^ ((am & 7) << 4);
        *(bf16x8*)((char*)As + ad) = pv;
      }
    } else {
      const float* xp = (const float*)Av + (size_t)(row0 + am) * KIN + k0 + akh;
#pragma unroll
      for (int c = 0; c < 4; c++) {
        float4 v0, v1;
        if (arow_ok) {
          v0 = *(const float4*)(xp + c * 8);
          v1 = *(const float4*)(xp + c * 8 + 4);
        } else {
          v0 = make_float4(0.f, 0.f, 0.f, 0.f);
          v1 = v0;
        }
        bf16x8 pk;
        pk[0] = (short)f2bf(v0.x); pk[1] = (short)f2bf(v0.y);
        pk[2] = (short)f2bf(v0.z); pk[3] = (short)f2bf(v0.w);
        pk[4] = (short)f2bf(v1.x); pk[5] = (short)f2bf(v1.y);
        pk[6] = (short)f2bf(v1.z); pk[7] = (short)f2bf(v1.w);
        int kc = akh + c * 8;
        int ad = (am * 128 + kc * 2) ^ ((am & 7) << 4);
        *(bf16x8*)((char*)As + ad) = pk;
      }
    }
    // ---- B stage
    {
      int bn = tid >> 1;
      int bkh = (tid & 1) * 32;
      const short* wp = Wt + (size_t)(col0 + bn) * KIN + k0 + bkh;
#pragma unroll
      for (int c = 0; c < 4; c++) {
        bf16x8 pv = *(const bf16x8*)(wp + c * 8);
        int kc = bkh + c * 8;
        int bd = (bn * 128 + kc * 2) ^ ((bn & 7) << 4);
        *(bf16x8*)((char*)Bs + bd) = pv;
      }
    }
    __syncthreads();
#pragma unroll
    for (int ks = 0; ks < 2; ks++) {
      int kb = ks * 32 + (lane >> 4) * 8;
      bf16x8 af[4], bfv[4];
#pragma unroll
      for (int mf = 0; mf < 4; mf++) {
        int r = wm * 64 + mf * 16 + (lane & 15);
        int ad = (r * 128 + kb * 2) ^ ((r & 7) << 4);
        af[mf] = *(bf16x8*)((char*)As + ad);
      }
#pragma unroll
      for (int nf = 0; nf < 4; nf++) {
        int cc = wn * 64 + nf * 16 + (lane & 15);
        int bd = (cc * 128 + kb * 2) ^ ((cc & 7) << 4);
        bfv[nf] = *(bf16x8*)((char*)Bs + bd);
      }
#pragma unroll
      for (int mf = 0; mf < 4; mf++)
#pragma unroll
        for (int nf = 0; nf < 4; nf++)
          acc[mf][nf] = __builtin_amdgcn_mfma_f32_16x16x32_bf16(af[mf], bfv[nf], acc[mf][nf], 0, 0, 0);
    }
  }
  int lr = lane >> 4, lc = lane & 15;
#pragma unroll
  for (int mf = 0; mf < 4; mf++) {
#pragma unroll
    for (int r4 = 0; r4 < 4; r4++) {
      int row = row0 + wm * 64 + mf * 16 + lr * 4 + r4;
      if (row < M) {
#pragma unroll
        for (int nf = 0; nf < 4; nf++) {
          int col = col0 + wn * 64 + nf * 16 + lc;
          float v = acc[mf][nf][r4];
          if (write_bf) ((unsigned short*)Cout)[(size_t)row * ldC + col] = f2bf(v);
          else ((float*)Cout)[(size_t)row * ldC + col] = v;
        }
      }
    }
  }
}

// ---------------- fused per-dst aggregation + softmax + mean + residual + LN + GELU
// One wave per dst node. out already holds proj residual (f32); overwritten in place.
__global__ __launch_bounds__(256) void agg_fused(
    const int* __restrict__ rowptr, const int* __restrict__ eid,
    const int* __restrict__ src,
    const float* __restrict__ el, const float* __restrict__ er,
    const unsigned short* __restrict__ fsb,
    const float* __restrict__ b, const float* __restrict__ pb,
    const float* __restrict__ g, const float* __restrict__ be,
    float* __restrict__ out, int M) {
  int wave = threadIdx.x >> 6, lane = threadIdx.x & 63;
  int n = blockIdx.x * 4 + wave;
  if (n >= M) return;
  int beg = rowptr[n], end = rowptr[n + 1];
  float4 ern = *(const float4*)(er + (size_t)n * HH);
  // pass 1: s_h
  float sx = 0.f, sy = 0.f, sz = 0.f, sw = 0.f;
  for (int t = beg; t < end; t++) {
    int si = src[eid[t]];
    float4 elv = *(const float4*)(el + (size_t)si * HH);
    float v0 = elv.x + ern.x, v1 = elv.y + ern.y, v2 = elv.z + ern.z, v3 = elv.w + ern.w;
    v0 = v0 > 0.f ? v0 : SLOPE * v0; v1 = v1 > 0.f ? v1 : SLOPE * v1;
    v2 = v2 > 0.f ? v2 : SLOPE * v2; v3 = v3 > 0.f ? v3 : SLOPE * v3;
    sx += __expf(v0); sy += __expf(v1); sz += __expf(v2); sw += __expf(v3);
  }
  float rsx = sx > 0.f ? 0.25f / sx : 0.f;
  float rsy = sy > 0.f ? 0.25f / sy : 0.f;
  float rsz = sz > 0.f ? 0.25f / sz : 0.f;
  float rsw = sw > 0.f ? 0.25f / sw : 0.f;
  // pass 2: accumulate 0.25 * sum_h sum_e a * fs
  float m0 = 0.f, m1 = 0.f;
  for (int t = beg; t < end; t++) {
    int si = src[eid[t]];
    float4 elv = *(const float4*)(el + (size_t)si * HH);
    float v0 = elv.x + ern.x, v1 = elv.y + ern.y, v2 = elv.z + ern.z, v3 = elv.w + ern.w;
    v0 = v0 > 0.f ? v0 : SLOPE * v0; v1 = v1 > 0.f ? v1 : SLOPE * v1;
    v2 = v2 > 0.f ? v2 : SLOPE * v2; v3 = v3 > 0.f ? v3 : SLOPE * v3;
    float a0 = __expf(v0) * rsx, a1 = __expf(v1) * rsy;
    float a2 = __expf(v2) * rsz, a3 = __expf(v3) * rsw;
    const unsigned int* f = (const unsigned int*)(fsb + (size_t)si * HD) + lane;
    unsigned int u0 = f[0], u1 = f[64], u2 = f[128], u3 = f[192];
    m0 = fmaf(a0, bf2f((unsigned short)(u0 & 0xffffu)), m0);
    m1 = fmaf(a0, bf2f((unsigned short)(u0 >> 16)), m1);
    m0 = fmaf(a1, bf2f((unsigned short)(u1 & 0xffffu)), m0);
    m1 = fmaf(a1, bf2f((unsigned short)(u1 >> 16)), m1);
    m0 = fmaf(a2, bf2f((unsigned short)(u2 & 0xffffu)), m0);
    m1 = fmaf(a2, bf2f((unsigned short)(u2 >> 16)), m1);
    m0 = fmaf(a3, bf2f((unsigned short)(u3 & 0xffffu)), m0);
    m1 = fmaf(a3, bf2f((unsigned short)(u3 >> 16)), m1);
  }
  // bias mean + residual + LN + GELU
  const float2* bb = (const float2*)b;
  float bx = 0.f, by = 0.f;
#pragma unroll
  for (int h = 0; h < HH; h++) {
    float2 bv = bb[h * 64 + lane];
    bx += bv.x; by += bv.y;
  }
  float2 pr = ((const float2*)(out + (size_t)n * DD))[lane];
  float2 pbv = ((const float2*)pb)[lane];
  float cx = m0 + 0.25f * bx + pr.x + pbv.x;
  float cy = m1 + 0.25f * by + pr.y + pbv.y;
  float ssum = cx + cy;
#pragma unroll
  for (int off = 32; off >= 1; off >>= 1) ssum += __shfl_xor(ssum, off);
  float mu = ssum * (1.f / 128.f);
  float dx = cx - mu, dy = cy - mu;
  float v2s = dx * dx + dy * dy;
#pragma unroll
  for (int off = 32; off >= 1; off >>= 1) v2s += __shfl_xor(v2s, off);
  float inv = rsqrtf(v2s * (1.f / 128.f) + LN_EPS);
  float2 gv = ((const float2*)g)[lane];
  float2 bev = ((const float2*)be)[lane];
  float yx = dx * inv * gv.x + bev.x;
  float yy = dy * inv * gv.y + bev.y;
  float ox = 0.5f * yx * (1.f + erff(yx * 0.70710678118f));
  float oy = 0.5f * yy * (1.f + erff(yy * 0.70710678118f));
  ((float2*)(out + (size_t)n * DD))[lane] = make_float2(ox, oy);
}

extern "C" void kernel_launch(void* const* d_in, const int* in_sizes, int n_in,
                              void* d_out, int out_size, void* d_ws, size_t ws_size,
                              hipStream_t stream) {
  const float* feat_host = (const float*)d_in[0];
  const float* feat_flow = (const float*)d_in[1];
  const float* W1  = (const float*)d_in[2];
  const float* al1 = (const float*)d_in[3];
  const float* ar1 = (const float*)d_in[4];
  const float* b1  = (const float*)d_in[5];
  const float* W2  = (const float*)d_in[6];
  const float* al2 = (const float*)d_in[7];
  const float* ar2 = (const float*)d_in[8];
  const float* b2  = (const float*)d_in[9];
  const float* pWh = (const float*)d_in[10];
  const float* pbh = (const float*)d_in[11];
  const float* pWf = (const float*)d_in[12];
  const float* pbf = (const float*)d_in[13];
  const float* gh  = (const float*)d_in[14];
  const float* beh = (const float*)d_in[15];
  const float* gf  = (const float*)d_in[16];
  const float* bef = (const float*)d_in[17];
  const int* e1s = (const int*)d_in[18];
  const int* e1d = (const int*)d_in[19];
  const int* e2s = (const int*)d_in[20];
  const int* e2d = (const int*)d_in[21];

  float* out = (float*)d_out;
  float* host_out = out;                       // [NN,128]
  float* flow_out = out + (size_t)NN * DD;     // [NN,128]

  float* ws = (float*)d_ws;
  size_t off = 0;
  unsigned short* fsb = (unsigned short*)(ws + off); off += (size_t)NN * 256;  // NN x 512 bf16
  short* W1t  = (short*)(ws + off); off += (512 * 256) / 2;
  short* W2t  = (short*)(ws + off); off += (512 * 256) / 2;
  short* pWht = (short*)(ws + off); off += (128 * 256) / 2;
  short* pWft = (short*)(ws + off); off += (128 * 256) / 2;
  float* el1b = ws + off; off += (size_t)NN * HH;
  float* er1b = ws + off; off += (size_t)NN * HH;
  float* el2b = ws + off; off += (size_t)NN * HH;
  float* er2b = ws + off; off += (size_t)NN * HH;
  float* Cbuf = ws + off; off += 4096;
  // CSR region (ints)
  int* ibase = (int*)(ws + off);
  int* rp1  = ibase;                 // NN+1
  int* rp2  = rp1 + (NN + 1);        // NN+1
  int* eid1 = rp2 + (NN + 1);        // EE
  int* eid2 = eid1 + EE;             // EE
  int* cur1 = eid2 + EE;             // NN
  int* cur2 = cur1 + NN;             // NN
  int* bsum = cur2 + NN;             // 256
  off += (size_t)(2 * (NN + 1) + 2 * EE + 2 * NN + 256 + 3) / 1 * sizeof(int) / sizeof(float);
  // optional bf16 feature copies
  size_t base_bytes = (off + 1024) * sizeof(float);
  size_t featb_bytes = (size_t)NN * KIN * 2 * 2;   // 102.4 MB
  bool use_featb = ws_size >= base_bytes + featb_bytes;
  short* fhb = nullptr;
  short* ffb = nullptr;
  if (use_featb) {
    fhb = (short*)(ws + off); off += (size_t)NN * KIN / 2;
    ffb = (short*)(ws + off); off += (size_t)NN * KIN / 2;
  }

  dim3 blk(256);
  int gx = (NN + 127) / 128;
  int sk_g = (NN + 3) / 4;
  int ag_g = (NN + 3) / 4;
  int ee2_g = (2 * EE + 255) / 256;
  int nn_g = (NN + 255) / 256;

  // ---- prep: weights, features, attention vectors
  convw<<<512, blk, 0, stream>>>(W1, W2, pWh, pWf, W1t, W2t, pWht, pWft);
  if (use_featb) {
    int n8 = NN * KIN / 8;
    convf<<<(n8 + 255) / 256, blk, 0, stream>>>(feat_host, fhb, n8);
    convf<<<(n8 + 255) / 256, blk, 0, stream>>>(feat_flow, ffb, n8);
  }
  make_c<<<dim3(1, 4), blk, 0, stream>>>(W1, al1, ar1, W2, al2, ar2, Cbuf);
  skinny8<<<sk_g, blk, 0, stream>>>(feat_host, Cbuf + 0,    Cbuf + 3072, el1b, er2b, NN);
  skinny8<<<sk_g, blk, 0, stream>>>(feat_flow, Cbuf + 1024, Cbuf + 2048, er1b, el2b, NN);

  // ---- CSR build for both relations
  hipMemsetAsync(cur1, 0, 2 * NN * sizeof(int), stream);
  hist2<<<ee2_g, blk, 0, stream>>>(e1d, e2d, cur1, cur2);
  scan_chunk<<<dim3(NB_SCAN, 2), blk, 0, stream>>>(cur1, cur2, rp1, rp2, bsum);
  scan_bsum<<<dim3(1, 2), 128, 0, stream>>>(bsum);
  addoff2<<<dim3(nn_g, 2), blk, 0, stream>>>(rp1, rp2, cur1, cur2, bsum);
  fill2<<<ee2_g, blk, 0, stream>>>(e1d, e2d, cur1, cur2, eid1, eid2);

  // ---- relation 1: host -> flow (dst = flow, out = flow_out)
  if (use_featb) {
    mfma_gemm<1><<<dim3(gx, 1), blk, 0, stream>>>(ffb, pWft, flow_out, DD, NN, 0);
    mfma_gemm<1><<<dim3(gx, 4), blk, 0, stream>>>(fhb, W1t, fsb, HD, NN, 1);
  } else {
    mfma_gemm<0><<<dim3(gx, 1), blk, 0, stream>>>(feat_flow, pWft, flow_out, DD, NN, 0);
    mfma_gemm<0><<<dim3(gx, 4), blk, 0, stream>>>(feat_host, W1t, fsb, HD, NN, 1);
  }
  agg_fused<<<ag_g, blk, 0, stream>>>(rp1, eid1, e1s, el1b, er1b, fsb,
                                      b1, pbf, gf, bef, flow_out, NN);

  // ---- relation 2: flow -> host (dst = host, out = host_out)
  if (use_featb) {
    mfma_gemm<1><<<dim3(gx, 1), blk, 0, stream>>>(fhb, pWht, host_out, DD, NN, 0);
    mfma_gemm<1><<<dim3(gx, 4), blk, 0, stream>>>(ffb, W2t, fsb, HD, NN, 1);
  } else {
    mfma_gemm<0><<<dim3(gx, 1), blk, 0, stream>>>(feat_host, pWht, host_out, DD, NN, 0);
    mfma_gemm<0><<<dim3(gx, 4), blk, 0, stream>>>(feat_flow, W2t, fsb, HD, NN, 1);
  }
  agg_fused<<<ag_g, blk, 0, stream>>>(rp2, eid2, e2s, el2b, er2b, fsb,
                                      b2, pbh, gh, beh, host_out, NN);
}

// Round 6
// 757.551 us; speedup vs baseline: 2.6029x; 1.0143x over previous
//
#include <hip/hip_runtime.h>
#include <math.h>

#define NN 100000      // nodes per type
#define EE 200000      // edges per relation
#define HH 4
#define DD 128
#define HD 512         // H*D
#define KIN 256        // input feature dim
#define LN_EPS 1e-5f
#define SLOPE 0.2f
#define NB_SCAN 98     // ceil(NN/1024)

typedef short bf16x8 __attribute__((ext_vector_type(8)));
typedef unsigned short u16x4 __attribute__((ext_vector_type(4)));
typedef float f32x4 __attribute__((ext_vector_type(4)));

static __device__ __forceinline__ unsigned short f2bf(float x) {
  unsigned int u = __float_as_uint(x);
  u += 0x7fffu + ((u >> 16) & 1u);   // RNE
  return (unsigned short)(u >> 16);
}
static __device__ __forceinline__ float bf_lo(unsigned int u) {
  return __uint_as_float(u << 16);
}
static __device__ __forceinline__ float bf_hi(unsigned int u) {
  return __uint_as_float(u & 0xffff0000u);
}

// ---------------- convert + transpose weights to bf16 [N][K]
__global__ __launch_bounds__(256) void convw(
    const float* __restrict__ W1, const float* __restrict__ W2,
    const float* __restrict__ pWh, const float* __restrict__ pWf,
    short* __restrict__ W1t, short* __restrict__ W2t,
    short* __restrict__ pWht, short* __restrict__ pWft) {
  int idx = blockIdx.x * 256 + threadIdx.x;
  if (idx < 512 * 256) {
    int n = idx >> 8, k = idx & 255;
    W1t[idx] = (short)f2bf(W1[(size_t)k * HD + n]);
    W2t[idx] = (short)f2bf(W2[(size_t)k * HD + n]);
  }
  if (idx < 128 * 256) {
    int n = idx >> 8, k = idx & 255;
    pWht[idx] = (short)f2bf(pWh[(size_t)k * DD + n]);
    pWft[idx] = (short)f2bf(pWf[(size_t)k * DD + n]);
  }
}

// ---------------- build C[k,h] = sum_d W[k, h*128+d] * a[h*128+d]
__global__ __launch_bounds__(256) void make_c(
    const float* __restrict__ W1, const float* __restrict__ al1, const float* __restrict__ ar1,
    const float* __restrict__ W2, const float* __restrict__ al2, const float* __restrict__ ar2,
    float* __restrict__ Cout) {
  int which = blockIdx.y;
  const float* W = (which < 2) ? W1 : W2;
  const float* a = (which == 0) ? al1 : (which == 1) ? ar1 : (which == 2) ? al2 : ar2;
  int k = threadIdx.x;
  float* C = Cout + (size_t)which * 1024;
#pragma unroll
  for (int h = 0; h < HH; h++) {
    float s = 0.f;
    for (int d = 0; d < DD; d++) s = fmaf(W[(size_t)k * HD + h * DD + d], a[h * DD + d], s);
    C[k * HH + h] = s;
  }
}

// ---------------- bm1[d] = 0.25*sum_h b1 + pbf ; bm2 likewise (b2, pbh)
__global__ __launch_bounds__(256) void make_bm(
    const float* __restrict__ b1, const float* __restrict__ pbf,
    const float* __restrict__ b2, const float* __restrict__ pbh,
    float* __restrict__ bm) {
  int d = threadIdx.x;
  if (d < 128) {
    bm[d] = 0.25f * (b1[d] + b1[128 + d] + b1[256 + d] + b1[384 + d]) + pbf[d];
  } else {
    int dd = d - 128;
    bm[d] = 0.25f * (b2[dd] + b2[128 + dd] + b2[256 + dd] + b2[384 + dd]) + pbh[dd];
  }
}

// ---------------- fused: bf16 convert + el/er skinny dots (one wave per row)
__global__ __launch_bounds__(256) void prep_feat(
    const float* __restrict__ X, const float* __restrict__ C1, const float* __restrict__ C2,
    short* __restrict__ Xb, float* __restrict__ o1, float* __restrict__ o2, int M) {
  __shared__ float Cs[KIN * 8];
  int tid = threadIdx.x;
  for (int i = tid; i < KIN * 4; i += 256) {
    int k = i >> 2, h = i & 3;
    Cs[k * 8 + h] = C1[i];
    Cs[k * 8 + 4 + h] = C2[i];
  }
  __syncthreads();
  int wave = tid >> 6, lane = tid & 63;
  int n = blockIdx.x * 4 + wave;
  if (n >= M) return;
  float4 xv = ((const float4*)(X + (size_t)n * KIN))[lane];
  float xs[4] = {xv.x, xv.y, xv.z, xv.w};
  u16x4 pk;
  pk[0] = f2bf(xs[0]); pk[1] = f2bf(xs[1]); pk[2] = f2bf(xs[2]); pk[3] = f2bf(xs[3]);
  *(u16x4*)(Xb + (size_t)n * KIN + lane * 4) = pk;
  float acc[8] = {0.f, 0.f, 0.f, 0.f, 0.f, 0.f, 0.f, 0.f};
#pragma unroll
  for (int j = 0; j < 4; j++) {
    int k = lane * 4 + j;
#pragma unroll
    for (int t = 0; t < 8; t++) acc[t] = fmaf(xs[j], Cs[k * 8 + t], acc[t]);
  }
#pragma unroll
  for (int off = 32; off >= 1; off >>= 1)
#pragma unroll
    for (int t = 0; t < 8; t++) acc[t] += __shfl_xor(acc[t], off);
  if (lane == 0) {
#pragma unroll
    for (int h = 0; h < HH; h++) {
      o1[(size_t)n * HH + h] = acc[h];
      o2[(size_t)n * HH + h] = acc[4 + h];
    }
  }
}

// ---------------- fallback skinny (no bf16 feature copy)
__global__ __launch_bounds__(256) void skinny8(
    const float* __restrict__ X, const float* __restrict__ C1, const float* __restrict__ C2,
    float* __restrict__ o1, float* __restrict__ o2, int M) {
  __shared__ float Cs[KIN * 8];
  int tid = threadIdx.x;
  for (int i = tid; i < KIN * 4; i += 256) {
    int k = i >> 2, h = i & 3;
    Cs[k * 8 + h] = C1[i];
    Cs[k * 8 + 4 + h] = C2[i];
  }
  __syncthreads();
  int wave = tid >> 6, lane = tid & 63;
  int n = blockIdx.x * 4 + wave;
  if (n >= M) return;
  float4 xv = ((const float4*)(X + (size_t)n * KIN))[lane];
  float xs[4] = {xv.x, xv.y, xv.z, xv.w};
  float acc[8] = {0.f, 0.f, 0.f, 0.f, 0.f, 0.f, 0.f, 0.f};
#pragma unroll
  for (int j = 0; j < 4; j++) {
    int k = lane * 4 + j;
#pragma unroll
    for (int t = 0; t < 8; t++) acc[t] = fmaf(xs[j], Cs[k * 8 + t], acc[t]);
  }
#pragma unroll
  for (int off = 32; off >= 1; off >>= 1)
#pragma unroll
    for (int t = 0; t < 8; t++) acc[t] += __shfl_xor(acc[t], off);
  if (lane == 0) {
#pragma unroll
    for (int h = 0; h < HH; h++) {
      o1[(size_t)n * HH + h] = acc[h];
      o2[(size_t)n * HH + h] = acc[4 + h];
    }
  }
}

// ---------------- CSR build ----------------
__global__ __launch_bounds__(256) void hist2(
    const int* __restrict__ d1, const int* __restrict__ d2,
    int* __restrict__ c1, int* __restrict__ c2) {
  int gid = blockIdx.x * 256 + threadIdx.x;
  if (gid < EE) atomicAdd(&c1[d1[gid]], 1);
  else if (gid < 2 * EE) atomicAdd(&c2[d2[gid - EE]], 1);
}

__global__ __launch_bounds__(256) void scan_chunk(
    const int* __restrict__ c1, const int* __restrict__ c2,
    int* __restrict__ rp1, int* __restrict__ rp2, int* __restrict__ bsum) {
  int rel = blockIdx.y;
  const int* counts = rel ? c2 : c1;
  int* rowptr = rel ? rp2 : rp1;
  int* bs = bsum + rel * 128;
  __shared__ int sd[256];
  int tid = threadIdx.x;
  int base = blockIdx.x * 1024 + tid * 4;
  int c[4];
#pragma unroll
  for (int j = 0; j < 4; j++) c[j] = (base + j < NN) ? counts[base + j] : 0;
  int tot = c[0] + c[1] + c[2] + c[3];
  sd[tid] = tot; __syncthreads();
  for (int o = 1; o < 256; o <<= 1) {
    int v = (tid >= o) ? sd[tid - o] : 0;
    __syncthreads();
    sd[tid] += v;
    __syncthreads();
  }
  int excl = sd[tid] - tot;
  int run = excl;
#pragma unroll
  for (int j = 0; j < 4; j++) {
    if (base + j < NN) rowptr[base + j] = run;
    run += c[j];
  }
  if (tid == 255) bs[blockIdx.x] = sd[255];
}

__global__ __launch_bounds__(128) void scan_bsum(int* __restrict__ bsum) {
  int rel = blockIdx.y;
  int* bs = bsum + rel * 128;
  __shared__ int sd[128];
  int tid = threadIdx.x;
  int v = (tid < NB_SCAN) ? bs[tid] : 0;
  sd[tid] = v; __syncthreads();
  for (int o = 1; o < 128; o <<= 1) {
    int t = (tid >= o) ? sd[tid - o] : 0;
    __syncthreads();
    sd[tid] += t;
    __syncthreads();
  }
  bs[tid] = sd[tid] - v;
}

__global__ __launch_bounds__(256) void addoff2(
    int* __restrict__ rp1, int* __restrict__ rp2,
    int* __restrict__ cur1, int* __restrict__ cur2,
    const int* __restrict__ bsum) {
  int rel = blockIdx.y;
  int* rowptr = rel ? rp2 : rp1;
  int* cur = rel ? cur2 : cur1;
  const int* bs = bsum + rel * 128;
  int i = blockIdx.x * 256 + threadIdx.x;
  if (i < NN) {
    int r = rowptr[i] + bs[i >> 10];
    rowptr[i] = r;
    cur[i] = r;
  }
  if (i == 0) rowptr[NN] = EE;
}

// ---------------- fill CSR (store src id directly) + softmax denominators
__global__ __launch_bounds__(256) void fill_s(
    const int* __restrict__ e1s, const int* __restrict__ e1d,
    const int* __restrict__ e2s, const int* __restrict__ e2d,
    const float* __restrict__ el1, const float* __restrict__ er1,
    const float* __restrict__ el2, const float* __restrict__ er2,
    int* __restrict__ cur1, int* __restrict__ cur2,
    float* __restrict__ s1, float* __restrict__ s2,
    int* __restrict__ adj1, int* __restrict__ adj2) {
  int gid = blockIdx.x * 256 + threadIdx.x;
  int rel = (gid >= EE);
  if (gid >= 2 * EE) return;
  int e = rel ? gid - EE : gid;
  const int* srcp = rel ? e2s : e1s;
  const int* dstp = rel ? e2d : e1d;
  const float* el = rel ? el2 : el1;
  const float* er = rel ? er2 : er1;
  int* cur = rel ? cur2 : cur1;
  float* s = rel ? s2 : s1;
  int* adj = rel ? adj2 : adj1;
  int si = srcp[e], di = dstp[e];
  int p = atomicAdd(&cur[di], 1);
  adj[p] = si;
  float4 l = *(const float4*)(el + (size_t)si * HH);
  float4 r = *(const float4*)(er + (size_t)di * HH);
  float v0 = l.x + r.x, v1 = l.y + r.y, v2 = l.z + r.z, v3 = l.w + r.w;
  v0 = v0 > 0.f ? v0 : SLOPE * v0; v1 = v1 > 0.f ? v1 : SLOPE * v1;
  v2 = v2 > 0.f ? v2 : SLOPE * v2; v3 = v3 > 0.f ? v3 : SLOPE * v3;
  atomicAdd(&s[(size_t)di * HH + 0], __expf(v0));
  atomicAdd(&s[(size_t)di * HH + 1], __expf(v1));
  atomicAdd(&s[(size_t)di * HH + 2], __expf(v2));
  atomicAdd(&s[(size_t)di * HH + 3], __expf(v3));
}

// ---------------- MFMA GEMM: C[M x N] = A[M x 256] @ Wt[N x 256]^T
// 1-D grid (rows*ncol blocks), XCD-bijective swizzle, col fastest (A L2 reuse).
template <int ABF>
__global__ __launch_bounds__(256) void mfma_gemm(
    const void* __restrict__ Av, const short* __restrict__ Wt,
    void* __restrict__ Cout, int ldC, int M, int write_bf, int ncol) {
  __shared__ short As[128 * 64];
  __shared__ short Bs[128 * 64];
  int nwg = gridDim.x;
  int q = nwg >> 3, r = nwg & 7;
  int xcd = blockIdx.x & 7, seq = blockIdx.x >> 3;
  int lid = (xcd < r) ? (xcd * (q + 1) + seq) : (r * (q + 1) + (xcd - r) * q + seq);
  int row0 = (lid / ncol) * 128;
  int col0 = (lid % ncol) * 128;

  int tid = threadIdx.x;
  int lane = tid & 63, wid = tid >> 6;
  int wm = wid >> 1, wn = wid & 1;

  f32x4 acc[4][4];
#pragma unroll
  for (int i = 0; i < 4; i++)
#pragma unroll
    for (int j = 0; j < 4; j++) acc[i][j] = (f32x4){0.f, 0.f, 0.f, 0.f};

  int am = tid >> 1;
  int akh = (tid & 1) * 32;
  bool arow_ok = (row0 + am) < M;

  for (int k0 = 0; k0 < KIN; k0 += 64) {
    __syncthreads();
    if (ABF) {
      const short* xp = (const short*)Av + (size_t)(row0 + am) * KIN + k0 + akh;
#pragma unroll
      for (int c = 0; c < 4; c++) {
        bf16x8 pv;
        if (arow_ok) pv = *(const bf16x8*)(xp + c * 8);
        else pv = (bf16x8){0, 0, 0, 0, 0, 0, 0, 0};
        int kc = akh + c * 8;
        int ad = (am * 128 + kc * 2) ^ ((am & 7) << 4);
        *(bf16x8*)((char*)As + ad) = pv;
      }
    } else {
      const float* xp = (const float*)Av + (size_t)(row0 + am) * KIN + k0 + akh;
#pragma unroll
      for (int c = 0; c < 4; c++) {
        float4 v0, v1;
        if (arow_ok) {
          v0 = *(const float4*)(xp + c * 8);
          v1 = *(const float4*)(xp + c * 8 + 4);
        } else {
          v0 = make_float4(0.f, 0.f, 0.f, 0.f);
          v1 = v0;
        }
        bf16x8 pk;
        pk[0] = (short)f2bf(v0.x); pk[1] = (short)f2bf(v0.y);
        pk[2] = (short)f2bf(v0.z); pk[3] = (short)f2bf(v0.w);
        pk[4] = (short)f2bf(v1.x); pk[5] = (short)f2bf(v1.y);
        pk[6] = (short)f2bf(v1.z); pk[7] = (short)f2bf(v1.w);
        int kc = akh + c * 8;
        int ad = (am * 128 + kc * 2) ^ ((am & 7) << 4);
        *(bf16x8*)((char*)As + ad) = pk;
      }
    }
    {
      int bn = tid >> 1;
      int bkh = (tid & 1) * 32;
      const short* wp = Wt + (size_t)(col0 + bn) * KIN + k0 + bkh;
#pragma unroll
      for (int c = 0; c < 4; c++) {
        bf16x8 pv = *(const bf16x8*)(wp + c * 8);
        int kc = bkh + c * 8;
        int bd = (bn * 128 + kc * 2) ^ ((bn & 7) << 4);
        *(bf16x8*)((char*)Bs + bd) = pv;
      }
    }
    __syncthreads();
#pragma unroll
    for (int ks = 0; ks < 2; ks++) {
      int kb = ks * 32 + (lane >> 4) * 8;
      bf16x8 af[4], bfv[4];
#pragma unroll
      for (int mf = 0; mf < 4; mf++) {
        int rr = wm * 64 + mf * 16 + (lane & 15);
        int ad = (rr * 128 + kb * 2) ^ ((rr & 7) << 4);
        af[mf] = *(bf16x8*)((char*)As + ad);
      }
#pragma unroll
      for (int nf = 0; nf < 4; nf++) {
        int cc = wn * 64 + nf * 16 + (lane & 15);
        int bd = (cc * 128 + kb * 2) ^ ((cc & 7) << 4);
        bfv[nf] = *(bf16x8*)((char*)Bs + bd);
      }
#pragma unroll
      for (int mf = 0; mf < 4; mf++)
#pragma unroll
        for (int nf = 0; nf < 4; nf++)
          acc[mf][nf] = __builtin_amdgcn_mfma_f32_16x16x32_bf16(af[mf], bfv[nf], acc[mf][nf], 0, 0, 0);
    }
  }
  int lr = lane >> 4, lc = lane & 15;
#pragma unroll
  for (int mf = 0; mf < 4; mf++) {
#pragma unroll
    for (int r4 = 0; r4 < 4; r4++) {
      int row = row0 + wm * 64 + mf * 16 + lr * 4 + r4;
      if (row < M) {
#pragma unroll
        for (int nf = 0; nf < 4; nf++) {
          int col = col0 + wn * 64 + nf * 16 + lc;
          float v = acc[mf][nf][r4];
          if (write_bf) ((unsigned short*)Cout)[(size_t)row * ldC + col] = f2bf(v);
          else ((float*)Cout)[(size_t)row * ldC + col] = v;
        }
      }
    }
  }
}

// ---------------- single-pass agg + mean + residual + LN + GELU (one wave/dst)
// lane l covers head (l>>4), dims 8*(l&15)..+8 of the fs row (dwordx4 gather).
__global__ __launch_bounds__(256) void agg2(
    const int* __restrict__ rowptr, const int* __restrict__ adj,
    const float* __restrict__ el, const float* __restrict__ er,
    const float* __restrict__ s,
    const unsigned short* __restrict__ fsb,
    const float* __restrict__ bm,
    const float* __restrict__ g, const float* __restrict__ be,
    float* __restrict__ out, int M) {
  int wave = threadIdx.x >> 6, lane = threadIdx.x & 63;
  int n = blockIdx.x * 4 + wave;
  if (n >= M) return;
  int beg = rowptr[n], end = rowptr[n + 1];
  float4 ern = *(const float4*)(er + (size_t)n * HH);
  float4 sv = *(const float4*)(s + (size_t)n * HH);
  float rs0 = sv.x > 0.f ? 0.25f / sv.x : 0.f;
  float rs1 = sv.y > 0.f ? 0.25f / sv.y : 0.f;
  float rs2 = sv.z > 0.f ? 0.25f / sv.z : 0.f;
  float rs3 = sv.w > 0.f ? 0.25f / sv.w : 0.f;
  int lh = lane >> 4, lc = lane & 15;
  float m[8] = {0.f, 0.f, 0.f, 0.f, 0.f, 0.f, 0.f, 0.f};
  for (int t = beg; t < end; t++) {
    int si = adj[t];
    float4 elv = *(const float4*)(el + (size_t)si * HH);
    float v0 = elv.x + ern.x, v1 = elv.y + ern.y, v2 = elv.z + ern.z, v3 = elv.w + ern.w;
    v0 = v0 > 0.f ? v0 : SLOPE * v0; v1 = v1 > 0.f ? v1 : SLOPE * v1;
    v2 = v2 > 0.f ? v2 : SLOPE * v2; v3 = v3 > 0.f ? v3 : SLOPE * v3;
    float a0 = __expf(v0) * rs0, a1 = __expf(v1) * rs1;
    float a2 = __expf(v2) * rs2, a3 = __expf(v3) * rs3;
    float ah = lh == 0 ? a0 : lh == 1 ? a1 : lh == 2 ? a2 : a3;
    uint4 u = *(const uint4*)(fsb + (size_t)si * HD + lane * 8);
    m[0] = fmaf(ah, bf_lo(u.x), m[0]); m[1] = fmaf(ah, bf_hi(u.x), m[1]);
    m[2] = fmaf(ah, bf_lo(u.y), m[2]); m[3] = fmaf(ah, bf_hi(u.y), m[3]);
    m[4] = fmaf(ah, bf_lo(u.z), m[4]); m[5] = fmaf(ah, bf_hi(u.z), m[5]);
    m[6] = fmaf(ah, bf_lo(u.w), m[6]); m[7] = fmaf(ah, bf_hi(u.w), m[7]);
  }
  // head reduce: combine across the 4 lane groups
#pragma unroll
  for (int j = 0; j < 8; j++) {
    m[j] += __shfl_xor(m[j], 16);
    m[j] += __shfl_xor(m[j], 32);
  }
  // c = agg_mean + bm + proj residual (already in out)
  const float4* bmp = (const float4*)(bm + lc * 8);
  float4 b0 = bmp[0], b1 = bmp[1];
  const float4* orow = (const float4*)(out + (size_t)n * DD + lc * 8);
  float4 p0 = orow[0], p1 = orow[1];
  float c[8];
  c[0] = m[0] + b0.x + p0.x; c[1] = m[1] + b0.y + p0.y;
  c[2] = m[2] + b0.z + p0.z; c[3] = m[3] + b0.w + p0.w;
  c[4] = m[4] + b1.x + p1.x; c[5] = m[5] + b1.y + p1.y;
  c[6] = m[6] + b1.z + p1.z; c[7] = m[7] + b1.w + p1.w;
  float ss = c[0] + c[1] + c[2] + c[3] + c[4] + c[5] + c[6] + c[7];
  ss += __shfl_xor(ss, 1); ss += __shfl_xor(ss, 2);
  ss += __shfl_xor(ss, 4); ss += __shfl_xor(ss, 8);
  float mu = ss * (1.f / 128.f);
  float vv = 0.f;
#pragma unroll
  for (int j = 0; j < 8; j++) { float d = c[j] - mu; vv = fmaf(d, d, vv); }
  vv += __shfl_xor(vv, 1); vv += __shfl_xor(vv, 2);
  vv += __shfl_xor(vv, 4); vv += __shfl_xor(vv, 8);
  float inv = rsqrtf(vv * (1.f / 128.f) + LN_EPS);
  const float4* gp = (const float4*)(g + lc * 8);
  const float4* bep = (const float4*)(be + lc * 8);
  float4 g0 = gp[0], g1 = gp[1];
  float4 e0 = bep[0], e1 = bep[1];
  float gv[8] = {g0.x, g0.y, g0.z, g0.w, g1.x, g1.y, g1.z, g1.w};
  float ev[8] = {e0.x, e0.y, e0.z, e0.w, e1.x, e1.y, e1.z, e1.w};
  float o[8];
#pragma unroll
  for (int j = 0; j < 8; j++) {
    float y = (c[j] - mu) * inv * gv[j] + ev[j];
    o[j] = 0.5f * y * (1.f + erff(y * 0.70710678118f));
  }
  if (lane < 16) {
    float4* op = (float4*)(out + (size_t)n * DD + lane * 8);
    op[0] = make_float4(o[0], o[1], o[2], o[3]);
    op[1] = make_float4(o[4], o[5], o[6], o[7]);
  }
}

extern "C" void kernel_launch(void* const* d_in, const int* in_sizes, int n_in,
                              void* d_out, int out_size, void* d_ws, size_t ws_size,
                              hipStream_t stream) {
  const float* feat_host = (const float*)d_in[0];
  const float* feat_flow = (const float*)d_in[1];
  const float* W1  = (const float*)d_in[2];
  const float* al1 = (const float*)d_in[3];
  const float* ar1 = (const float*)d_in[4];
  const float* b1  = (const float*)d_in[5];
  const float* W2  = (const float*)d_in[6];
  const float* al2 = (const float*)d_in[7];
  const float* ar2 = (const float*)d_in[8];
  const float* b2  = (const float*)d_in[9];
  const float* pWh = (const float*)d_in[10];
  const float* pbh = (const float*)d_in[11];
  const float* pWf = (const float*)d_in[12];
  const float* pbf = (const float*)d_in[13];
  const float* gh  = (const float*)d_in[14];
  const float* beh = (const float*)d_in[15];
  const float* gf  = (const float*)d_in[16];
  const float* bef = (const float*)d_in[17];
  const int* e1s = (const int*)d_in[18];
  const int* e1d = (const int*)d_in[19];
  const int* e2s = (const int*)d_in[20];
  const int* e2d = (const int*)d_in[21];

  float* out = (float*)d_out;
  float* host_out = out;                       // [NN,128]
  float* flow_out = out + (size_t)NN * DD;     // [NN,128]

  float* ws = (float*)d_ws;
  size_t off = 0;
  unsigned short* fsb = (unsigned short*)(ws + off); off += (size_t)NN * 256;  // NN x 512 bf16
  short* W1t  = (short*)(ws + off); off += (512 * 256) / 2;
  short* W2t  = (short*)(ws + off); off += (512 * 256) / 2;
  short* pWht = (short*)(ws + off); off += (128 * 256) / 2;
  short* pWft = (short*)(ws + off); off += (128 * 256) / 2;
  float* el1b = ws + off; off += (size_t)NN * HH;
  float* er1b = ws + off; off += (size_t)NN * HH;
  float* el2b = ws + off; off += (size_t)NN * HH;
  float* er2b = ws + off; off += (size_t)NN * HH;
  float* Cbuf = ws + off; off += 4096;
  float* bm   = ws + off; off += 256;          // bm1 | bm2
  // CSR + denominators
  int* rp1  = (int*)(ws + off);      // NN+1
  int* rp2  = rp1 + (NN + 1);
  int* adj1 = rp2 + (NN + 1);        // EE (src ids)
  int* adj2 = adj1 + EE;
  int* bsum = adj2 + EE;             // 256
  int* cur1 = bsum + 256;            // NN   } contiguous memset region:
  int* cur2 = cur1 + NN;             // NN   } cur1,cur2,s1,s2 = 10*NN*4 B
  float* s1 = (float*)(cur2 + NN);   // NN*4
  float* s2 = s1 + (size_t)NN * HH;  // NN*4
  off += (size_t)(2 * (NN + 1) + 2 * EE + 256 + 10 * NN + 4);
  // optional bf16 feature copies
  size_t base_bytes = (off + 1024) * sizeof(float);
  size_t featb_bytes = (size_t)NN * KIN * 2 * 2;
  bool use_featb = ws_size >= base_bytes + featb_bytes;
  short* fhb = nullptr;
  short* ffb = nullptr;
  if (use_featb) {
    fhb = (short*)(ws + off); off += (size_t)NN * KIN / 2;
    ffb = (short*)(ws + off); off += (size_t)NN * KIN / 2;
  }

  dim3 blk(256);
  int gx = (NN + 127) / 128;                 // 782 row tiles
  int pf_g = (NN + 3) / 4;
  int ag_g = (NN + 3) / 4;
  int ee2_g = (2 * EE + 255) / 256;
  int nn_g = (NN + 255) / 256;

  // ---- prep
  convw<<<512, blk, 0, stream>>>(W1, W2, pWh, pWf, W1t, W2t, pWht, pWft);
  make_c<<<dim3(1, 4), blk, 0, stream>>>(W1, al1, ar1, W2, al2, ar2, Cbuf);
  make_bm<<<1, blk, 0, stream>>>(b1, pbf, b2, pbh, bm);
  if (use_featb) {
    prep_feat<<<pf_g, blk, 0, stream>>>(feat_host, Cbuf + 0,    Cbuf + 3072, fhb, el1b, er2b, NN);
    prep_feat<<<pf_g, blk, 0, stream>>>(feat_flow, Cbuf + 1024, Cbuf + 2048, ffb, er1b, el2b, NN);
  } else {
    skinny8<<<pf_g, blk, 0, stream>>>(feat_host, Cbuf + 0,    Cbuf + 3072, el1b, er2b, NN);
    skinny8<<<pf_g, blk, 0, stream>>>(feat_flow, Cbuf + 1024, Cbuf + 2048, er1b, el2b, NN);
  }

  // ---- CSR + softmax denominators
  hipMemsetAsync(cur1, 0, (size_t)10 * NN * sizeof(int), stream);
  hist2<<<ee2_g, blk, 0, stream>>>(e1d, e2d, cur1, cur2);
  scan_chunk<<<dim3(NB_SCAN, 2), blk, 0, stream>>>(cur1, cur2, rp1, rp2, bsum);
  scan_bsum<<<dim3(1, 2), 128, 0, stream>>>(bsum);
  addoff2<<<dim3(nn_g, 2), blk, 0, stream>>>(rp1, rp2, cur1, cur2, bsum);
  fill_s<<<ee2_g, blk, 0, stream>>>(e1s, e1d, e2s, e2d, el1b, er1b, el2b, er2b,
                                    cur1, cur2, s1, s2, adj1, adj2);

  // ---- relation 1: host -> flow (dst = flow, out = flow_out)
  if (use_featb) {
    mfma_gemm<1><<<gx, blk, 0, stream>>>(ffb, pWft, flow_out, DD, NN, 0, 1);
    mfma_gemm<1><<<gx * 4, blk, 0, stream>>>(fhb, W1t, fsb, HD, NN, 1, 4);
  } else {
    mfma_gemm<0><<<gx, blk, 0, stream>>>(feat_flow, pWft, flow_out, DD, NN, 0, 1);
    mfma_gemm<0><<<gx * 4, blk, 0, stream>>>(feat_host, W1t, fsb, HD, NN, 1, 4);
  }
  agg2<<<ag_g, blk, 0, stream>>>(rp1, adj1, el1b, er1b, s1, fsb, bm, gf, bef, flow_out, NN);

  // ---- relation 2: flow -> host (dst = host, out = host_out)
  if (use_featb) {
    mfma_gemm<1><<<gx, blk, 0, stream>>>(fhb, pWht, host_out, DD, NN, 0, 1);
    mfma_gemm<1><<<gx * 4, blk, 0, stream>>>(ffb, W2t, fsb, HD, NN, 1, 4);
  } else {
    mfma_gemm<0><<<gx, blk, 0, stream>>>(feat_host, pWht, host_out, DD, NN, 0, 1);
    mfma_gemm<0><<<gx * 4, blk, 0, stream>>>(feat_flow, W2t, fsb, HD, NN, 1, 4);
  }
  agg2<<<ag_g, blk, 0, stream>>>(rp2, adj2, el2b, er2b, s2, fsb, bm + 128, gh, beh, host_out, NN);
}

// Round 7
// 712.577 us; speedup vs baseline: 2.7672x; 1.0631x over previous
//
#include <hip/hip_runtime.h>
#include <math.h>

#define NN 100000      // nodes per type
#define EE 200000      // edges per relation
#define HH 4
#define DD 128
#define HD 512         // H*D
#define KIN 256        // input feature dim
#define LN_EPS 1e-5f
#define SLOPE 0.2f
#define NB_SCAN 98     // ceil(NN/1024)

typedef short bf16x8 __attribute__((ext_vector_type(8)));
typedef unsigned short u16x4 __attribute__((ext_vector_type(4)));
typedef float f32x4 __attribute__((ext_vector_type(4)));

static __device__ __forceinline__ unsigned short f2bf(float x) {
  unsigned int u = __float_as_uint(x);
  u += 0x7fffu + ((u >> 16) & 1u);   // RNE
  return (unsigned short)(u >> 16);
}
static __device__ __forceinline__ float bf_lo(unsigned int u) {
  return __uint_as_float(u << 16);
}
static __device__ __forceinline__ float bf_hi(unsigned int u) {
  return __uint_as_float(u & 0xffff0000u);
}

// ---------------- convert + transpose weights to bf16 [N][K]
__global__ __launch_bounds__(256) void convw(
    const float* __restrict__ W1, const float* __restrict__ W2,
    const float* __restrict__ pWh, const float* __restrict__ pWf,
    short* __restrict__ W1t, short* __restrict__ W2t,
    short* __restrict__ pWht, short* __restrict__ pWft) {
  int idx = blockIdx.x * 256 + threadIdx.x;
  if (idx < 512 * 256) {
    int n = idx >> 8, k = idx & 255;
    W1t[idx] = (short)f2bf(W1[(size_t)k * HD + n]);
    W2t[idx] = (short)f2bf(W2[(size_t)k * HD + n]);
  }
  if (idx < 128 * 256) {
    int n = idx >> 8, k = idx & 255;
    pWht[idx] = (short)f2bf(pWh[(size_t)k * DD + n]);
    pWft[idx] = (short)f2bf(pWf[(size_t)k * DD + n]);
  }
}

// ---------------- build C[k,h] = sum_d W[k, h*128+d] * a[h*128+d]
__global__ __launch_bounds__(256) void make_c(
    const float* __restrict__ W1, const float* __restrict__ al1, const float* __restrict__ ar1,
    const float* __restrict__ W2, const float* __restrict__ al2, const float* __restrict__ ar2,
    float* __restrict__ Cout) {
  int which = blockIdx.y;
  const float* W = (which < 2) ? W1 : W2;
  const float* a = (which == 0) ? al1 : (which == 1) ? ar1 : (which == 2) ? al2 : ar2;
  int k = threadIdx.x;
  float* C = Cout + (size_t)which * 1024;
#pragma unroll
  for (int h = 0; h < HH; h++) {
    float s = 0.f;
    for (int d = 0; d < DD; d++) s = fmaf(W[(size_t)k * HD + h * DD + d], a[h * DD + d], s);
    C[k * HH + h] = s;
  }
}

// ---------------- bm1[d] = 0.25*sum_h b1 + pbf ; bm2 likewise (b2, pbh)
__global__ __launch_bounds__(256) void make_bm(
    const float* __restrict__ b1, const float* __restrict__ pbf,
    const float* __restrict__ b2, const float* __restrict__ pbh,
    float* __restrict__ bm) {
  int d = threadIdx.x;
  if (d < 128) {
    bm[d] = 0.25f * (b1[d] + b1[128 + d] + b1[256 + d] + b1[384 + d]) + pbf[d];
  } else {
    int dd = d - 128;
    bm[d] = 0.25f * (b2[dd] + b2[128 + dd] + b2[256 + dd] + b2[384 + dd]) + pbh[dd];
  }
}

// ---------------- fused: bf16 convert + el/er skinny dots (one wave per row)
__global__ __launch_bounds__(256) void prep_feat(
    const float* __restrict__ X, const float* __restrict__ C1, const float* __restrict__ C2,
    short* __restrict__ Xb, float* __restrict__ o1, float* __restrict__ o2, int M) {
  __shared__ float Cs[KIN * 8];
  int tid = threadIdx.x;
  for (int i = tid; i < KIN * 4; i += 256) {
    int k = i >> 2, h = i & 3;
    Cs[k * 8 + h] = C1[i];
    Cs[k * 8 + 4 + h] = C2[i];
  }
  __syncthreads();
  int wave = tid >> 6, lane = tid & 63;
  int n = blockIdx.x * 4 + wave;
  if (n >= M) return;
  float4 xv = ((const float4*)(X + (size_t)n * KIN))[lane];
  float xs[4] = {xv.x, xv.y, xv.z, xv.w};
  u16x4 pk;
  pk[0] = f2bf(xs[0]); pk[1] = f2bf(xs[1]); pk[2] = f2bf(xs[2]); pk[3] = f2bf(xs[3]);
  *(u16x4*)(Xb + (size_t)n * KIN + lane * 4) = pk;
  float acc[8] = {0.f, 0.f, 0.f, 0.f, 0.f, 0.f, 0.f, 0.f};
#pragma unroll
  for (int j = 0; j < 4; j++) {
    int k = lane * 4 + j;
#pragma unroll
    for (int t = 0; t < 8; t++) acc[t] = fmaf(xs[j], Cs[k * 8 + t], acc[t]);
  }
#pragma unroll
  for (int off = 32; off >= 1; off >>= 1)
#pragma unroll
    for (int t = 0; t < 8; t++) acc[t] += __shfl_xor(acc[t], off);
  if (lane == 0) {
#pragma unroll
    for (int h = 0; h < HH; h++) {
      o1[(size_t)n * HH + h] = acc[h];
      o2[(size_t)n * HH + h] = acc[4 + h];
    }
  }
}

// ---------------- fallback skinny (no bf16 feature copy)
__global__ __launch_bounds__(256) void skinny8(
    const float* __restrict__ X, const float* __restrict__ C1, const float* __restrict__ C2,
    float* __restrict__ o1, float* __restrict__ o2, int M) {
  __shared__ float Cs[KIN * 8];
  int tid = threadIdx.x;
  for (int i = tid; i < KIN * 4; i += 256) {
    int k = i >> 2, h = i & 3;
    Cs[k * 8 + h] = C1[i];
    Cs[k * 8 + 4 + h] = C2[i];
  }
  __syncthreads();
  int wave = tid >> 6, lane = tid & 63;
  int n = blockIdx.x * 4 + wave;
  if (n >= M) return;
  float4 xv = ((const float4*)(X + (size_t)n * KIN))[lane];
  float xs[4] = {xv.x, xv.y, xv.z, xv.w};
  float acc[8] = {0.f, 0.f, 0.f, 0.f, 0.f, 0.f, 0.f, 0.f};
#pragma unroll
  for (int j = 0; j < 4; j++) {
    int k = lane * 4 + j;
#pragma unroll
    for (int t = 0; t < 8; t++) acc[t] = fmaf(xs[j], Cs[k * 8 + t], acc[t]);
  }
#pragma unroll
  for (int off = 32; off >= 1; off >>= 1)
#pragma unroll
    for (int t = 0; t < 8; t++) acc[t] += __shfl_xor(acc[t], off);
  if (lane == 0) {
#pragma unroll
    for (int h = 0; h < HH; h++) {
      o1[(size_t)n * HH + h] = acc[h];
      o2[(size_t)n * HH + h] = acc[4 + h];
    }
  }
}

// ---------------- CSR build ----------------
__global__ __launch_bounds__(256) void hist2(
    const int* __restrict__ d1, const int* __restrict__ d2,
    int* __restrict__ c1, int* __restrict__ c2) {
  int gid = blockIdx.x * 256 + threadIdx.x;
  if (gid < EE) atomicAdd(&c1[d1[gid]], 1);
  else if (gid < 2 * EE) atomicAdd(&c2[d2[gid - EE]], 1);
}

__global__ __launch_bounds__(256) void scan_chunk(
    const int* __restrict__ c1, const int* __restrict__ c2,
    int* __restrict__ rp1, int* __restrict__ rp2, int* __restrict__ bsum) {
  int rel = blockIdx.y;
  const int* counts = rel ? c2 : c1;
  int* rowptr = rel ? rp2 : rp1;
  int* bs = bsum + rel * 128;
  __shared__ int sd[256];
  int tid = threadIdx.x;
  int base = blockIdx.x * 1024 + tid * 4;
  int c[4];
#pragma unroll
  for (int j = 0; j < 4; j++) c[j] = (base + j < NN) ? counts[base + j] : 0;
  int tot = c[0] + c[1] + c[2] + c[3];
  sd[tid] = tot; __syncthreads();
  for (int o = 1; o < 256; o <<= 1) {
    int v = (tid >= o) ? sd[tid - o] : 0;
    __syncthreads();
    sd[tid] += v;
    __syncthreads();
  }
  int excl = sd[tid] - tot;
  int run = excl;
#pragma unroll
  for (int j = 0; j < 4; j++) {
    if (base + j < NN) rowptr[base + j] = run;
    run += c[j];
  }
  if (tid == 255) bs[blockIdx.x] = sd[255];
}

__global__ __launch_bounds__(128) void scan_bsum(int* __restrict__ bsum) {
  int rel = blockIdx.y;
  int* bs = bsum + rel * 128;
  __shared__ int sd[128];
  int tid = threadIdx.x;
  int v = (tid < NB_SCAN) ? bs[tid] : 0;
  sd[tid] = v; __syncthreads();
  for (int o = 1; o < 128; o <<= 1) {
    int t = (tid >= o) ? sd[tid - o] : 0;
    __syncthreads();
    sd[tid] += t;
    __syncthreads();
  }
  bs[tid] = sd[tid] - v;
}

__global__ __launch_bounds__(256) void addoff2(
    int* __restrict__ rp1, int* __restrict__ rp2,
    int* __restrict__ cur1, int* __restrict__ cur2,
    const int* __restrict__ bsum) {
  int rel = blockIdx.y;
  int* rowptr = rel ? rp2 : rp1;
  int* cur = rel ? cur2 : cur1;
  const int* bs = bsum + rel * 128;
  int i = blockIdx.x * 256 + threadIdx.x;
  if (i < NN) {
    int r = rowptr[i] + bs[i >> 10];
    rowptr[i] = r;
    cur[i] = r;
  }
  if (i == 0) rowptr[NN] = EE;
}

// ---------------- fill CSR (src id + per-edge exp coeffs) + softmax denominators
__global__ __launch_bounds__(256) void fill_s(
    const int* __restrict__ e1s, const int* __restrict__ e1d,
    const int* __restrict__ e2s, const int* __restrict__ e2d,
    const float* __restrict__ el1, const float* __restrict__ er1,
    const float* __restrict__ el2, const float* __restrict__ er2,
    int* __restrict__ cur1, int* __restrict__ cur2,
    float* __restrict__ s1, float* __restrict__ s2,
    int* __restrict__ adj1, int* __restrict__ adj2,
    float* __restrict__ wexp1, float* __restrict__ wexp2) {
  int gid = blockIdx.x * 256 + threadIdx.x;
  int rel = (gid >= EE);
  if (gid >= 2 * EE) return;
  int e = rel ? gid - EE : gid;
  const int* srcp = rel ? e2s : e1s;
  const int* dstp = rel ? e2d : e1d;
  const float* el = rel ? el2 : el1;
  const float* er = rel ? er2 : er1;
  int* cur = rel ? cur2 : cur1;
  float* s = rel ? s2 : s1;
  int* adj = rel ? adj2 : adj1;
  float* wexp = rel ? wexp2 : wexp1;
  int si = srcp[e], di = dstp[e];
  int p = atomicAdd(&cur[di], 1);
  adj[p] = si;
  float4 l = *(const float4*)(el + (size_t)si * HH);
  float4 r = *(const float4*)(er + (size_t)di * HH);
  float v0 = l.x + r.x, v1 = l.y + r.y, v2 = l.z + r.z, v3 = l.w + r.w;
  v0 = v0 > 0.f ? v0 : SLOPE * v0; v1 = v1 > 0.f ? v1 : SLOPE * v1;
  v2 = v2 > 0.f ? v2 : SLOPE * v2; v3 = v3 > 0.f ? v3 : SLOPE * v3;
  float w0 = __expf(v0), w1 = __expf(v1), w2 = __expf(v2), w3 = __expf(v3);
  *(float4*)(wexp + (size_t)p * HH) = make_float4(w0, w1, w2, w3);
  atomicAdd(&s[(size_t)di * HH + 0], w0);
  atomicAdd(&s[(size_t)di * HH + 1], w1);
  atomicAdd(&s[(size_t)di * HH + 2], w2);
  atomicAdd(&s[(size_t)di * HH + 3], w3);
}

// ---------------- MFMA GEMM: C[M x N] = A[M x 256] @ Wt[N x 256]^T
// 1-D grid, XCD-bijective swizzle, col fastest (A L2 reuse).
template <int ABF>
__global__ __launch_bounds__(256) void mfma_gemm(
    const void* __restrict__ Av, const short* __restrict__ Wt,
    void* __restrict__ Cout, int ldC, int M, int write_bf, int ncol) {
  __shared__ short As[128 * 64];
  __shared__ short Bs[128 * 64];
  int nwg = gridDim.x;
  int q = nwg >> 3, r = nwg & 7;
  int xcd = blockIdx.x & 7, seq = blockIdx.x >> 3;
  int lid = (xcd < r) ? (xcd * (q + 1) + seq) : (r * (q + 1) + (xcd - r) * q + seq);
  int row0 = (lid / ncol) * 128;
  int col0 = (lid % ncol) * 128;

  int tid = threadIdx.x;
  int lane = tid & 63, wid = tid >> 6;
  int wm = wid >> 1, wn = wid & 1;

  f32x4 acc[4][4];
#pragma unroll
  for (int i = 0; i < 4; i++)
#pragma unroll
    for (int j = 0; j < 4; j++) acc[i][j] = (f32x4){0.f, 0.f, 0.f, 0.f};

  int am = tid >> 1;
  int akh = (tid & 1) * 32;
  bool arow_ok = (row0 + am) < M;

  for (int k0 = 0; k0 < KIN; k0 += 64) {
    __syncthreads();
    if (ABF) {
      const short* xp = (const short*)Av + (size_t)(row0 + am) * KIN + k0 + akh;
#pragma unroll
      for (int c = 0; c < 4; c++) {
        bf16x8 pv;
        if (arow_ok) pv = *(const bf16x8*)(xp + c * 8);
        else pv = (bf16x8){0, 0, 0, 0, 0, 0, 0, 0};
        int kc = akh + c * 8;
        int ad = (am * 128 + kc * 2) ^ ((am & 7) << 4);
        *(bf16x8*)((char*)As + ad) = pv;
      }
    } else {
      const float* xp = (const float*)Av + (size_t)(row0 + am) * KIN + k0 + akh;
#pragma unroll
      for (int c = 0; c < 4; c++) {
        float4 v0, v1;
        if (arow_ok) {
          v0 = *(const float4*)(xp + c * 8);
          v1 = *(const float4*)(xp + c * 8 + 4);
        } else {
          v0 = make_float4(0.f, 0.f, 0.f, 0.f);
          v1 = v0;
        }
        bf16x8 pk;
        pk[0] = (short)f2bf(v0.x); pk[1] = (short)f2bf(v0.y);
        pk[2] = (short)f2bf(v0.z); pk[3] = (short)f2bf(v0.w);
        pk[4] = (short)f2bf(v1.x); pk[5] = (short)f2bf(v1.y);
        pk[6] = (short)f2bf(v1.z); pk[7] = (short)f2bf(v1.w);
        int kc = akh + c * 8;
        int ad = (am * 128 + kc * 2) ^ ((am & 7) << 4);
        *(bf16x8*)((char*)As + ad) = pk;
      }
    }
    {
      int bn = tid >> 1;
      int bkh = (tid & 1) * 32;
      const short* wp = Wt + (size_t)(col0 + bn) * KIN + k0 + bkh;
#pragma unroll
      for (int c = 0; c < 4; c++) {
        bf16x8 pv = *(const bf16x8*)(wp + c * 8);
        int kc = bkh + c * 8;
        int bd = (bn * 128 + kc * 2) ^ ((bn & 7) << 4);
        *(bf16x8*)((char*)Bs + bd) = pv;
      }
    }
    __syncthreads();
#pragma unroll
    for (int ks = 0; ks < 2; ks++) {
      int kb = ks * 32 + (lane >> 4) * 8;
      bf16x8 af[4], bfv[4];
#pragma unroll
      for (int mf = 0; mf < 4; mf++) {
        int rr = wm * 64 + mf * 16 + (lane & 15);
        int ad = (rr * 128 + kb * 2) ^ ((rr & 7) << 4);
        af[mf] = *(bf16x8*)((char*)As + ad);
      }
#pragma unroll
      for (int nf = 0; nf < 4; nf++) {
        int cc = wn * 64 + nf * 16 + (lane & 15);
        int bd = (cc * 128 + kb * 2) ^ ((cc & 7) << 4);
        bfv[nf] = *(bf16x8*)((char*)Bs + bd);
      }
#pragma unroll
      for (int mf = 0; mf < 4; mf++)
#pragma unroll
        for (int nf = 0; nf < 4; nf++)
          acc[mf][nf] = __builtin_amdgcn_mfma_f32_16x16x32_bf16(af[mf], bfv[nf], acc[mf][nf], 0, 0, 0);
    }
  }
  int lr = lane >> 4, lc = lane & 15;
#pragma unroll
  for (int mf = 0; mf < 4; mf++) {
#pragma unroll
    for (int r4 = 0; r4 < 4; r4++) {
      int row = row0 + wm * 64 + mf * 16 + lr * 4 + r4;
      if (row < M) {
#pragma unroll
        for (int nf = 0; nf < 4; nf++) {
          int col = col0 + wn * 64 + nf * 16 + lc;
          float v = acc[mf][nf][r4];
          if (write_bf) ((unsigned short*)Cout)[(size_t)row * ldC + col] = f2bf(v);
          else ((float*)Cout)[(size_t)row * ldC + col] = v;
        }
      }
    }
  }
}

// ---------------- single-pass agg + mean + residual + LN + GELU (one wave/dst)
// lane l: head (l>>4), dims 8*(l&15)..+8. Coeffs precomputed (wexp), no exp here.
__global__ __launch_bounds__(256) void agg2(
    const int* __restrict__ rowptr, const int* __restrict__ adj,
    const float* __restrict__ wexp, const float* __restrict__ s,
    const unsigned short* __restrict__ fsb,
    const float* __restrict__ bm,
    const float* __restrict__ g, const float* __restrict__ be,
    float* __restrict__ out, int M) {
  int wave = threadIdx.x >> 6, lane = threadIdx.x & 63;
  int n = blockIdx.x * 4 + wave;
  if (n >= M) return;
  int beg = rowptr[n], end = rowptr[n + 1];
  int lh = lane >> 4, lc = lane & 15;
  float sh = s[(size_t)n * HH + lh];
  float rsh = sh > 0.f ? 0.25f / sh : 0.f;
  float m[8] = {0.f, 0.f, 0.f, 0.f, 0.f, 0.f, 0.f, 0.f};
  for (int t = beg; t < end; t++) {
    int si = adj[t];
    float ah = wexp[(size_t)t * HH + lh] * rsh;
    uint4 u = *(const uint4*)(fsb + (size_t)si * HD + lane * 8);
    m[0] = fmaf(ah, bf_lo(u.x), m[0]); m[1] = fmaf(ah, bf_hi(u.x), m[1]);
    m[2] = fmaf(ah, bf_lo(u.y), m[2]); m[3] = fmaf(ah, bf_hi(u.y), m[3]);
    m[4] = fmaf(ah, bf_lo(u.z), m[4]); m[5] = fmaf(ah, bf_hi(u.z), m[5]);
    m[6] = fmaf(ah, bf_lo(u.w), m[6]); m[7] = fmaf(ah, bf_hi(u.w), m[7]);
  }
  // head reduce across the 4 lane groups
#pragma unroll
  for (int j = 0; j < 8; j++) {
    m[j] += __shfl_xor(m[j], 16);
    m[j] += __shfl_xor(m[j], 32);
  }
  const float4* bmp = (const float4*)(bm + lc * 8);
  float4 b0 = bmp[0], b1 = bmp[1];
  const float4* orow = (const float4*)(out + (size_t)n * DD + lc * 8);
  float4 p0 = orow[0], p1 = orow[1];
  float c[8];
  c[0] = m[0] + b0.x + p0.x; c[1] = m[1] + b0.y + p0.y;
  c[2] = m[2] + b0.z + p0.z; c[3] = m[3] + b0.w + p0.w;
  c[4] = m[4] + b1.x + p1.x; c[5] = m[5] + b1.y + p1.y;
  c[6] = m[6] + b1.z + p1.z; c[7] = m[7] + b1.w + p1.w;
  float ss = c[0] + c[1] + c[2] + c[3] + c[4] + c[5] + c[6] + c[7];
  ss += __shfl_xor(ss, 1); ss += __shfl_xor(ss, 2);
  ss += __shfl_xor(ss, 4); ss += __shfl_xor(ss, 8);
  float mu = ss * (1.f / 128.f);
  float vv = 0.f;
#pragma unroll
  for (int j = 0; j < 8; j++) { float d = c[j] - mu; vv = fmaf(d, d, vv); }
  vv += __shfl_xor(vv, 1); vv += __shfl_xor(vv, 2);
  vv += __shfl_xor(vv, 4); vv += __shfl_xor(vv, 8);
  float inv = rsqrtf(vv * (1.f / 128.f) + LN_EPS);
  const float4* gp = (const float4*)(g + lc * 8);
  const float4* bep = (const float4*)(be + lc * 8);
  float4 g0 = gp[0], g1 = gp[1];
  float4 e0 = bep[0], e1 = bep[1];
  float gv[8] = {g0.x, g0.y, g0.z, g0.w, g1.x, g1.y, g1.z, g1.w};
  float ev[8] = {e0.x, e0.y, e0.z, e0.w, e1.x, e1.y, e1.z, e1.w};
  float o[8];
#pragma unroll
  for (int j = 0; j < 8; j++) {
    float y = (c[j] - mu) * inv * gv[j] + ev[j];
    o[j] = 0.5f * y * (1.f + erff(y * 0.70710678118f));
  }
  if (lane < 16) {
    float4* op = (float4*)(out + (size_t)n * DD + lane * 8);
    op[0] = make_float4(o[0], o[1], o[2], o[3]);
    op[1] = make_float4(o[4], o[5], o[6], o[7]);
  }
}

extern "C" void kernel_launch(void* const* d_in, const int* in_sizes, int n_in,
                              void* d_out, int out_size, void* d_ws, size_t ws_size,
                              hipStream_t stream) {
  const float* feat_host = (const float*)d_in[0];
  const float* feat_flow = (const float*)d_in[1];
  const float* W1  = (const float*)d_in[2];
  const float* al1 = (const float*)d_in[3];
  const float* ar1 = (const float*)d_in[4];
  const float* b1  = (const float*)d_in[5];
  const float* W2  = (const float*)d_in[6];
  const float* al2 = (const float*)d_in[7];
  const float* ar2 = (const float*)d_in[8];
  const float* b2  = (const float*)d_in[9];
  const float* pWh = (const float*)d_in[10];
  const float* pbh = (const float*)d_in[11];
  const float* pWf = (const float*)d_in[12];
  const float* pbf = (const float*)d_in[13];
  const float* gh  = (const float*)d_in[14];
  const float* beh = (const float*)d_in[15];
  const float* gf  = (const float*)d_in[16];
  const float* bef = (const float*)d_in[17];
  const int* e1s = (const int*)d_in[18];
  const int* e1d = (const int*)d_in[19];
  const int* e2s = (const int*)d_in[20];
  const int* e2d = (const int*)d_in[21];

  float* out = (float*)d_out;
  float* host_out = out;                       // [NN,128]
  float* flow_out = out + (size_t)NN * DD;     // [NN,128]

  float* ws = (float*)d_ws;
  size_t off = 0;
  unsigned short* fsb = (unsigned short*)(ws + off); off += (size_t)NN * 256;  // NN x 512 bf16
  short* W1t  = (short*)(ws + off); off += (512 * 256) / 2;
  short* W2t  = (short*)(ws + off); off += (512 * 256) / 2;
  short* pWht = (short*)(ws + off); off += (128 * 256) / 2;
  short* pWft = (short*)(ws + off); off += (128 * 256) / 2;
  float* el1b = ws + off; off += (size_t)NN * HH;
  float* er1b = ws + off; off += (size_t)NN * HH;
  float* el2b = ws + off; off += (size_t)NN * HH;
  float* er2b = ws + off; off += (size_t)NN * HH;
  float* Cbuf = ws + off; off += 4096;
  float* bm   = ws + off; off += 256;          // bm1 | bm2
  float* wexp1 = ws + off; off += (size_t)EE * HH;   // per-slot exp coeffs
  float* wexp2 = ws + off; off += (size_t)EE * HH;
  // CSR + denominators
  int* rp1  = (int*)(ws + off);      // NN+1
  int* rp2  = rp1 + (NN + 1);
  int* adj1 = rp2 + (NN + 1);        // EE (src ids)
  int* adj2 = adj1 + EE;
  int* bsum = adj2 + EE;             // 256
  int* cur1 = bsum + 256;            // NN   } contiguous memset region:
  int* cur2 = cur1 + NN;             // NN   } cur1,cur2,s1,s2 = 10*NN*4 B
  float* s1 = (float*)(cur2 + NN);   // NN*4
  float* s2 = s1 + (size_t)NN * HH;  // NN*4
  off += (size_t)(2 * (NN + 1) + 2 * EE + 256 + 10 * NN + 4);
  // optional bf16 feature copies
  size_t base_bytes = (off + 1024) * sizeof(float);
  size_t featb_bytes = (size_t)NN * KIN * 2 * 2;
  bool use_featb = ws_size >= base_bytes + featb_bytes;
  short* fhb = nullptr;
  short* ffb = nullptr;
  if (use_featb) {
    fhb = (short*)(ws + off); off += (size_t)NN * KIN / 2;
    ffb = (short*)(ws + off); off += (size_t)NN * KIN / 2;
  }

  dim3 blk(256);
  int gx = (NN + 127) / 128;                 // 782 row tiles
  int pf_g = (NN + 3) / 4;
  int ag_g = (NN + 3) / 4;
  int ee2_g = (2 * EE + 255) / 256;
  int nn_g = (NN + 255) / 256;

  // ---- prep
  convw<<<512, blk, 0, stream>>>(W1, W2, pWh, pWf, W1t, W2t, pWht, pWft);
  make_c<<<dim3(1, 4), blk, 0, stream>>>(W1, al1, ar1, W2, al2, ar2, Cbuf);
  make_bm<<<1, blk, 0, stream>>>(b1, pbf, b2, pbh, bm);
  if (use_featb) {
    prep_feat<<<pf_g, blk, 0, stream>>>(feat_host, Cbuf + 0,    Cbuf + 3072, fhb, el1b, er2b, NN);
    prep_feat<<<pf_g, blk, 0, stream>>>(feat_flow, Cbuf + 1024, Cbuf + 2048, ffb, er1b, el2b, NN);
  } else {
    skinny8<<<pf_g, blk, 0, stream>>>(feat_host, Cbuf + 0,    Cbuf + 3072, el1b, er2b, NN);
    skinny8<<<pf_g, blk, 0, stream>>>(feat_flow, Cbuf + 1024, Cbuf + 2048, er1b, el2b, NN);
  }

  // ---- CSR + coeffs + softmax denominators
  hipMemsetAsync(cur1, 0, (size_t)10 * NN * sizeof(int), stream);
  hist2<<<ee2_g, blk, 0, stream>>>(e1d, e2d, cur1, cur2);
  scan_chunk<<<dim3(NB_SCAN, 2), blk, 0, stream>>>(cur1, cur2, rp1, rp2, bsum);
  scan_bsum<<<dim3(1, 2), 128, 0, stream>>>(bsum);
  addoff2<<<dim3(nn_g, 2), blk, 0, stream>>>(rp1, rp2, cur1, cur2, bsum);
  fill_s<<<ee2_g, blk, 0, stream>>>(e1s, e1d, e2s, e2d, el1b, er1b, el2b, er2b,
                                    cur1, cur2, s1, s2, adj1, adj2, wexp1, wexp2);

  // ---- relation 1: host -> flow (dst = flow, out = flow_out)
  if (use_featb) {
    mfma_gemm<1><<<gx, blk, 0, stream>>>(ffb, pWft, flow_out, DD, NN, 0, 1);
    mfma_gemm<1><<<gx * 4, blk, 0, stream>>>(fhb, W1t, fsb, HD, NN, 1, 4);
  } else {
    mfma_gemm<0><<<gx, blk, 0, stream>>>(feat_flow, pWft, flow_out, DD, NN, 0, 1);
    mfma_gemm<0><<<gx * 4, blk, 0, stream>>>(feat_host, W1t, fsb, HD, NN, 1, 4);
  }
  agg2<<<ag_g, blk, 0, stream>>>(rp1, adj1, wexp1, s1, fsb, bm, gf, bef, flow_out, NN);

  // ---- relation 2: flow -> host (dst = host, out = host_out)
  if (use_featb) {
    mfma_gemm<1><<<gx, blk, 0, stream>>>(fhb, pWht, host_out, DD, NN, 0, 1);
    mfma_gemm<1><<<gx * 4, blk, 0, stream>>>(ffb, W2t, fsb, HD, NN, 1, 4);
  } else {
    mfma_gemm<0><<<gx, blk, 0, stream>>>(feat_host, pWht, host_out, DD, NN, 0, 1);
    mfma_gemm<0><<<gx * 4, blk, 0, stream>>>(feat_flow, W2t, fsb, HD, NN, 1, 4);
  }
  agg2<<<ag_g, blk, 0, stream>>>(rp2, adj2, wexp2, s2, fsb, bm + 128, gh, beh, host_out, NN);
}

// Round 8
// 661.312 us; speedup vs baseline: 2.9817x; 1.0775x over previous
//
#include <hip/hip_runtime.h>
#include <math.h>

#define NN 100000      // nodes per type
#define EE 200000      // edges per relation
#define HH 4
#define DD 128
#define HD 512         // H*D
#define KIN 256        // input feature dim
#define LN_EPS 1e-5f
#define SLOPE 0.2f
#define NB_SCAN 98     // ceil(NN/1024)

// LDS bank-conflict swizzle for the Cs[2048] table: XOR low-5 addr bits with
// bits [9:5] (== lane id at read time). Bijective; read becomes 2-way = free.
#define CSW(a) ((a) ^ (((a) >> 5) & 31))

typedef short bf16x8 __attribute__((ext_vector_type(8)));
typedef unsigned short u16x4 __attribute__((ext_vector_type(4)));
typedef float f32x4 __attribute__((ext_vector_type(4)));

static __device__ __forceinline__ unsigned short f2bf(float x) {
  unsigned int u = __float_as_uint(x);
  u += 0x7fffu + ((u >> 16) & 1u);   // RNE
  return (unsigned short)(u >> 16);
}
static __device__ __forceinline__ float bf_lo(unsigned int u) {
  return __uint_as_float(u << 16);
}
static __device__ __forceinline__ float bf_hi(unsigned int u) {
  return __uint_as_float(u & 0xffff0000u);
}

// ---------------- convert + transpose weights to bf16 [N][K]
__global__ __launch_bounds__(256) void convw(
    const float* __restrict__ W1, const float* __restrict__ W2,
    const float* __restrict__ pWh, const float* __restrict__ pWf,
    short* __restrict__ W1t, short* __restrict__ W2t,
    short* __restrict__ pWht, short* __restrict__ pWft) {
  int idx = blockIdx.x * 256 + threadIdx.x;
  if (idx < 512 * 256) {
    int n = idx >> 8, k = idx & 255;
    W1t[idx] = (short)f2bf(W1[(size_t)k * HD + n]);
    W2t[idx] = (short)f2bf(W2[(size_t)k * HD + n]);
  }
  if (idx < 128 * 256) {
    int n = idx >> 8, k = idx & 255;
    pWht[idx] = (short)f2bf(pWh[(size_t)k * DD + n]);
    pWft[idx] = (short)f2bf(pWf[(size_t)k * DD + n]);
  }
}

// ---------------- build C[k,h] = sum_d W[k, h*128+d] * a[h*128+d]
__global__ __launch_bounds__(256) void make_c(
    const float* __restrict__ W1, const float* __restrict__ al1, const float* __restrict__ ar1,
    const float* __restrict__ W2, const float* __restrict__ al2, const float* __restrict__ ar2,
    float* __restrict__ Cout) {
  int which = blockIdx.y;
  const float* W = (which < 2) ? W1 : W2;
  const float* a = (which == 0) ? al1 : (which == 1) ? ar1 : (which == 2) ? al2 : ar2;
  int k = threadIdx.x;
  float* C = Cout + (size_t)which * 1024;
#pragma unroll
  for (int h = 0; h < HH; h++) {
    float s = 0.f;
    for (int d = 0; d < DD; d++) s = fmaf(W[(size_t)k * HD + h * DD + d], a[h * DD + d], s);
    C[k * HH + h] = s;
  }
}

// ---------------- bm1[d] = 0.25*sum_h b1 + pbf ; bm2 likewise (b2, pbh)
__global__ __launch_bounds__(256) void make_bm(
    const float* __restrict__ b1, const float* __restrict__ pbf,
    const float* __restrict__ b2, const float* __restrict__ pbh,
    float* __restrict__ bm) {
  int d = threadIdx.x;
  if (d < 128) {
    bm[d] = 0.25f * (b1[d] + b1[128 + d] + b1[256 + d] + b1[384 + d]) + pbf[d];
  } else {
    int dd = d - 128;
    bm[d] = 0.25f * (b2[dd] + b2[128 + dd] + b2[256 + dd] + b2[384 + dd]) + pbh[dd];
  }
}

// ---------------- fused: bf16 convert + el/er skinny dots (one wave per row)
__global__ __launch_bounds__(256) void prep_feat(
    const float* __restrict__ X, const float* __restrict__ C1, const float* __restrict__ C2,
    short* __restrict__ Xb, float* __restrict__ o1, float* __restrict__ o2, int M) {
  __shared__ float Cs[KIN * 8];
  int tid = threadIdx.x;
  for (int i = tid; i < KIN * 4; i += 256) {
    int k = i >> 2, h = i & 3;
    Cs[CSW(k * 8 + h)] = C1[i];
    Cs[CSW(k * 8 + 4 + h)] = C2[i];
  }
  __syncthreads();
  int wave = tid >> 6, lane = tid & 63;
  int n = blockIdx.x * 4 + wave;
  if (n >= M) return;
  float4 xv = ((const float4*)(X + (size_t)n * KIN))[lane];
  float xs[4] = {xv.x, xv.y, xv.z, xv.w};
  u16x4 pk;
  pk[0] = f2bf(xs[0]); pk[1] = f2bf(xs[1]); pk[2] = f2bf(xs[2]); pk[3] = f2bf(xs[3]);
  *(u16x4*)(Xb + (size_t)n * KIN + lane * 4) = pk;
  float acc[8] = {0.f, 0.f, 0.f, 0.f, 0.f, 0.f, 0.f, 0.f};
#pragma unroll
  for (int j = 0; j < 4; j++) {
    int k = lane * 4 + j;
#pragma unroll
    for (int t = 0; t < 8; t++) acc[t] = fmaf(xs[j], Cs[CSW(k * 8 + t)], acc[t]);
  }
#pragma unroll
  for (int off = 32; off >= 1; off >>= 1)
#pragma unroll
    for (int t = 0; t < 8; t++) acc[t] += __shfl_xor(acc[t], off);
  if (lane == 0) {
#pragma unroll
    for (int h = 0; h < HH; h++) {
      o1[(size_t)n * HH + h] = acc[h];
      o2[(size_t)n * HH + h] = acc[4 + h];
    }
  }
}

// ---------------- fallback skinny (no bf16 feature copy)
__global__ __launch_bounds__(256) void skinny8(
    const float* __restrict__ X, const float* __restrict__ C1, const float* __restrict__ C2,
    float* __restrict__ o1, float* __restrict__ o2, int M) {
  __shared__ float Cs[KIN * 8];
  int tid = threadIdx.x;
  for (int i = tid; i < KIN * 4; i += 256) {
    int k = i >> 2, h = i & 3;
    Cs[CSW(k * 8 + h)] = C1[i];
    Cs[CSW(k * 8 + 4 + h)] = C2[i];
  }
  __syncthreads();
  int wave = tid >> 6, lane = tid & 63;
  int n = blockIdx.x * 4 + wave;
  if (n >= M) return;
  float4 xv = ((const float4*)(X + (size_t)n * KIN))[lane];
  float xs[4] = {xv.x, xv.y, xv.z, xv.w};
  float acc[8] = {0.f, 0.f, 0.f, 0.f, 0.f, 0.f, 0.f, 0.f};
#pragma unroll
  for (int j = 0; j < 4; j++) {
    int k = lane * 4 + j;
#pragma unroll
    for (int t = 0; t < 8; t++) acc[t] = fmaf(xs[j], Cs[CSW(k * 8 + t)], acc[t]);
  }
#pragma unroll
  for (int off = 32; off >= 1; off >>= 1)
#pragma unroll
    for (int t = 0; t < 8; t++) acc[t] += __shfl_xor(acc[t], off);
  if (lane == 0) {
#pragma unroll
    for (int h = 0; h < HH; h++) {
      o1[(size_t)n * HH + h] = acc[h];
      o2[(size_t)n * HH + h] = acc[4 + h];
    }
  }
}

// ---------------- CSR build ----------------
__global__ __launch_bounds__(256) void hist2(
    const int* __restrict__ d1, const int* __restrict__ d2,
    int* __restrict__ c1, int* __restrict__ c2) {
  int gid = blockIdx.x * 256 + threadIdx.x;
  if (gid < EE) atomicAdd(&c1[d1[gid]], 1);
  else if (gid < 2 * EE) atomicAdd(&c2[d2[gid - EE]], 1);
}

__global__ __launch_bounds__(256) void scan_chunk(
    const int* __restrict__ c1, const int* __restrict__ c2,
    int* __restrict__ rp1, int* __restrict__ rp2, int* __restrict__ bsum) {
  int rel = blockIdx.y;
  const int* counts = rel ? c2 : c1;
  int* rowptr = rel ? rp2 : rp1;
  int* bs = bsum + rel * 128;
  __shared__ int sd[256];
  int tid = threadIdx.x;
  int base = blockIdx.x * 1024 + tid * 4;
  int c[4];
#pragma unroll
  for (int j = 0; j < 4; j++) c[j] = (base + j < NN) ? counts[base + j] : 0;
  int tot = c[0] + c[1] + c[2] + c[3];
  sd[tid] = tot; __syncthreads();
  for (int o = 1; o < 256; o <<= 1) {
    int v = (tid >= o) ? sd[tid - o] : 0;
    __syncthreads();
    sd[tid] += v;
    __syncthreads();
  }
  int excl = sd[tid] - tot;
  int run = excl;
#pragma unroll
  for (int j = 0; j < 4; j++) {
    if (base + j < NN) rowptr[base + j] = run;
    run += c[j];
  }
  if (tid == 255) bs[blockIdx.x] = sd[255];
}

__global__ __launch_bounds__(128) void scan_bsum(int* __restrict__ bsum) {
  int rel = blockIdx.y;
  int* bs = bsum + rel * 128;
  __shared__ int sd[128];
  int tid = threadIdx.x;
  int v = (tid < NB_SCAN) ? bs[tid] : 0;
  sd[tid] = v; __syncthreads();
  for (int o = 1; o < 128; o <<= 1) {
    int t = (tid >= o) ? sd[tid - o] : 0;
    __syncthreads();
    sd[tid] += t;
    __syncthreads();
  }
  bs[tid] = sd[tid] - v;
}

__global__ __launch_bounds__(256) void addoff2(
    int* __restrict__ rp1, int* __restrict__ rp2,
    int* __restrict__ cur1, int* __restrict__ cur2,
    const int* __restrict__ bsum) {
  int rel = blockIdx.y;
  int* rowptr = rel ? rp2 : rp1;
  int* cur = rel ? cur2 : cur1;
  const int* bs = bsum + rel * 128;
  int i = blockIdx.x * 256 + threadIdx.x;
  if (i < NN) {
    int r = rowptr[i] + bs[i >> 10];
    rowptr[i] = r;
    cur[i] = r;
  }
  if (i == 0) rowptr[NN] = EE;
}

// ---------------- fill CSR (src id + per-edge exp coeffs) + softmax denominators
__global__ __launch_bounds__(256) void fill_s(
    const int* __restrict__ e1s, const int* __restrict__ e1d,
    const int* __restrict__ e2s, const int* __restrict__ e2d,
    const float* __restrict__ el1, const float* __restrict__ er1,
    const float* __restrict__ el2, const float* __restrict__ er2,
    int* __restrict__ cur1, int* __restrict__ cur2,
    float* __restrict__ s1, float* __restrict__ s2,
    int* __restrict__ adj1, int* __restrict__ adj2,
    float* __restrict__ wexp1, float* __restrict__ wexp2) {
  int gid = blockIdx.x * 256 + threadIdx.x;
  int rel = (gid >= EE);
  if (gid >= 2 * EE) return;
  int e = rel ? gid - EE : gid;
  const int* srcp = rel ? e2s : e1s;
  const int* dstp = rel ? e2d : e1d;
  const float* el = rel ? el2 : el1;
  const float* er = rel ? er2 : er1;
  int* cur = rel ? cur2 : cur1;
  float* s = rel ? s2 : s1;
  int* adj = rel ? adj2 : adj1;
  float* wexp = rel ? wexp2 : wexp1;
  int si = srcp[e], di = dstp[e];
  int p = atomicAdd(&cur[di], 1);
  adj[p] = si;
  float4 l = *(const float4*)(el + (size_t)si * HH);
  float4 r = *(const float4*)(er + (size_t)di * HH);
  float v0 = l.x + r.x, v1 = l.y + r.y, v2 = l.z + r.z, v3 = l.w + r.w;
  v0 = v0 > 0.f ? v0 : SLOPE * v0; v1 = v1 > 0.f ? v1 : SLOPE * v1;
  v2 = v2 > 0.f ? v2 : SLOPE * v2; v3 = v3 > 0.f ? v3 : SLOPE * v3;
  float w0 = __expf(v0), w1 = __expf(v1), w2 = __expf(v2), w3 = __expf(v3);
  *(float4*)(wexp + (size_t)p * HH) = make_float4(w0, w1, w2, w3);
  atomicAdd(&s[(size_t)di * HH + 0], w0);
  atomicAdd(&s[(size_t)di * HH + 1], w1);
  atomicAdd(&s[(size_t)di * HH + 2], w2);
  atomicAdd(&s[(size_t)di * HH + 3], w3);
}

// ---------------- MFMA GEMM: C[M x N] = A[M x 256] @ Wt[N x 256]^T
// 1-D grid, XCD-bijective swizzle, col fastest (A L2 reuse).
template <int ABF>
__global__ __launch_bounds__(256) void mfma_gemm(
    const void* __restrict__ Av, const short* __restrict__ Wt,
    void* __restrict__ Cout, int ldC, int M, int write_bf, int ncol) {
  __shared__ short As[128 * 64];
  __shared__ short Bs[128 * 64];
  int nwg = gridDim.x;
  int q = nwg >> 3, r = nwg & 7;
  int xcd = blockIdx.x & 7, seq = blockIdx.x >> 3;
  int lid = (xcd < r) ? (xcd * (q + 1) + seq) : (r * (q + 1) + (xcd - r) * q + seq);
  int row0 = (lid / ncol) * 128;
  int col0 = (lid % ncol) * 128;

  int tid = threadIdx.x;
  int lane = tid & 63, wid = tid >> 6;
  int wm = wid >> 1, wn = wid & 1;

  f32x4 acc[4][4];
#pragma unroll
  for (int i = 0; i < 4; i++)
#pragma unroll
    for (int j = 0; j < 4; j++) acc[i][j] = (f32x4){0.f, 0.f, 0.f, 0.f};

  int am = tid >> 1;
  int akh = (tid & 1) * 32;
  bool arow_ok = (row0 + am) < M;

  for (int k0 = 0; k0 < KIN; k0 += 64) {
    __syncthreads();
    if (ABF) {
      const short* xp = (const short*)Av + (size_t)(row0 + am) * KIN + k0 + akh;
#pragma unroll
      for (int c = 0; c < 4; c++) {
        bf16x8 pv;
        if (arow_ok) pv = *(const bf16x8*)(xp + c * 8);
        else pv = (bf16x8){0, 0, 0, 0, 0, 0, 0, 0};
        int kc = akh + c * 8;
        int ad = (am * 128 + kc * 2) ^ ((am & 7) << 4);
        *(bf16x8*)((char*)As + ad) = pv;
      }
    } else {
      const float* xp = (const float*)Av + (size_t)(row0 + am) * KIN + k0 + akh;
#pragma unroll
      for (int c = 0; c < 4; c++) {
        float4 v0, v1;
        if (arow_ok) {
          v0 = *(const float4*)(xp + c * 8);
          v1 = *(const float4*)(xp + c * 8 + 4);
        } else {
          v0 = make_float4(0.f, 0.f, 0.f, 0.f);
          v1 = v0;
        }
        bf16x8 pk;
        pk[0] = (short)f2bf(v0.x); pk[1] = (short)f2bf(v0.y);
        pk[2] = (short)f2bf(v0.z); pk[3] = (short)f2bf(v0.w);
        pk[4] = (short)f2bf(v1.x); pk[5] = (short)f2bf(v1.y);
        pk[6] = (short)f2bf(v1.z); pk[7] = (short)f2bf(v1.w);
        int kc = akh + c * 8;
        int ad = (am * 128 + kc * 2) ^ ((am & 7) << 4);
        *(bf16x8*)((char*)As + ad) = pk;
      }
    }
    {
      int bn = tid >> 1;
      int bkh = (tid & 1) * 32;
      const short* wp = Wt + (size_t)(col0 + bn) * KIN + k0 + bkh;
#pragma unroll
      for (int c = 0; c < 4; c++) {
        bf16x8 pv = *(const bf16x8*)(wp + c * 8);
        int kc = bkh + c * 8;
        int bd = (bn * 128 + kc * 2) ^ ((bn & 7) << 4);
        *(bf16x8*)((char*)Bs + bd) = pv;
      }
    }
    __syncthreads();
#pragma unroll
    for (int ks = 0; ks < 2; ks++) {
      int kb = ks * 32 + (lane >> 4) * 8;
      bf16x8 af[4], bfv[4];
#pragma unroll
      for (int mf = 0; mf < 4; mf++) {
        int rr = wm * 64 + mf * 16 + (lane & 15);
        int ad = (rr * 128 + kb * 2) ^ ((rr & 7) << 4);
        af[mf] = *(bf16x8*)((char*)As + ad);
      }
#pragma unroll
      for (int nf = 0; nf < 4; nf++) {
        int cc = wn * 64 + nf * 16 + (lane & 15);
        int bd = (cc * 128 + kb * 2) ^ ((cc & 7) << 4);
        bfv[nf] = *(bf16x8*)((char*)Bs + bd);
      }
#pragma unroll
      for (int mf = 0; mf < 4; mf++)
#pragma unroll
        for (int nf = 0; nf < 4; nf++)
          acc[mf][nf] = __builtin_amdgcn_mfma_f32_16x16x32_bf16(af[mf], bfv[nf], acc[mf][nf], 0, 0, 0);
    }
  }
  int lr = lane >> 4, lc = lane & 15;
#pragma unroll
  for (int mf = 0; mf < 4; mf++) {
#pragma unroll
    for (int r4 = 0; r4 < 4; r4++) {
      int row = row0 + wm * 64 + mf * 16 + lr * 4 + r4;
      if (row < M) {
#pragma unroll
        for (int nf = 0; nf < 4; nf++) {
          int col = col0 + wn * 64 + nf * 16 + lc;
          float v = acc[mf][nf][r4];
          if (write_bf) ((unsigned short*)Cout)[(size_t)row * ldC + col] = f2bf(v);
          else ((float*)Cout)[(size_t)row * ldC + col] = v;
        }
      }
    }
  }
}

// ---------------- single-pass agg + mean + residual + LN + GELU (one wave/dst)
// lane l: head (l>>4), dims 8*(l&15)..+8. Coeffs precomputed (wexp), no exp here.
__global__ __launch_bounds__(256) void agg2(
    const int* __restrict__ rowptr, const int* __restrict__ adj,
    const float* __restrict__ wexp, const float* __restrict__ s,
    const unsigned short* __restrict__ fsb,
    const float* __restrict__ bm,
    const float* __restrict__ g, const float* __restrict__ be,
    float* __restrict__ out, int M) {
  int wave = threadIdx.x >> 6, lane = threadIdx.x & 63;
  int n = blockIdx.x * 4 + wave;
  if (n >= M) return;
  int beg = rowptr[n], end = rowptr[n + 1];
  int lh = lane >> 4, lc = lane & 15;
  float sh = s[(size_t)n * HH + lh];
  float rsh = sh > 0.f ? 0.25f / sh : 0.f;
  float m[8] = {0.f, 0.f, 0.f, 0.f, 0.f, 0.f, 0.f, 0.f};
  for (int t = beg; t < end; t++) {
    int si = adj[t];
    float ah = wexp[(size_t)t * HH + lh] * rsh;
    uint4 u = *(const uint4*)(fsb + (size_t)si * HD + lane * 8);
    m[0] = fmaf(ah, bf_lo(u.x), m[0]); m[1] = fmaf(ah, bf_hi(u.x), m[1]);
    m[2] = fmaf(ah, bf_lo(u.y), m[2]); m[3] = fmaf(ah, bf_hi(u.y), m[3]);
    m[4] = fmaf(ah, bf_lo(u.z), m[4]); m[5] = fmaf(ah, bf_hi(u.z), m[5]);
    m[6] = fmaf(ah, bf_lo(u.w), m[6]); m[7] = fmaf(ah, bf_hi(u.w), m[7]);
  }
  // head reduce across the 4 lane groups
#pragma unroll
  for (int j = 0; j < 8; j++) {
    m[j] += __shfl_xor(m[j], 16);
    m[j] += __shfl_xor(m[j], 32);
  }
  const float4* bmp = (const float4*)(bm + lc * 8);
  float4 b0 = bmp[0], b1 = bmp[1];
  const float4* orow = (const float4*)(out + (size_t)n * DD + lc * 8);
  float4 p0 = orow[0], p1 = orow[1];
  float c[8];
  c[0] = m[0] + b0.x + p0.x; c[1] = m[1] + b0.y + p0.y;
  c[2] = m[2] + b0.z + p0.z; c[3] = m[3] + b0.w + p0.w;
  c[4] = m[4] + b1.x + p1.x; c[5] = m[5] + b1.y + p1.y;
  c[6] = m[6] + b1.z + p1.z; c[7] = m[7] + b1.w + p1.w;
  float ss = c[0] + c[1] + c[2] + c[3] + c[4] + c[5] + c[6] + c[7];
  ss += __shfl_xor(ss, 1); ss += __shfl_xor(ss, 2);
  ss += __shfl_xor(ss, 4); ss += __shfl_xor(ss, 8);
  float mu = ss * (1.f / 128.f);
  float vv = 0.f;
#pragma unroll
  for (int j = 0; j < 8; j++) { float d = c[j] - mu; vv = fmaf(d, d, vv); }
  vv += __shfl_xor(vv, 1); vv += __shfl_xor(vv, 2);
  vv += __shfl_xor(vv, 4); vv += __shfl_xor(vv, 8);
  float inv = rsqrtf(vv * (1.f / 128.f) + LN_EPS);
  const float4* gp = (const float4*)(g + lc * 8);
  const float4* bep = (const float4*)(be + lc * 8);
  float4 g0 = gp[0], g1 = gp[1];
  float4 e0 = bep[0], e1 = bep[1];
  float gv[8] = {g0.x, g0.y, g0.z, g0.w, g1.x, g1.y, g1.z, g1.w};
  float ev[8] = {e0.x, e0.y, e0.z, e0.w, e1.x, e1.y, e1.z, e1.w};
  float o[8];
#pragma unroll
  for (int j = 0; j < 8; j++) {
    float y = (c[j] - mu) * inv * gv[j] + ev[j];
    o[j] = 0.5f * y * (1.f + erff(y * 0.70710678118f));
  }
  if (lane < 16) {
    float4* op = (float4*)(out + (size_t)n * DD + lane * 8);
    op[0] = make_float4(o[0], o[1], o[2], o[3]);
    op[1] = make_float4(o[4], o[5], o[6], o[7]);
  }
}

extern "C" void kernel_launch(void* const* d_in, const int* in_sizes, int n_in,
                              void* d_out, int out_size, void* d_ws, size_t ws_size,
                              hipStream_t stream) {
  const float* feat_host = (const float*)d_in[0];
  const float* feat_flow = (const float*)d_in[1];
  const float* W1  = (const float*)d_in[2];
  const float* al1 = (const float*)d_in[3];
  const float* ar1 = (const float*)d_in[4];
  const float* b1  = (const float*)d_in[5];
  const float* W2  = (const float*)d_in[6];
  const float* al2 = (const float*)d_in[7];
  const float* ar2 = (const float*)d_in[8];
  const float* b2  = (const float*)d_in[9];
  const float* pWh = (const float*)d_in[10];
  const float* pbh = (const float*)d_in[11];
  const float* pWf = (const float*)d_in[12];
  const float* pbf = (const float*)d_in[13];
  const float* gh  = (const float*)d_in[14];
  const float* beh = (const float*)d_in[15];
  const float* gf  = (const float*)d_in[16];
  const float* bef = (const float*)d_in[17];
  const int* e1s = (const int*)d_in[18];
  const int* e1d = (const int*)d_in[19];
  const int* e2s = (const int*)d_in[20];
  const int* e2d = (const int*)d_in[21];

  float* out = (float*)d_out;
  float* host_out = out;                       // [NN,128]
  float* flow_out = out + (size_t)NN * DD;     // [NN,128]

  float* ws = (float*)d_ws;
  size_t off = 0;
  unsigned short* fsb = (unsigned short*)(ws + off); off += (size_t)NN * 256;  // NN x 512 bf16
  short* W1t  = (short*)(ws + off); off += (512 * 256) / 2;
  short* W2t  = (short*)(ws + off); off += (512 * 256) / 2;
  short* pWht = (short*)(ws + off); off += (128 * 256) / 2;
  short* pWft = (short*)(ws + off); off += (128 * 256) / 2;
  float* el1b = ws + off; off += (size_t)NN * HH;
  float* er1b = ws + off; off += (size_t)NN * HH;
  float* el2b = ws + off; off += (size_t)NN * HH;
  float* er2b = ws + off; off += (size_t)NN * HH;
  float* Cbuf = ws + off; off += 4096;
  float* bm   = ws + off; off += 256;          // bm1 | bm2
  float* wexp1 = ws + off; off += (size_t)EE * HH;   // per-slot exp coeffs
  float* wexp2 = ws + off; off += (size_t)EE * HH;
  // CSR + denominators
  int* rp1  = (int*)(ws + off);      // NN+1
  int* rp2  = rp1 + (NN + 1);
  int* adj1 = rp2 + (NN + 1);        // EE (src ids)
  int* adj2 = adj1 + EE;
  int* bsum = adj2 + EE;             // 256
  int* cur1 = bsum + 256;            // NN   } contiguous memset region:
  int* cur2 = cur1 + NN;             // NN   } cur1,cur2,s1,s2 = 10*NN*4 B
  float* s1 = (float*)(cur2 + NN);   // NN*4
  float* s2 = s1 + (size_t)NN * HH;  // NN*4
  off += (size_t)(2 * (NN + 1) + 2 * EE + 256 + 10 * NN + 4);
  // optional bf16 feature copies
  size_t base_bytes = (off + 1024) * sizeof(float);
  size_t featb_bytes = (size_t)NN * KIN * 2 * 2;
  bool use_featb = ws_size >= base_bytes + featb_bytes;
  short* fhb = nullptr;
  short* ffb = nullptr;
  if (use_featb) {
    fhb = (short*)(ws + off); off += (size_t)NN * KIN / 2;
    ffb = (short*)(ws + off); off += (size_t)NN * KIN / 2;
  }

  dim3 blk(256);
  int gx = (NN + 127) / 128;                 // 782 row tiles
  int pf_g = (NN + 3) / 4;
  int ag_g = (NN + 3) / 4;
  int ee2_g = (2 * EE + 255) / 256;
  int nn_g = (NN + 255) / 256;

  // ---- prep
  convw<<<512, blk, 0, stream>>>(W1, W2, pWh, pWf, W1t, W2t, pWht, pWft);
  make_c<<<dim3(1, 4), blk, 0, stream>>>(W1, al1, ar1, W2, al2, ar2, Cbuf);
  make_bm<<<1, blk, 0, stream>>>(b1, pbf, b2, pbh, bm);
  if (use_featb) {
    prep_feat<<<pf_g, blk, 0, stream>>>(feat_host, Cbuf + 0,    Cbuf + 3072, fhb, el1b, er2b, NN);
    prep_feat<<<pf_g, blk, 0, stream>>>(feat_flow, Cbuf + 1024, Cbuf + 2048, ffb, er1b, el2b, NN);
  } else {
    skinny8<<<pf_g, blk, 0, stream>>>(feat_host, Cbuf + 0,    Cbuf + 3072, el1b, er2b, NN);
    skinny8<<<pf_g, blk, 0, stream>>>(feat_flow, Cbuf + 1024, Cbuf + 2048, er1b, el2b, NN);
  }

  // ---- CSR + coeffs + softmax denominators
  hipMemsetAsync(cur1, 0, (size_t)10 * NN * sizeof(int), stream);
  hist2<<<ee2_g, blk, 0, stream>>>(e1d, e2d, cur1, cur2);
  scan_chunk<<<dim3(NB_SCAN, 2), blk, 0, stream>>>(cur1, cur2, rp1, rp2, bsum);
  scan_bsum<<<dim3(1, 2), 128, 0, stream>>>(bsum);
  addoff2<<<dim3(nn_g, 2), blk, 0, stream>>>(rp1, rp2, cur1, cur2, bsum);
  fill_s<<<ee2_g, blk, 0, stream>>>(e1s, e1d, e2s, e2d, el1b, er1b, el2b, er2b,
                                    cur1, cur2, s1, s2, adj1, adj2, wexp1, wexp2);

  // ---- relation 1: host -> flow (dst = flow, out = flow_out)
  if (use_featb) {
    mfma_gemm<1><<<gx, blk, 0, stream>>>(ffb, pWft, flow_out, DD, NN, 0, 1);
    mfma_gemm<1><<<gx * 4, blk, 0, stream>>>(fhb, W1t, fsb, HD, NN, 1, 4);
  } else {
    mfma_gemm<0><<<gx, blk, 0, stream>>>(feat_flow, pWft, flow_out, DD, NN, 0, 1);
    mfma_gemm<0><<<gx * 4, blk, 0, stream>>>(feat_host, W1t, fsb, HD, NN, 1, 4);
  }
  agg2<<<ag_g, blk, 0, stream>>>(rp1, adj1, wexp1, s1, fsb, bm, gf, bef, flow_out, NN);

  // ---- relation 2: flow -> host (dst = host, out = host_out)
  if (use_featb) {
    mfma_gemm<1><<<gx, blk, 0, stream>>>(fhb, pWht, host_out, DD, NN, 0, 1);
    mfma_gemm<1><<<gx * 4, blk, 0, stream>>>(ffb, W2t, fsb, HD, NN, 1, 4);
  } else {
    mfma_gemm<0><<<gx, blk, 0, stream>>>(feat_host, pWht, host_out, DD, NN, 0, 1);
    mfma_gemm<0><<<gx * 4, blk, 0, stream>>>(feat_flow, W2t, fsb, HD, NN, 1, 4);
  }
  agg2<<<ag_g, blk, 0, stream>>>(rp2, adj2, wexp2, s2, fsb, bm + 128, gh, beh, host_out, NN);
}

// Round 10
// 548.640 us; speedup vs baseline: 3.5940x; 1.2054x over previous
//
#include <hip/hip_runtime.h>
#include <math.h>

#define NN 100000      // nodes per type
#define EE 200000      // edges per relation
#define HH 4
#define DD 128
#define HD 512         // H*D
#define KIN 256        // input feature dim
#define LN_EPS 1e-5f
#define SLOPE 0.2f
#define NB_SCAN 98     // ceil(NN/1024)

// LDS bank-conflict swizzle for the Cs[2048] table (prep_feat/skinny8).
#define CSW(a) ((a) ^ (((a) >> 5) & 31))

typedef short bf16x8 __attribute__((ext_vector_type(8)));
typedef unsigned short u16x4 __attribute__((ext_vector_type(4)));
typedef float f32x4 __attribute__((ext_vector_type(4)));

typedef __attribute__((address_space(3))) unsigned int lds_uint;
typedef const __attribute__((address_space(1))) unsigned int glb_uint;

static __device__ __forceinline__ void gload_lds16(const void* g, void* l) {
  __builtin_amdgcn_global_load_lds((glb_uint*)g, (lds_uint*)l, 16, 0, 0);
}

static __device__ __forceinline__ unsigned short f2bf(float x) {
  unsigned int u = __float_as_uint(x);
  u += 0x7fffu + ((u >> 16) & 1u);   // RNE
  return (unsigned short)(u >> 16);
}
static __device__ __forceinline__ float bf_lo(unsigned int u) {
  return __uint_as_float(u << 16);
}
static __device__ __forceinline__ float bf_hi(unsigned int u) {
  return __uint_as_float(u & 0xffff0000u);
}

// ---------------- convert + transpose weights to bf16 [N][K]
__global__ __launch_bounds__(256) void convw(
    const float* __restrict__ W1, const float* __restrict__ W2,
    const float* __restrict__ pWh, const float* __restrict__ pWf,
    short* __restrict__ W1t, short* __restrict__ W2t,
    short* __restrict__ pWht, short* __restrict__ pWft) {
  int idx = blockIdx.x * 256 + threadIdx.x;
  if (idx < 512 * 256) {
    int n = idx >> 8, k = idx & 255;
    W1t[idx] = (short)f2bf(W1[(size_t)k * HD + n]);
    W2t[idx] = (short)f2bf(W2[(size_t)k * HD + n]);
  }
  if (idx < 128 * 256) {
    int n = idx >> 8, k = idx & 255;
    pWht[idx] = (short)f2bf(pWh[(size_t)k * DD + n]);
    pWft[idx] = (short)f2bf(pWf[(size_t)k * DD + n]);
  }
}

// ---------------- build C[k,h] = sum_d W[k, h*128+d] * a[h*128+d]
__global__ __launch_bounds__(256) void make_c(
    const float* __restrict__ W1, const float* __restrict__ al1, const float* __restrict__ ar1,
    const float* __restrict__ W2, const float* __restrict__ al2, const float* __restrict__ ar2,
    float* __restrict__ Cout) {
  int which = blockIdx.y;
  const float* W = (which < 2) ? W1 : W2;
  const float* a = (which == 0) ? al1 : (which == 1) ? ar1 : (which == 2) ? al2 : ar2;
  int k = threadIdx.x;
  float* C = Cout + (size_t)which * 1024;
#pragma unroll
  for (int h = 0; h < HH; h++) {
    float s = 0.f;
    for (int d = 0; d < DD; d++) s = fmaf(W[(size_t)k * HD + h * DD + d], a[h * DD + d], s);
    C[k * HH + h] = s;
  }
}

// ---------------- bm1[d] = 0.25*sum_h b1 + pbf ; bm2 likewise (b2, pbh)
__global__ __launch_bounds__(256) void make_bm(
    const float* __restrict__ b1, const float* __restrict__ pbf,
    const float* __restrict__ b2, const float* __restrict__ pbh,
    float* __restrict__ bm) {
  int d = threadIdx.x;
  if (d < 128) {
    bm[d] = 0.25f * (b1[d] + b1[128 + d] + b1[256 + d] + b1[384 + d]) + pbf[d];
  } else {
    int dd = d - 128;
    bm[d] = 0.25f * (b2[dd] + b2[128 + dd] + b2[256 + dd] + b2[384 + dd]) + pbh[dd];
  }
}

// ---------------- fused: bf16 convert + el/er skinny dots (one wave per row)
__global__ __launch_bounds__(256) void prep_feat(
    const float* __restrict__ X, const float* __restrict__ C1, const float* __restrict__ C2,
    short* __restrict__ Xb, float* __restrict__ o1, float* __restrict__ o2, int M) {
  __shared__ float Cs[KIN * 8];
  int tid = threadIdx.x;
  for (int i = tid; i < KIN * 4; i += 256) {
    int k = i >> 2, h = i & 3;
    Cs[CSW(k * 8 + h)] = C1[i];
    Cs[CSW(k * 8 + 4 + h)] = C2[i];
  }
  __syncthreads();
  int wave = tid >> 6, lane = tid & 63;
  int n = blockIdx.x * 4 + wave;
  if (n >= M) return;
  float4 xv = ((const float4*)(X + (size_t)n * KIN))[lane];
  float xs[4] = {xv.x, xv.y, xv.z, xv.w};
  u16x4 pk;
  pk[0] = f2bf(xs[0]); pk[1] = f2bf(xs[1]); pk[2] = f2bf(xs[2]); pk[3] = f2bf(xs[3]);
  *(u16x4*)(Xb + (size_t)n * KIN + lane * 4) = pk;
  float acc[8] = {0.f, 0.f, 0.f, 0.f, 0.f, 0.f, 0.f, 0.f};
#pragma unroll
  for (int j = 0; j < 4; j++) {
    int k = lane * 4 + j;
#pragma unroll
    for (int t = 0; t < 8; t++) acc[t] = fmaf(xs[j], Cs[CSW(k * 8 + t)], acc[t]);
  }
#pragma unroll
  for (int off = 32; off >= 1; off >>= 1)
#pragma unroll
    for (int t = 0; t < 8; t++) acc[t] += __shfl_xor(acc[t], off);
  if (lane == 0) {
#pragma unroll
    for (int h = 0; h < HH; h++) {
      o1[(size_t)n * HH + h] = acc[h];
      o2[(size_t)n * HH + h] = acc[4 + h];
    }
  }
}

// ---------------- fallback skinny (no bf16 feature copy)
__global__ __launch_bounds__(256) void skinny8(
    const float* __restrict__ X, const float* __restrict__ C1, const float* __restrict__ C2,
    float* __restrict__ o1, float* __restrict__ o2, int M) {
  __shared__ float Cs[KIN * 8];
  int tid = threadIdx.x;
  for (int i = tid; i < KIN * 4; i += 256) {
    int k = i >> 2, h = i & 3;
    Cs[CSW(k * 8 + h)] = C1[i];
    Cs[CSW(k * 8 + 4 + h)] = C2[i];
  }
  __syncthreads();
  int wave = tid >> 6, lane = tid & 63;
  int n = blockIdx.x * 4 + wave;
  if (n >= M) return;
  float4 xv = ((const float4*)(X + (size_t)n * KIN))[lane];
  float xs[4] = {xv.x, xv.y, xv.z, xv.w};
  float acc[8] = {0.f, 0.f, 0.f, 0.f, 0.f, 0.f, 0.f, 0.f};
#pragma unroll
  for (int j = 0; j < 4; j++) {
    int k = lane * 4 + j;
#pragma unroll
    for (int t = 0; t < 8; t++) acc[t] = fmaf(xs[j], Cs[CSW(k * 8 + t)], acc[t]);
  }
#pragma unroll
  for (int off = 32; off >= 1; off >>= 1)
#pragma unroll
    for (int t = 0; t < 8; t++) acc[t] += __shfl_xor(acc[t], off);
  if (lane == 0) {
#pragma unroll
    for (int h = 0; h < HH; h++) {
      o1[(size_t)n * HH + h] = acc[h];
      o2[(size_t)n * HH + h] = acc[4 + h];
    }
  }
}

// ---------------- CSR build ----------------
__global__ __launch_bounds__(256) void hist2(
    const int* __restrict__ d1, const int* __restrict__ d2,
    int* __restrict__ c1, int* __restrict__ c2) {
  int gid = blockIdx.x * 256 + threadIdx.x;
  if (gid < EE) atomicAdd(&c1[d1[gid]], 1);
  else if (gid < 2 * EE) atomicAdd(&c2[d2[gid - EE]], 1);
}

__global__ __launch_bounds__(256) void scan_chunk(
    const int* __restrict__ c1, const int* __restrict__ c2,
    int* __restrict__ rp1, int* __restrict__ rp2, int* __restrict__ bsum) {
  int rel = blockIdx.y;
  const int* counts = rel ? c2 : c1;
  int* rowptr = rel ? rp2 : rp1;
  int* bs = bsum + rel * 128;
  __shared__ int sd[256];
  int tid = threadIdx.x;
  int base = blockIdx.x * 1024 + tid * 4;
  int c[4];
#pragma unroll
  for (int j = 0; j < 4; j++) c[j] = (base + j < NN) ? counts[base + j] : 0;
  int tot = c[0] + c[1] + c[2] + c[3];
  sd[tid] = tot; __syncthreads();
  for (int o = 1; o < 256; o <<= 1) {
    int v = (tid >= o) ? sd[tid - o] : 0;
    __syncthreads();
    sd[tid] += v;
    __syncthreads();
  }
  int excl = sd[tid] - tot;
  int run = excl;
#pragma unroll
  for (int j = 0; j < 4; j++) {
    if (base + j < NN) rowptr[base + j] = run;
    run += c[j];
  }
  if (tid == 255) bs[blockIdx.x] = sd[255];
}

__global__ __launch_bounds__(128) void scan_bsum(int* __restrict__ bsum) {
  int rel = blockIdx.y;
  int* bs = bsum + rel * 128;
  __shared__ int sd[128];
  int tid = threadIdx.x;
  int v = (tid < NB_SCAN) ? bs[tid] : 0;
  sd[tid] = v; __syncthreads();
  for (int o = 1; o < 128; o <<= 1) {
    int t = (tid >= o) ? sd[tid - o] : 0;
    __syncthreads();
    sd[tid] += t;
    __syncthreads();
  }
  bs[tid] = sd[tid] - v;
}

__global__ __launch_bounds__(256) void addoff2(
    int* __restrict__ rp1, int* __restrict__ rp2,
    int* __restrict__ cur1, int* __restrict__ cur2,
    const int* __restrict__ bsum) {
  int rel = blockIdx.y;
  int* rowptr = rel ? rp2 : rp1;
  int* cur = rel ? cur2 : cur1;
  const int* bs = bsum + rel * 128;
  int i = blockIdx.x * 256 + threadIdx.x;
  if (i < NN) {
    int r = rowptr[i] + bs[i >> 10];
    rowptr[i] = r;
    cur[i] = r;
  }
  if (i == 0) rowptr[NN] = EE;
}

// ---------------- fill CSR: src id + per-edge exp coeffs (NO denominator atomics)
__global__ __launch_bounds__(256) void fill_s(
    const int* __restrict__ e1s, const int* __restrict__ e1d,
    const int* __restrict__ e2s, const int* __restrict__ e2d,
    const float* __restrict__ el1, const float* __restrict__ er1,
    const float* __restrict__ el2, const float* __restrict__ er2,
    int* __restrict__ cur1, int* __restrict__ cur2,
    int* __restrict__ adj1, int* __restrict__ adj2,
    float* __restrict__ wexp1, float* __restrict__ wexp2) {
  int gid = blockIdx.x * 256 + threadIdx.x;
  int rel = (gid >= EE);
  if (gid >= 2 * EE) return;
  int e = rel ? gid - EE : gid;
  const int* srcp = rel ? e2s : e1s;
  const int* dstp = rel ? e2d : e1d;
  const float* el = rel ? el2 : el1;
  const float* er = rel ? er2 : er1;
  int* cur = rel ? cur2 : cur1;
  int* adj = rel ? adj2 : adj1;
  float* wexp = rel ? wexp2 : wexp1;
  int si = srcp[e], di = dstp[e];
  int p = atomicAdd(&cur[di], 1);
  adj[p] = si;
  float4 l = *(const float4*)(el + (size_t)si * HH);
  float4 r = *(const float4*)(er + (size_t)di * HH);
  float v0 = l.x + r.x, v1 = l.y + r.y, v2 = l.z + r.z, v3 = l.w + r.w;
  v0 = v0 > 0.f ? v0 : SLOPE * v0; v1 = v1 > 0.f ? v1 : SLOPE * v1;
  v2 = v2 > 0.f ? v2 : SLOPE * v2; v3 = v3 > 0.f ? v3 : SLOPE * v3;
  *(float4*)(wexp + (size_t)p * HH) =
      make_float4(__expf(v0), __expf(v1), __expf(v2), __expf(v3));
}

// ---------------- MFMA GEMM: C[M x N] = A[M x 256] @ Wt[N x 256]^T
// 1-D grid, XCD-bijective swizzle, col fastest (A L2 reuse).
// ABF=1: bf16 A; staging via global_load_lds(16B), linear LDS dest +
// inverse-swizzled per-lane global source (XOR stays within each 128B K-window).
template <int ABF>
__global__ __launch_bounds__(256) void mfma_gemm(
    const void* __restrict__ Av, const short* __restrict__ Wt,
    void* __restrict__ Cout, int ldC, int M, int write_bf, int ncol) {
  __shared__ short As[128 * 64];
  __shared__ short Bs[128 * 64];
  int nwg = gridDim.x;
  int q = nwg >> 3, r = nwg & 7;
  int xcd = blockIdx.x & 7, seq = blockIdx.x >> 3;
  int lid = (xcd < r) ? (xcd * (q + 1) + seq) : (r * (q + 1) + (xcd - r) * q + seq);
  int row0 = (lid / ncol) * 128;
  int col0 = (lid % ncol) * 128;

  int tid = threadIdx.x;
  int lane = tid & 63, wid = tid >> 6;
  int wm = wid >> 1, wn = wid & 1;

  f32x4 acc[4][4];
#pragma unroll
  for (int i = 0; i < 4; i++)
#pragma unroll
    for (int j = 0; j < 4; j++) acc[i][j] = (f32x4){0.f, 0.f, 0.f, 0.f};

  int am = tid >> 1;
  int akh = (tid & 1) * 32;
  bool arow_ok = (row0 + am) < M;

  for (int k0 = 0; k0 < KIN; k0 += 64) {
    __syncthreads();
    if (ABF) {
      // ---- async staging: 4 calls A + 4 calls B per wave
      int rr8 = lane >> 3;            // 0..7 row within the 8-row chunk
      int bby = (lane & 7) * 16;      // byte chunk within 128B K-window
#pragma unroll
      for (int c2 = 0; c2 < 4; c2++) {
        int rr = wid * 32 + c2 * 8 + rr8;
        int rg = row0 + rr; if (rg > M - 1) rg = M - 1;
        int sb = bby ^ ((rr & 7) << 4);
        gload_lds16((const char*)Av + (size_t)rg * (KIN * 2) + k0 * 2 + sb,
                    (char*)As + wid * 4096 + c2 * 1024);
      }
#pragma unroll
      for (int c2 = 0; c2 < 4; c2++) {
        int rr = wid * 32 + c2 * 8 + rr8;
        int sb = bby ^ ((rr & 7) << 4);
        gload_lds16((const char*)Wt + (size_t)(col0 + rr) * (KIN * 2) + k0 * 2 + sb,
                    (char*)Bs + wid * 4096 + c2 * 1024);
      }
    } else {
      const float* xp = (const float*)Av + (size_t)(row0 + am) * KIN + k0 + akh;
#pragma unroll
      for (int c = 0; c < 4; c++) {
        float4 v0, v1;
        if (arow_ok) {
          v0 = *(const float4*)(xp + c * 8);
          v1 = *(const float4*)(xp + c * 8 + 4);
        } else {
          v0 = make_float4(0.f, 0.f, 0.f, 0.f);
          v1 = v0;
        }
        bf16x8 pk;
        pk[0] = (short)f2bf(v0.x); pk[1] = (short)f2bf(v0.y);
        pk[2] = (short)f2bf(v0.z); pk[3] = (short)f2bf(v0.w);
        pk[4] = (short)f2bf(v1.x); pk[5] = (short)f2bf(v1.y);
        pk[6] = (short)f2bf(v1.z); pk[7] = (short)f2bf(v1.w);
        int kc = akh + c * 8;
        int ad = (am * 128 + kc * 2) ^ ((am & 7) << 4);
        *(bf16x8*)((char*)As + ad) = pk;
      }
      int bn = tid >> 1;
      int bkh = (tid & 1) * 32;
      const short* wp = Wt + (size_t)(col0 + bn) * KIN + k0 + bkh;
#pragma unroll
      for (int c = 0; c < 4; c++) {
        bf16x8 pv = *(const bf16x8*)(wp + c * 8);
        int kc = bkh + c * 8;
        int bd = (bn * 128 + kc * 2) ^ ((bn & 7) << 4);
        *(bf16x8*)((char*)Bs + bd) = pv;
      }
    }
    __syncthreads();
#pragma unroll
    for (int ks = 0; ks < 2; ks++) {
      int kb = ks * 32 + (lane >> 4) * 8;
      bf16x8 af[4], bfv[4];
#pragma unroll
      for (int mf = 0; mf < 4; mf++) {
        int rr = wm * 64 + mf * 16 + (lane & 15);
        int ad = (rr * 128 + kb * 2) ^ ((rr & 7) << 4);
        af[mf] = *(bf16x8*)((char*)As + ad);
      }
#pragma unroll
      for (int nf = 0; nf < 4; nf++) {
        int cc = wn * 64 + nf * 16 + (lane & 15);
        int bd = (cc * 128 + kb * 2) ^ ((cc & 7) << 4);
        bfv[nf] = *(bf16x8*)((char*)Bs + bd);
      }
#pragma unroll
      for (int mf = 0; mf < 4; mf++)
#pragma unroll
        for (int nf = 0; nf < 4; nf++)
          acc[mf][nf] = __builtin_amdgcn_mfma_f32_16x16x32_bf16(af[mf], bfv[nf], acc[mf][nf], 0, 0, 0);
    }
  }
  int lr = lane >> 4, lc = lane & 15;
#pragma unroll
  for (int mf = 0; mf < 4; mf++) {
#pragma unroll
    for (int r4 = 0; r4 < 4; r4++) {
      int row = row0 + wm * 64 + mf * 16 + lr * 4 + r4;
      if (row < M) {
#pragma unroll
        for (int nf = 0; nf < 4; nf++) {
          int col = col0 + wn * 64 + nf * 16 + lc;
          float v = acc[mf][nf][r4];
          if (write_bf) ((unsigned short*)Cout)[(size_t)row * ldC + col] = f2bf(v);
          else ((float*)Cout)[(size_t)row * ldC + col] = v;
        }
      }
    }
  }
}

// ---------------- single-pass agg + mean + residual + LN + GELU (one wave/dst)
// lane l: head (l>>4), dims 8*(l&15)..+8. Denominator folded: m = (Σ w·fs)·(0.25/Σw).
__global__ __launch_bounds__(256) void agg2(
    const int* __restrict__ rowptr, const int* __restrict__ adj,
    const float* __restrict__ wexp,
    const unsigned short* __restrict__ fsb,
    const float* __restrict__ bm,
    const float* __restrict__ g, const float* __restrict__ be,
    float* __restrict__ out, int M) {
  int wave = threadIdx.x >> 6, lane = threadIdx.x & 63;
  int n = blockIdx.x * 4 + wave;
  if (n >= M) return;
  int beg = rowptr[n], end = rowptr[n + 1];
  int lh = lane >> 4, lc = lane & 15;
  float sh = 0.f;
  float m[8] = {0.f, 0.f, 0.f, 0.f, 0.f, 0.f, 0.f, 0.f};
  for (int t = beg; t < end; t++) {
    int si = adj[t];
    float wh = wexp[(size_t)t * HH + lh];
    sh += wh;
    uint4 u = *(const uint4*)(fsb + (size_t)si * HD + lane * 8);
    m[0] = fmaf(wh, bf_lo(u.x), m[0]); m[1] = fmaf(wh, bf_hi(u.x), m[1]);
    m[2] = fmaf(wh, bf_lo(u.y), m[2]); m[3] = fmaf(wh, bf_hi(u.y), m[3]);
    m[4] = fmaf(wh, bf_lo(u.z), m[4]); m[5] = fmaf(wh, bf_hi(u.z), m[5]);
    m[6] = fmaf(wh, bf_lo(u.w), m[6]); m[7] = fmaf(wh, bf_hi(u.w), m[7]);
  }
  float rsh = sh > 0.f ? 0.25f / sh : 0.f;
#pragma unroll
  for (int j = 0; j < 8; j++) m[j] *= rsh;
  // head reduce across the 4 lane groups
#pragma unroll
  for (int j = 0; j < 8; j++) {
    m[j] += __shfl_xor(m[j], 16);
    m[j] += __shfl_xor(m[j], 32);
  }
  const float4* bmp = (const float4*)(bm + lc * 8);
  float4 b0 = bmp[0], b1 = bmp[1];
  const float4* orow = (const float4*)(out + (size_t)n * DD + lc * 8);
  float4 p0 = orow[0], p1 = orow[1];
  float c[8];
  c[0] = m[0] + b0.x + p0.x; c[1] = m[1] + b0.y + p0.y;
  c[2] = m[2] + b0.z + p0.z; c[3] = m[3] + b0.w + p0.w;
  c[4] = m[4] + b1.x + p1.x; c[5] = m[5] + b1.y + p1.y;
  c[6] = m[6] + b1.z + p1.z; c[7] = m[7] + b1.w + p1.w;
  float ss = c[0] + c[1] + c[2] + c[3] + c[4] + c[5] + c[6] + c[7];
  ss += __shfl_xor(ss, 1); ss += __shfl_xor(ss, 2);
  ss += __shfl_xor(ss, 4); ss += __shfl_xor(ss, 8);
  float mu = ss * (1.f / 128.f);
  float vv = 0.f;
#pragma unroll
  for (int j = 0; j < 8; j++) { float d = c[j] - mu; vv = fmaf(d, d, vv); }
  vv += __shfl_xor(vv, 1); vv += __shfl_xor(vv, 2);
  vv += __shfl_xor(vv, 4); vv += __shfl_xor(vv, 8);
  float inv = rsqrtf(vv * (1.f / 128.f) + LN_EPS);
  const float4* gp = (const float4*)(g + lc * 8);
  const float4* bep = (const float4*)(be + lc * 8);
  float4 g0 = gp[0], g1 = gp[1];
  float4 e0 = bep[0], e1 = bep[1];
  float gv[8] = {g0.x, g0.y, g0.z, g0.w, g1.x, g1.y, g1.z, g1.w};
  float ev[8] = {e0.x, e0.y, e0.z, e0.w, e1.x, e1.y, e1.z, e1.w};
  float o[8];
#pragma unroll
  for (int j = 0; j < 8; j++) {
    float y = (c[j] - mu) * inv * gv[j] + ev[j];
    o[j] = 0.5f * y * (1.f + erff(y * 0.70710678118f));
  }
  if (lane < 16) {
    float4* op = (float4*)(out + (size_t)n * DD + lane * 8);
    op[0] = make_float4(o[0], o[1], o[2], o[3]);
    op[1] = make_float4(o[4], o[5], o[6], o[7]);
  }
}

extern "C" void kernel_launch(void* const* d_in, const int* in_sizes, int n_in,
                              void* d_out, int out_size, void* d_ws, size_t ws_size,
                              hipStream_t stream) {
  const float* feat_host = (const float*)d_in[0];
  const float* feat_flow = (const float*)d_in[1];
  const float* W1  = (const float*)d_in[2];
  const float* al1 = (const float*)d_in[3];
  const float* ar1 = (const float*)d_in[4];
  const float* b1  = (const float*)d_in[5];
  const float* W2  = (const float*)d_in[6];
  const float* al2 = (const float*)d_in[7];
  const float* ar2 = (const float*)d_in[8];
  const float* b2  = (const float*)d_in[9];
  const float* pWh = (const float*)d_in[10];
  const float* pbh = (const float*)d_in[11];
  const float* pWf = (const float*)d_in[12];
  const float* pbf = (const float*)d_in[13];
  const float* gh  = (const float*)d_in[14];
  const float* beh = (const float*)d_in[15];
  const float* gf  = (const float*)d_in[16];
  const float* bef = (const float*)d_in[17];
  const int* e1s = (const int*)d_in[18];
  const int* e1d = (const int*)d_in[19];
  const int* e2s = (const int*)d_in[20];
  const int* e2d = (const int*)d_in[21];

  float* out = (float*)d_out;
  float* host_out = out;                       // [NN,128]
  float* flow_out = out + (size_t)NN * DD;     // [NN,128]

  float* ws = (float*)d_ws;
  size_t off = 0;
  unsigned short* fsb = (unsigned short*)(ws + off); off += (size_t)NN * 256;  // NN x 512 bf16
  short* W1t  = (short*)(ws + off); off += (512 * 256) / 2;
  short* W2t  = (short*)(ws + off); off += (512 * 256) / 2;
  short* pWht = (short*)(ws + off); off += (128 * 256) / 2;
  short* pWft = (short*)(ws + off); off += (128 * 256) / 2;
  float* el1b = ws + off; off += (size_t)NN * HH;
  float* er1b = ws + off; off += (size_t)NN * HH;
  float* el2b = ws + off; off += (size_t)NN * HH;
  float* er2b = ws + off; off += (size_t)NN * HH;
  float* Cbuf = ws + off; off += 4096;
  float* bm   = ws + off; off += 256;          // bm1 | bm2
  float* wexp1 = ws + off; off += (size_t)EE * HH;   // per-slot exp coeffs
  float* wexp2 = ws + off; off += (size_t)EE * HH;
  // CSR
  int* rp1  = (int*)(ws + off);      // NN+1
  int* rp2  = rp1 + (NN + 1);
  int* adj1 = rp2 + (NN + 1);        // EE (src ids)
  int* adj2 = adj1 + EE;
  int* bsum = adj2 + EE;             // 256
  int* cur1 = bsum + 256;            // NN } contiguous memset region (2*NN)
  int* cur2 = cur1 + NN;             // NN }
  off += (size_t)(2 * (NN + 1) + 2 * EE + 256 + 2 * NN + 4);
  // optional bf16 feature copies
  size_t base_bytes = (off + 1024) * sizeof(float);
  size_t featb_bytes = (size_t)NN * KIN * 2 * 2;
  bool use_featb = ws_size >= base_bytes + featb_bytes;
  short* fhb = nullptr;
  short* ffb = nullptr;
  if (use_featb) {
    fhb = (short*)(ws + off); off += (size_t)NN * KIN / 2;
    ffb = (short*)(ws + off); off += (size_t)NN * KIN / 2;
  }

  dim3 blk(256);
  int gx = (NN + 127) / 128;                 // 782 row tiles
  int pf_g = (NN + 3) / 4;
  int ag_g = (NN + 3) / 4;
  int ee2_g = (2 * EE + 255) / 256;
  int nn_g = (NN + 255) / 256;

  // ---- prep
  convw<<<512, blk, 0, stream>>>(W1, W2, pWh, pWf, W1t, W2t, pWht, pWft);
  make_c<<<dim3(1, 4), blk, 0, stream>>>(W1, al1, ar1, W2, al2, ar2, Cbuf);
  make_bm<<<1, blk, 0, stream>>>(b1, pbf, b2, pbh, bm);
  if (use_featb) {
    prep_feat<<<pf_g, blk, 0, stream>>>(feat_host, Cbuf + 0,    Cbuf + 3072, fhb, el1b, er2b, NN);
    prep_feat<<<pf_g, blk, 0, stream>>>(feat_flow, Cbuf + 1024, Cbuf + 2048, ffb, er1b, el2b, NN);
  } else {
    skinny8<<<pf_g, blk, 0, stream>>>(feat_host, Cbuf + 0,    Cbuf + 3072, el1b, er2b, NN);
    skinny8<<<pf_g, blk, 0, stream>>>(feat_flow, Cbuf + 1024, Cbuf + 2048, er1b, el2b, NN);
  }

  // ---- CSR + per-edge coeffs (no denominator atomics)
  hipMemsetAsync(cur1, 0, (size_t)2 * NN * sizeof(int), stream);
  hist2<<<ee2_g, blk, 0, stream>>>(e1d, e2d, cur1, cur2);
  scan_chunk<<<dim3(NB_SCAN, 2), blk, 0, stream>>>(cur1, cur2, rp1, rp2, bsum);
  scan_bsum<<<dim3(1, 2), 128, 0, stream>>>(bsum);
  addoff2<<<dim3(nn_g, 2), blk, 0, stream>>>(rp1, rp2, cur1, cur2, bsum);
  fill_s<<<ee2_g, blk, 0, stream>>>(e1s, e1d, e2s, e2d, el1b, er1b, el2b, er2b,
                                    cur1, cur2, adj1, adj2, wexp1, wexp2);

  // ---- relation 1: host -> flow (dst = flow, out = flow_out)
  if (use_featb) {
    mfma_gemm<1><<<gx, blk, 0, stream>>>(ffb, pWft, flow_out, DD, NN, 0, 1);
    mfma_gemm<1><<<gx * 4, blk, 0, stream>>>(fhb, W1t, fsb, HD, NN, 1, 4);
  } else {
    mfma_gemm<0><<<gx, blk, 0, stream>>>(feat_flow, pWft, flow_out, DD, NN, 0, 1);
    mfma_gemm<0><<<gx * 4, blk, 0, stream>>>(feat_host, W1t, fsb, HD, NN, 1, 4);
  }
  agg2<<<ag_g, blk, 0, stream>>>(rp1, adj1, wexp1, fsb, bm, gf, bef, flow_out, NN);

  // ---- relation 2: flow -> host (dst = host, out = host_out)
  if (use_featb) {
    mfma_gemm<1><<<gx, blk, 0, stream>>>(fhb, pWht, host_out, DD, NN, 0, 1);
    mfma_gemm<1><<<gx * 4, blk, 0, stream>>>(ffb, W2t, fsb, HD, NN, 1, 4);
  } else {
    mfma_gemm<0><<<gx, blk, 0, stream>>>(feat_host, pWht, host_out, DD, NN, 0, 1);
    mfma_gemm<0><<<gx * 4, blk, 0, stream>>>(feat_flow, W2t, fsb, HD, NN, 1, 4);
  }
  agg2<<<ag_g, blk, 0, stream>>>(rp2, adj2, wexp2, fsb, bm + 128, gh, beh, host_out, NN);
}

// Round 11
// 536.981 us; speedup vs baseline: 3.6720x; 1.0217x over previous
//
#include <hip/hip_runtime.h>
#include <math.h>

#define NN 100000      // nodes per type
#define EE 200000      // edges per relation
#define HH 4
#define DD 128
#define HD 512         // H*D
#define KIN 256        // input feature dim
#define LN_EPS 1e-5f
#define SLOPE 0.2f
#define NB_SCAN 98     // ceil(NN/1024)

// LDS bank-conflict swizzle for the Cs[2048] table (prep_feat/skinny8).
#define CSW(a) ((a) ^ (((a) >> 5) & 31))

typedef short bf16x8 __attribute__((ext_vector_type(8)));
typedef unsigned short u16x4 __attribute__((ext_vector_type(4)));
typedef float f32x4 __attribute__((ext_vector_type(4)));

typedef __attribute__((address_space(3))) unsigned int lds_uint;
typedef const __attribute__((address_space(1))) unsigned int glb_uint;

static __device__ __forceinline__ void gload_lds16(const void* g, void* l) {
  __builtin_amdgcn_global_load_lds((glb_uint*)g, (lds_uint*)l, 16, 0, 0);
}

static __device__ __forceinline__ unsigned short f2bf(float x) {
  unsigned int u = __float_as_uint(x);
  u += 0x7fffu + ((u >> 16) & 1u);   // RNE
  return (unsigned short)(u >> 16);
}
static __device__ __forceinline__ float bf_lo(unsigned int u) {
  return __uint_as_float(u << 16);
}
static __device__ __forceinline__ float bf_hi(unsigned int u) {
  return __uint_as_float(u & 0xffff0000u);
}

// Branch-free erf, Abramowitz-Stegun 7.1.26 (max err 1.5e-7).
static __device__ __forceinline__ float erf_fast(float x) {
  float ax = fabsf(x);
  float t = __builtin_amdgcn_rcpf(fmaf(0.3275911f, ax, 1.0f));
  float p = fmaf(1.061405429f, t, -1.453152027f);
  p = fmaf(p, t, 1.421413741f);
  p = fmaf(p, t, -0.284496736f);
  p = fmaf(p, t, 0.254829592f);
  p = p * t;
  float r = 1.0f - p * __expf(-ax * ax);
  return copysignf(r, x);
}
static __device__ __forceinline__ float gelu_fast(float y) {
  return 0.5f * y * (1.0f + erf_fast(y * 0.70710678118f));
}

// ---------------- convert + transpose weights to bf16 [N][K]
__global__ __launch_bounds__(256) void convw(
    const float* __restrict__ W1, const float* __restrict__ W2,
    const float* __restrict__ pWh, const float* __restrict__ pWf,
    short* __restrict__ W1t, short* __restrict__ W2t,
    short* __restrict__ pWht, short* __restrict__ pWft) {
  int idx = blockIdx.x * 256 + threadIdx.x;
  if (idx < 512 * 256) {
    int n = idx >> 8, k = idx & 255;
    W1t[idx] = (short)f2bf(W1[(size_t)k * HD + n]);
    W2t[idx] = (short)f2bf(W2[(size_t)k * HD + n]);
  }
  if (idx < 128 * 256) {
    int n = idx >> 8, k = idx & 255;
    pWht[idx] = (short)f2bf(pWh[(size_t)k * DD + n]);
    pWft[idx] = (short)f2bf(pWf[(size_t)k * DD + n]);
  }
}

// ---------------- build C[k,h] = sum_d W[k, h*128+d] * a[h*128+d]
__global__ __launch_bounds__(256) void make_c(
    const float* __restrict__ W1, const float* __restrict__ al1, const float* __restrict__ ar1,
    const float* __restrict__ W2, const float* __restrict__ al2, const float* __restrict__ ar2,
    float* __restrict__ Cout) {
  int which = blockIdx.y;
  const float* W = (which < 2) ? W1 : W2;
  const float* a = (which == 0) ? al1 : (which == 1) ? ar1 : (which == 2) ? al2 : ar2;
  int k = threadIdx.x;
  float* C = Cout + (size_t)which * 1024;
#pragma unroll
  for (int h = 0; h < HH; h++) {
    float s = 0.f;
    for (int d = 0; d < DD; d++) s = fmaf(W[(size_t)k * HD + h * DD + d], a[h * DD + d], s);
    C[k * HH + h] = s;
  }
}

// ---------------- bm1[d] = 0.25*sum_h b1 + pbf ; bm2 likewise (b2, pbh)
__global__ __launch_bounds__(256) void make_bm(
    const float* __restrict__ b1, const float* __restrict__ pbf,
    const float* __restrict__ b2, const float* __restrict__ pbh,
    float* __restrict__ bm) {
  int d = threadIdx.x;
  if (d < 128) {
    bm[d] = 0.25f * (b1[d] + b1[128 + d] + b1[256 + d] + b1[384 + d]) + pbf[d];
  } else {
    int dd = d - 128;
    bm[d] = 0.25f * (b2[dd] + b2[128 + dd] + b2[256 + dd] + b2[384 + dd]) + pbh[dd];
  }
}

// ---------------- fused: bf16 convert + el/er skinny dots (one wave per row)
__global__ __launch_bounds__(256) void prep_feat(
    const float* __restrict__ X, const float* __restrict__ C1, const float* __restrict__ C2,
    short* __restrict__ Xb, float* __restrict__ o1, float* __restrict__ o2, int M) {
  __shared__ float Cs[KIN * 8];
  int tid = threadIdx.x;
  for (int i = tid; i < KIN * 4; i += 256) {
    int k = i >> 2, h = i & 3;
    Cs[CSW(k * 8 + h)] = C1[i];
    Cs[CSW(k * 8 + 4 + h)] = C2[i];
  }
  __syncthreads();
  int wave = tid >> 6, lane = tid & 63;
  int n = blockIdx.x * 4 + wave;
  if (n >= M) return;
  float4 xv = ((const float4*)(X + (size_t)n * KIN))[lane];
  float xs[4] = {xv.x, xv.y, xv.z, xv.w};
  u16x4 pk;
  pk[0] = f2bf(xs[0]); pk[1] = f2bf(xs[1]); pk[2] = f2bf(xs[2]); pk[3] = f2bf(xs[3]);
  *(u16x4*)(Xb + (size_t)n * KIN + lane * 4) = pk;
  float acc[8] = {0.f, 0.f, 0.f, 0.f, 0.f, 0.f, 0.f, 0.f};
#pragma unroll
  for (int j = 0; j < 4; j++) {
    int k = lane * 4 + j;
#pragma unroll
    for (int t = 0; t < 8; t++) acc[t] = fmaf(xs[j], Cs[CSW(k * 8 + t)], acc[t]);
  }
#pragma unroll
  for (int off = 32; off >= 1; off >>= 1)
#pragma unroll
    for (int t = 0; t < 8; t++) acc[t] += __shfl_xor(acc[t], off);
  if (lane == 0) {
#pragma unroll
    for (int h = 0; h < HH; h++) {
      o1[(size_t)n * HH + h] = acc[h];
      o2[(size_t)n * HH + h] = acc[4 + h];
    }
  }
}

// ---------------- fallback skinny (no bf16 feature copy)
__global__ __launch_bounds__(256) void skinny8(
    const float* __restrict__ X, const float* __restrict__ C1, const float* __restrict__ C2,
    float* __restrict__ o1, float* __restrict__ o2, int M) {
  __shared__ float Cs[KIN * 8];
  int tid = threadIdx.x;
  for (int i = tid; i < KIN * 4; i += 256) {
    int k = i >> 2, h = i & 3;
    Cs[CSW(k * 8 + h)] = C1[i];
    Cs[CSW(k * 8 + 4 + h)] = C2[i];
  }
  __syncthreads();
  int wave = tid >> 6, lane = tid & 63;
  int n = blockIdx.x * 4 + wave;
  if (n >= M) return;
  float4 xv = ((const float4*)(X + (size_t)n * KIN))[lane];
  float xs[4] = {xv.x, xv.y, xv.z, xv.w};
  float acc[8] = {0.f, 0.f, 0.f, 0.f, 0.f, 0.f, 0.f, 0.f};
#pragma unroll
  for (int j = 0; j < 4; j++) {
    int k = lane * 4 + j;
#pragma unroll
    for (int t = 0; t < 8; t++) acc[t] = fmaf(xs[j], Cs[CSW(k * 8 + t)], acc[t]);
  }
#pragma unroll
  for (int off = 32; off >= 1; off >>= 1)
#pragma unroll
    for (int t = 0; t < 8; t++) acc[t] += __shfl_xor(acc[t], off);
  if (lane == 0) {
#pragma unroll
    for (int h = 0; h < HH; h++) {
      o1[(size_t)n * HH + h] = acc[h];
      o2[(size_t)n * HH + h] = acc[4 + h];
    }
  }
}

// ---------------- CSR build ----------------
__global__ __launch_bounds__(256) void hist2(
    const int* __restrict__ d1, const int* __restrict__ d2,
    int* __restrict__ c1, int* __restrict__ c2) {
  int gid = blockIdx.x * 256 + threadIdx.x;
  if (gid < EE) atomicAdd(&c1[d1[gid]], 1);
  else if (gid < 2 * EE) atomicAdd(&c2[d2[gid - EE]], 1);
}

__global__ __launch_bounds__(256) void scan_chunk(
    const int* __restrict__ c1, const int* __restrict__ c2,
    int* __restrict__ rp1, int* __restrict__ rp2, int* __restrict__ bsum) {
  int rel = blockIdx.y;
  const int* counts = rel ? c2 : c1;
  int* rowptr = rel ? rp2 : rp1;
  int* bs = bsum + rel * 128;
  __shared__ int sd[256];
  int tid = threadIdx.x;
  int base = blockIdx.x * 1024 + tid * 4;
  int c[4];
#pragma unroll
  for (int j = 0; j < 4; j++) c[j] = (base + j < NN) ? counts[base + j] : 0;
  int tot = c[0] + c[1] + c[2] + c[3];
  sd[tid] = tot; __syncthreads();
  for (int o = 1; o < 256; o <<= 1) {
    int v = (tid >= o) ? sd[tid - o] : 0;
    __syncthreads();
    sd[tid] += v;
    __syncthreads();
  }
  int excl = sd[tid] - tot;
  int run = excl;
#pragma unroll
  for (int j = 0; j < 4; j++) {
    if (base + j < NN) rowptr[base + j] = run;
    run += c[j];
  }
  if (tid == 255) bs[blockIdx.x] = sd[255];
}

__global__ __launch_bounds__(128) void scan_bsum(int* __restrict__ bsum) {
  int rel = blockIdx.y;
  int* bs = bsum + rel * 128;
  __shared__ int sd[128];
  int tid = threadIdx.x;
  int v = (tid < NB_SCAN) ? bs[tid] : 0;
  sd[tid] = v; __syncthreads();
  for (int o = 1; o < 128; o <<= 1) {
    int t = (tid >= o) ? sd[tid - o] : 0;
    __syncthreads();
    sd[tid] += t;
    __syncthreads();
  }
  bs[tid] = sd[tid] - v;
}

__global__ __launch_bounds__(256) void addoff2(
    int* __restrict__ rp1, int* __restrict__ rp2,
    int* __restrict__ cur1, int* __restrict__ cur2,
    const int* __restrict__ bsum) {
  int rel = blockIdx.y;
  int* rowptr = rel ? rp2 : rp1;
  int* cur = rel ? cur2 : cur1;
  const int* bs = bsum + rel * 128;
  int i = blockIdx.x * 256 + threadIdx.x;
  if (i < NN) {
    int r = rowptr[i] + bs[i >> 10];
    rowptr[i] = r;
    cur[i] = r;
  }
  if (i == 0) rowptr[NN] = EE;
}

// ---------------- fill CSR: src id + per-edge exp coeffs (NO denominator atomics)
__global__ __launch_bounds__(256) void fill_s(
    const int* __restrict__ e1s, const int* __restrict__ e1d,
    const int* __restrict__ e2s, const int* __restrict__ e2d,
    const float* __restrict__ el1, const float* __restrict__ er1,
    const float* __restrict__ el2, const float* __restrict__ er2,
    int* __restrict__ cur1, int* __restrict__ cur2,
    int* __restrict__ adj1, int* __restrict__ adj2,
    float* __restrict__ wexp1, float* __restrict__ wexp2) {
  int gid = blockIdx.x * 256 + threadIdx.x;
  int rel = (gid >= EE);
  if (gid >= 2 * EE) return;
  int e = rel ? gid - EE : gid;
  const int* srcp = rel ? e2s : e1s;
  const int* dstp = rel ? e2d : e1d;
  const float* el = rel ? el2 : el1;
  const float* er = rel ? er2 : er1;
  int* cur = rel ? cur2 : cur1;
  int* adj = rel ? adj2 : adj1;
  float* wexp = rel ? wexp2 : wexp1;
  int si = srcp[e], di = dstp[e];
  int p = atomicAdd(&cur[di], 1);
  adj[p] = si;
  float4 l = *(const float4*)(el + (size_t)si * HH);
  float4 r = *(const float4*)(er + (size_t)di * HH);
  float v0 = l.x + r.x, v1 = l.y + r.y, v2 = l.z + r.z, v3 = l.w + r.w;
  v0 = v0 > 0.f ? v0 : SLOPE * v0; v1 = v1 > 0.f ? v1 : SLOPE * v1;
  v2 = v2 > 0.f ? v2 : SLOPE * v2; v3 = v3 > 0.f ? v3 : SLOPE * v3;
  *(float4*)(wexp + (size_t)p * HH) =
      make_float4(__expf(v0), __expf(v1), __expf(v2), __expf(v3));
}

// ---------------- MFMA GEMM: C[M x N] = A[M x 256] @ Wt[N x 256]^T
// 1-D grid, XCD-bijective swizzle, col fastest (A L2 reuse).
// ABF=1: bf16 A; staging via global_load_lds(16B), linear LDS dest +
// inverse-swizzled per-lane global source (XOR stays within each 128B K-window).
template <int ABF>
__global__ __launch_bounds__(256) void mfma_gemm(
    const void* __restrict__ Av, const short* __restrict__ Wt,
    void* __restrict__ Cout, int ldC, int M, int write_bf, int ncol) {
  __shared__ short As[128 * 64];
  __shared__ short Bs[128 * 64];
  int nwg = gridDim.x;
  int q = nwg >> 3, r = nwg & 7;
  int xcd = blockIdx.x & 7, seq = blockIdx.x >> 3;
  int lid = (xcd < r) ? (xcd * (q + 1) + seq) : (r * (q + 1) + (xcd - r) * q + seq);
  int row0 = (lid / ncol) * 128;
  int col0 = (lid % ncol) * 128;

  int tid = threadIdx.x;
  int lane = tid & 63, wid = tid >> 6;
  int wm = wid >> 1, wn = wid & 1;

  f32x4 acc[4][4];
#pragma unroll
  for (int i = 0; i < 4; i++)
#pragma unroll
    for (int j = 0; j < 4; j++) acc[i][j] = (f32x4){0.f, 0.f, 0.f, 0.f};

  int am = tid >> 1;
  int akh = (tid & 1) * 32;
  bool arow_ok = (row0 + am) < M;

  for (int k0 = 0; k0 < KIN; k0 += 64) {
    __syncthreads();
    if (ABF) {
      // ---- async staging: 4 calls A + 4 calls B per wave
      int rr8 = lane >> 3;            // 0..7 row within the 8-row chunk
      int bby = (lane & 7) * 16;      // byte chunk within 128B K-window
#pragma unroll
      for (int c2 = 0; c2 < 4; c2++) {
        int rr = wid * 32 + c2 * 8 + rr8;
        int rg = row0 + rr; if (rg > M - 1) rg = M - 1;
        int sb = bby ^ ((rr & 7) << 4);
        gload_lds16((const char*)Av + (size_t)rg * (KIN * 2) + k0 * 2 + sb,
                    (char*)As + wid * 4096 + c2 * 1024);
      }
#pragma unroll
      for (int c2 = 0; c2 < 4; c2++) {
        int rr = wid * 32 + c2 * 8 + rr8;
        int sb = bby ^ ((rr & 7) << 4);
        gload_lds16((const char*)Wt + (size_t)(col0 + rr) * (KIN * 2) + k0 * 2 + sb,
                    (char*)Bs + wid * 4096 + c2 * 1024);
      }
    } else {
      const float* xp = (const float*)Av + (size_t)(row0 + am) * KIN + k0 + akh;
#pragma unroll
      for (int c = 0; c < 4; c++) {
        float4 v0, v1;
        if (arow_ok) {
          v0 = *(const float4*)(xp + c * 8);
          v1 = *(const float4*)(xp + c * 8 + 4);
        } else {
          v0 = make_float4(0.f, 0.f, 0.f, 0.f);
          v1 = v0;
        }
        bf16x8 pk;
        pk[0] = (short)f2bf(v0.x); pk[1] = (short)f2bf(v0.y);
        pk[2] = (short)f2bf(v0.z); pk[3] = (short)f2bf(v0.w);
        pk[4] = (short)f2bf(v1.x); pk[5] = (short)f2bf(v1.y);
        pk[6] = (short)f2bf(v1.z); pk[7] = (short)f2bf(v1.w);
        int kc = akh + c * 8;
        int ad = (am * 128 + kc * 2) ^ ((am & 7) << 4);
        *(bf16x8*)((char*)As + ad) = pk;
      }
      int bn = tid >> 1;
      int bkh = (tid & 1) * 32;
      const short* wp = Wt + (size_t)(col0 + bn) * KIN + k0 + bkh;
#pragma unroll
      for (int c = 0; c < 4; c++) {
        bf16x8 pv = *(const bf16x8*)(wp + c * 8);
        int kc = bkh + c * 8;
        int bd = (bn * 128 + kc * 2) ^ ((bn & 7) << 4);
        *(bf16x8*)((char*)Bs + bd) = pv;
      }
    }
    __syncthreads();
#pragma unroll
    for (int ks = 0; ks < 2; ks++) {
      int kb = ks * 32 + (lane >> 4) * 8;
      bf16x8 af[4], bfv[4];
#pragma unroll
      for (int mf = 0; mf < 4; mf++) {
        int rr = wm * 64 + mf * 16 + (lane & 15);
        int ad = (rr * 128 + kb * 2) ^ ((rr & 7) << 4);
        af[mf] = *(bf16x8*)((char*)As + ad);
      }
#pragma unroll
      for (int nf = 0; nf < 4; nf++) {
        int cc = wn * 64 + nf * 16 + (lane & 15);
        int bd = (cc * 128 + kb * 2) ^ ((cc & 7) << 4);
        bfv[nf] = *(bf16x8*)((char*)Bs + bd);
      }
#pragma unroll
      for (int mf = 0; mf < 4; mf++)
#pragma unroll
        for (int nf = 0; nf < 4; nf++)
          acc[mf][nf] = __builtin_amdgcn_mfma_f32_16x16x32_bf16(af[mf], bfv[nf], acc[mf][nf], 0, 0, 0);
    }
  }
  int lr = lane >> 4, lc = lane & 15;
#pragma unroll
  for (int mf = 0; mf < 4; mf++) {
#pragma unroll
    for (int r4 = 0; r4 < 4; r4++) {
      int row = row0 + wm * 64 + mf * 16 + lr * 4 + r4;
      if (row < M) {
#pragma unroll
        for (int nf = 0; nf < 4; nf++) {
          int col = col0 + wn * 64 + nf * 16 + lc;
          float v = acc[mf][nf][r4];
          if (write_bf) ((unsigned short*)Cout)[(size_t)row * ldC + col] = f2bf(v);
          else ((float*)Cout)[(size_t)row * ldC + col] = v;
        }
      }
    }
  }
}

// ---------------- single-pass agg + mean + residual + LN + GELU (one wave/dst)
// lane l: head (l>>4), dims 8*(l&15)..+8. Denominator folded: m = (Σ w·fs)·(0.25/Σw).
__global__ __launch_bounds__(256) void agg2(
    const int* __restrict__ rowptr, const int* __restrict__ adj,
    const float* __restrict__ wexp,
    const unsigned short* __restrict__ fsb,
    const float* __restrict__ bm,
    const float* __restrict__ g, const float* __restrict__ be,
    float* __restrict__ out, int M) {
  int wave = threadIdx.x >> 6, lane = threadIdx.x & 63;
  int n = blockIdx.x * 4 + wave;
  if (n >= M) return;
  int beg = rowptr[n], end = rowptr[n + 1];
  int lh = lane >> 4, lc = lane & 15;
  float sh = 0.f;
  float m[8] = {0.f, 0.f, 0.f, 0.f, 0.f, 0.f, 0.f, 0.f};
  for (int t = beg; t < end; t++) {
    int si = adj[t];
    float wh = wexp[(size_t)t * HH + lh];
    sh += wh;
    uint4 u = *(const uint4*)(fsb + (size_t)si * HD + lane * 8);
    m[0] = fmaf(wh, bf_lo(u.x), m[0]); m[1] = fmaf(wh, bf_hi(u.x), m[1]);
    m[2] = fmaf(wh, bf_lo(u.y), m[2]); m[3] = fmaf(wh, bf_hi(u.y), m[3]);
    m[4] = fmaf(wh, bf_lo(u.z), m[4]); m[5] = fmaf(wh, bf_hi(u.z), m[5]);
    m[6] = fmaf(wh, bf_lo(u.w), m[6]); m[7] = fmaf(wh, bf_hi(u.w), m[7]);
  }
  float rsh = sh > 0.f ? 0.25f / sh : 0.f;
#pragma unroll
  for (int j = 0; j < 8; j++) m[j] *= rsh;
  // head reduce across the 4 lane groups
#pragma unroll
  for (int j = 0; j < 8; j++) {
    m[j] += __shfl_xor(m[j], 16);
    m[j] += __shfl_xor(m[j], 32);
  }
  const float4* bmp = (const float4*)(bm + lc * 8);
  float4 b0 = bmp[0], b1 = bmp[1];
  const float4* orow = (const float4*)(out + (size_t)n * DD + lc * 8);
  float4 p0 = orow[0], p1 = orow[1];
  float c[8];
  c[0] = m[0] + b0.x + p0.x; c[1] = m[1] + b0.y + p0.y;
  c[2] = m[2] + b0.z + p0.z; c[3] = m[3] + b0.w + p0.w;
  c[4] = m[4] + b1.x + p1.x; c[5] = m[5] + b1.y + p1.y;
  c[6] = m[6] + b1.z + p1.z; c[7] = m[7] + b1.w + p1.w;
  float ss = c[0] + c[1] + c[2] + c[3] + c[4] + c[5] + c[6] + c[7];
  ss += __shfl_xor(ss, 1); ss += __shfl_xor(ss, 2);
  ss += __shfl_xor(ss, 4); ss += __shfl_xor(ss, 8);
  float mu = ss * (1.f / 128.f);
  float vv = 0.f;
#pragma unroll
  for (int j = 0; j < 8; j++) { float d = c[j] - mu; vv = fmaf(d, d, vv); }
  vv += __shfl_xor(vv, 1); vv += __shfl_xor(vv, 2);
  vv += __shfl_xor(vv, 4); vv += __shfl_xor(vv, 8);
  float inv = rsqrtf(vv * (1.f / 128.f) + LN_EPS);
  const float4* gp = (const float4*)(g + lc * 8);
  const float4* bep = (const float4*)(be + lc * 8);
  float4 g0 = gp[0], g1 = gp[1];
  float4 e0 = bep[0], e1 = bep[1];
  float gv[8] = {g0.x, g0.y, g0.z, g0.w, g1.x, g1.y, g1.z, g1.w};
  float ev[8] = {e0.x, e0.y, e0.z, e0.w, e1.x, e1.y, e1.z, e1.w};
  float o[8];
#pragma unroll
  for (int j = 0; j < 8; j++) {
    float y = (c[j] - mu) * inv * gv[j] + ev[j];
    o[j] = gelu_fast(y);
  }
  if (lane < 16) {
    float4* op = (float4*)(out + (size_t)n * DD + lane * 8);
    op[0] = make_float4(o[0], o[1], o[2], o[3]);
    op[1] = make_float4(o[4], o[5], o[6], o[7]);
  }
}

extern "C" void kernel_launch(void* const* d_in, const int* in_sizes, int n_in,
                              void* d_out, int out_size, void* d_ws, size_t ws_size,
                              hipStream_t stream) {
  const float* feat_host = (const float*)d_in[0];
  const float* feat_flow = (const float*)d_in[1];
  const float* W1  = (const float*)d_in[2];
  const float* al1 = (const float*)d_in[3];
  const float* ar1 = (const float*)d_in[4];
  const float* b1  = (const float*)d_in[5];
  const float* W2  = (const float*)d_in[6];
  const float* al2 = (const float*)d_in[7];
  const float* ar2 = (const float*)d_in[8];
  const float* b2  = (const float*)d_in[9];
  const float* pWh = (const float*)d_in[10];
  const float* pbh = (const float*)d_in[11];
  const float* pWf = (const float*)d_in[12];
  const float* pbf = (const float*)d_in[13];
  const float* gh  = (const float*)d_in[14];
  const float* beh = (const float*)d_in[15];
  const float* gf  = (const float*)d_in[16];
  const float* bef = (const float*)d_in[17];
  const int* e1s = (const int*)d_in[18];
  const int* e1d = (const int*)d_in[19];
  const int* e2s = (const int*)d_in[20];
  const int* e2d = (const int*)d_in[21];

  float* out = (float*)d_out;
  float* host_out = out;                       // [NN,128]
  float* flow_out = out + (size_t)NN * DD;     // [NN,128]

  float* ws = (float*)d_ws;
  size_t off = 0;
  unsigned short* fsb = (unsigned short*)(ws + off); off += (size_t)NN * 256;  // NN x 512 bf16
  short* W1t  = (short*)(ws + off); off += (512 * 256) / 2;
  short* W2t  = (short*)(ws + off); off += (512 * 256) / 2;
  short* pWht = (short*)(ws + off); off += (128 * 256) / 2;
  short* pWft = (short*)(ws + off); off += (128 * 256) / 2;
  float* el1b = ws + off; off += (size_t)NN * HH;
  float* er1b = ws + off; off += (size_t)NN * HH;
  float* el2b = ws + off; off += (size_t)NN * HH;
  float* er2b = ws + off; off += (size_t)NN * HH;
  float* Cbuf = ws + off; off += 4096;
  float* bm   = ws + off; off += 256;          // bm1 | bm2
  float* wexp1 = ws + off; off += (size_t)EE * HH;   // per-slot exp coeffs
  float* wexp2 = ws + off; off += (size_t)EE * HH;
  // CSR
  int* rp1  = (int*)(ws + off);      // NN+1
  int* rp2  = rp1 + (NN + 1);
  int* adj1 = rp2 + (NN + 1);        // EE (src ids)
  int* adj2 = adj1 + EE;
  int* bsum = adj2 + EE;             // 256
  int* cur1 = bsum + 256;            // NN } contiguous memset region (2*NN)
  int* cur2 = cur1 + NN;             // NN }
  off += (size_t)(2 * (NN + 1) + 2 * EE + 256 + 2 * NN + 4);
  // optional bf16 feature copies
  size_t base_bytes = (off + 1024) * sizeof(float);
  size_t featb_bytes = (size_t)NN * KIN * 2 * 2;
  bool use_featb = ws_size >= base_bytes + featb_bytes;
  short* fhb = nullptr;
  short* ffb = nullptr;
  if (use_featb) {
    fhb = (short*)(ws + off); off += (size_t)NN * KIN / 2;
    ffb = (short*)(ws + off); off += (size_t)NN * KIN / 2;
  }

  dim3 blk(256);
  int gx = (NN + 127) / 128;                 // 782 row tiles
  int pf_g = (NN + 3) / 4;
  int ag_g = (NN + 3) / 4;
  int ee2_g = (2 * EE + 255) / 256;
  int nn_g = (NN + 255) / 256;

  // ---- prep
  convw<<<512, blk, 0, stream>>>(W1, W2, pWh, pWf, W1t, W2t, pWht, pWft);
  make_c<<<dim3(1, 4), blk, 0, stream>>>(W1, al1, ar1, W2, al2, ar2, Cbuf);
  make_bm<<<1, blk, 0, stream>>>(b1, pbf, b2, pbh, bm);
  if (use_featb) {
    prep_feat<<<pf_g, blk, 0, stream>>>(feat_host, Cbuf + 0,    Cbuf + 3072, fhb, el1b, er2b, NN);
    prep_feat<<<pf_g, blk, 0, stream>>>(feat_flow, Cbuf + 1024, Cbuf + 2048, ffb, er1b, el2b, NN);
  } else {
    skinny8<<<pf_g, blk, 0, stream>>>(feat_host, Cbuf + 0,    Cbuf + 3072, el1b, er2b, NN);
    skinny8<<<pf_g, blk, 0, stream>>>(feat_flow, Cbuf + 1024, Cbuf + 2048, er1b, el2b, NN);
  }

  // ---- CSR + per-edge coeffs (no denominator atomics)
  hipMemsetAsync(cur1, 0, (size_t)2 * NN * sizeof(int), stream);
  hist2<<<ee2_g, blk, 0, stream>>>(e1d, e2d, cur1, cur2);
  scan_chunk<<<dim3(NB_SCAN, 2), blk, 0, stream>>>(cur1, cur2, rp1, rp2, bsum);
  scan_bsum<<<dim3(1, 2), 128, 0, stream>>>(bsum);
  addoff2<<<dim3(nn_g, 2), blk, 0, stream>>>(rp1, rp2, cur1, cur2, bsum);
  fill_s<<<ee2_g, blk, 0, stream>>>(e1s, e1d, e2s, e2d, el1b, er1b, el2b, er2b,
                                    cur1, cur2, adj1, adj2, wexp1, wexp2);

  // ---- relation 1: host -> flow (dst = flow, out = flow_out)
  if (use_featb) {
    mfma_gemm<1><<<gx, blk, 0, stream>>>(ffb, pWft, flow_out, DD, NN, 0, 1);
    mfma_gemm<1><<<gx * 4, blk, 0, stream>>>(fhb, W1t, fsb, HD, NN, 1, 4);
  } else {
    mfma_gemm<0><<<gx, blk, 0, stream>>>(feat_flow, pWft, flow_out, DD, NN, 0, 1);
    mfma_gemm<0><<<gx * 4, blk, 0, stream>>>(feat_host, W1t, fsb, HD, NN, 1, 4);
  }
  agg2<<<ag_g, blk, 0, stream>>>(rp1, adj1, wexp1, fsb, bm, gf, bef, flow_out, NN);

  // ---- relation 2: flow -> host (dst = host, out = host_out)
  if (use_featb) {
    mfma_gemm<1><<<gx, blk, 0, stream>>>(fhb, pWht, host_out, DD, NN, 0, 1);
    mfma_gemm<1><<<gx * 4, blk, 0, stream>>>(ffb, W2t, fsb, HD, NN, 1, 4);
  } else {
    mfma_gemm<0><<<gx, blk, 0, stream>>>(feat_host, pWht, host_out, DD, NN, 0, 1);
    mfma_gemm<0><<<gx * 4, blk, 0, stream>>>(feat_flow, W2t, fsb, HD, NN, 1, 4);
  }
  agg2<<<ag_g, blk, 0, stream>>>(rp2, adj2, wexp2, fsb, bm + 128, gh, beh, host_out, NN);
}

// Round 12
// 476.478 us; speedup vs baseline: 4.1383x; 1.1270x over previous
//
#include <hip/hip_runtime.h>
#include <math.h>

#define NN 100000      // nodes per type
#define EE 200000      // edges per relation
#define HH 4
#define DD 128
#define HD 512         // H*D
#define KIN 256        // input feature dim
#define LN_EPS 1e-5f
#define SLOPE 0.2f
#define NB_SCAN 98     // ceil(NN/1024)

// LDS bank-conflict swizzle for the Cs[2048] table (skinny8 fallback).
#define CSW(a) ((a) ^ (((a) >> 5) & 31))

typedef short bf16x8 __attribute__((ext_vector_type(8)));
typedef unsigned short u16x4 __attribute__((ext_vector_type(4)));
typedef float f32x4 __attribute__((ext_vector_type(4)));

typedef __attribute__((address_space(3))) unsigned int lds_uint;
typedef const __attribute__((address_space(1))) unsigned int glb_uint;

static __device__ __forceinline__ void gload_lds16(const void* g, void* l) {
  __builtin_amdgcn_global_load_lds((glb_uint*)g, (lds_uint*)l, 16, 0, 0);
}

static __device__ __forceinline__ unsigned short f2bf(float x) {
  unsigned int u = __float_as_uint(x);
  u += 0x7fffu + ((u >> 16) & 1u);   // RNE
  return (unsigned short)(u >> 16);
}
static __device__ __forceinline__ float bf_lo(unsigned int u) {
  return __uint_as_float(u << 16);
}
static __device__ __forceinline__ float bf_hi(unsigned int u) {
  return __uint_as_float(u & 0xffff0000u);
}

// Branch-free erf, Abramowitz-Stegun 7.1.26 (max err 1.5e-7).
static __device__ __forceinline__ float erf_fast(float x) {
  float ax = fabsf(x);
  float t = __builtin_amdgcn_rcpf(fmaf(0.3275911f, ax, 1.0f));
  float p = fmaf(1.061405429f, t, -1.453152027f);
  p = fmaf(p, t, 1.421413741f);
  p = fmaf(p, t, -0.284496736f);
  p = fmaf(p, t, 0.254829592f);
  p = p * t;
  float r = 1.0f - p * __expf(-ax * ax);
  return copysignf(r, x);
}
static __device__ __forceinline__ float gelu_fast(float y) {
  return 0.5f * y * (1.0f + erf_fast(y * 0.70710678118f));
}

// ---------------- convert + transpose weights to bf16 [N][K]
__global__ __launch_bounds__(256) void convw(
    const float* __restrict__ W1, const float* __restrict__ W2,
    const float* __restrict__ pWh, const float* __restrict__ pWf,
    short* __restrict__ W1t, short* __restrict__ W2t,
    short* __restrict__ pWht, short* __restrict__ pWft) {
  int idx = blockIdx.x * 256 + threadIdx.x;
  if (idx < 512 * 256) {
    int n = idx >> 8, k = idx & 255;
    W1t[idx] = (short)f2bf(W1[(size_t)k * HD + n]);
    W2t[idx] = (short)f2bf(W2[(size_t)k * HD + n]);
  }
  if (idx < 128 * 256) {
    int n = idx >> 8, k = idx & 255;
    pWht[idx] = (short)f2bf(pWh[(size_t)k * DD + n]);
    pWft[idx] = (short)f2bf(pWf[(size_t)k * DD + n]);
  }
}

// ---------------- build C[k,h] = sum_d W[k,h*128+d]*a[h*128+d]  (f32 + bf16 Ct)
// Ct layout [16][256] bf16 (row = output col of the skinny MFMA):
//   CtH rows 0-3 = W1*al1 (el1), rows 4-7 = W2*ar2 (er2), rows 8-15 = 0
//   CtF rows 0-3 = W1*ar1 (er1), rows 4-7 = W2*al2 (el2), rows 8-15 = 0
__global__ __launch_bounds__(256) void make_c(
    const float* __restrict__ W1, const float* __restrict__ al1, const float* __restrict__ ar1,
    const float* __restrict__ W2, const float* __restrict__ al2, const float* __restrict__ ar2,
    float* __restrict__ Cout, short* __restrict__ CtH, short* __restrict__ CtF) {
  int which = blockIdx.y;
  const float* W = (which < 2) ? W1 : W2;
  const float* a = (which == 0) ? al1 : (which == 1) ? ar1 : (which == 2) ? al2 : ar2;
  int k = threadIdx.x;
  float* C = Cout + (size_t)which * 1024;
#pragma unroll
  for (int h = 0; h < HH; h++) {
    float s = 0.f;
    for (int d = 0; d < DD; d++) s = fmaf(W[(size_t)k * HD + h * DD + d], a[h * DD + d], s);
    C[k * HH + h] = s;
    short b = (short)f2bf(s);
    if (which == 0)      CtH[h * KIN + k] = b;
    else if (which == 3) CtH[(4 + h) * KIN + k] = b;
    else if (which == 1) CtF[h * KIN + k] = b;
    else                 CtF[(4 + h) * KIN + k] = b;
  }
  if (which == 0) {
#pragma unroll
    for (int j = 0; j < 8; j++) CtH[(8 + j) * KIN + k] = 0;
  } else if (which == 1) {
#pragma unroll
    for (int j = 0; j < 8; j++) CtF[(8 + j) * KIN + k] = 0;
  }
}

// ---------------- bm1[d] = 0.25*sum_h b1 + pbf ; bm2 likewise (b2, pbh)
__global__ __launch_bounds__(256) void make_bm(
    const float* __restrict__ b1, const float* __restrict__ pbf,
    const float* __restrict__ b2, const float* __restrict__ pbh,
    float* __restrict__ bm) {
  int d = threadIdx.x;
  if (d < 128) {
    bm[d] = 0.25f * (b1[d] + b1[128 + d] + b1[256 + d] + b1[384 + d]) + pbf[d];
  } else {
    int dd = d - 128;
    bm[d] = 0.25f * (b2[dd] + b2[128 + dd] + b2[256 + dd] + b2[384 + dd]) + pbh[dd];
  }
}

// ---------------- fused bf16 convert + el/er dots via MFMA (one wave per 16 rows)
// A frag: lane holds X[row=lane&15][k=(lane>>4)*8..+8]; B frag: Ct[col=lane&15][same k].
// D: col=lane&15, row=(lane>>4)*4+r (m89 layout). Cols 0-3 -> o1, 4-7 -> o2.
__global__ __launch_bounds__(256) void prep_mfma(
    const float* __restrict__ XH, const float* __restrict__ XF,
    const short* __restrict__ CtH, const short* __restrict__ CtF,
    short* __restrict__ XbH, short* __restrict__ XbF,
    float* __restrict__ o1H, float* __restrict__ o2H,
    float* __restrict__ o1F, float* __restrict__ o2F, int M) {
  int which = blockIdx.y;
  const float* X = which ? XF : XH;
  const short* Ct = which ? CtF : CtH;
  short* Xb = which ? XbF : XbH;
  float* o1 = which ? o1F : o1H;
  float* o2 = which ? o2F : o2H;
  int tid = threadIdx.x, lane = tid & 63, wid = tid >> 6;
  int row0 = blockIdx.x * 64 + wid * 16;
  if (row0 >= M) return;
  int lr = lane & 15, lk = lane >> 4;
  bf16x8 bfrag[8];
#pragma unroll
  for (int kc = 0; kc < 8; kc++)
    bfrag[kc] = *(const bf16x8*)(Ct + lr * KIN + kc * 32 + lk * 8);
  int arow = row0 + lr;
  if (arow > M - 1) arow = M - 1;   // tail: duplicate row, same data rewritten (benign)
  const float* xp = X + (size_t)arow * KIN + lk * 8;
  short* xbp = Xb + (size_t)arow * KIN + lk * 8;
  f32x4 acc = (f32x4){0.f, 0.f, 0.f, 0.f};
#pragma unroll
  for (int kc = 0; kc < 8; kc++) {
    float4 v0 = *(const float4*)(xp + kc * 32);
    float4 v1 = *(const float4*)(xp + kc * 32 + 4);
    bf16x8 af;
    af[0] = (short)f2bf(v0.x); af[1] = (short)f2bf(v0.y);
    af[2] = (short)f2bf(v0.z); af[3] = (short)f2bf(v0.w);
    af[4] = (short)f2bf(v1.x); af[5] = (short)f2bf(v1.y);
    af[6] = (short)f2bf(v1.z); af[7] = (short)f2bf(v1.w);
    *(bf16x8*)(xbp + kc * 32) = af;
    acc = __builtin_amdgcn_mfma_f32_16x16x32_bf16(af, bfrag[kc], acc, 0, 0, 0);
  }
  if (lr < 8) {
    int rbase = row0 + lk * 4;
#pragma unroll
    for (int r = 0; r < 4; r++) {
      int row = rbase + r;
      if (row < M) {
        if (lr < 4) o1[(size_t)row * HH + lr] = acc[r];
        else        o2[(size_t)row * HH + (lr - 4)] = acc[r];
      }
    }
  }
}

// ---------------- fallback skinny (no bf16 feature copy)
__global__ __launch_bounds__(256) void skinny8(
    const float* __restrict__ X, const float* __restrict__ C1, const float* __restrict__ C2,
    float* __restrict__ o1, float* __restrict__ o2, int M) {
  __shared__ float Cs[KIN * 8];
  int tid = threadIdx.x;
  for (int i = tid; i < KIN * 4; i += 256) {
    int k = i >> 2, h = i & 3;
    Cs[CSW(k * 8 + h)] = C1[i];
    Cs[CSW(k * 8 + 4 + h)] = C2[i];
  }
  __syncthreads();
  int wave = tid >> 6, lane = tid & 63;
  int n = blockIdx.x * 4 + wave;
  if (n >= M) return;
  float4 xv = ((const float4*)(X + (size_t)n * KIN))[lane];
  float xs[4] = {xv.x, xv.y, xv.z, xv.w};
  float acc[8] = {0.f, 0.f, 0.f, 0.f, 0.f, 0.f, 0.f, 0.f};
#pragma unroll
  for (int j = 0; j < 4; j++) {
    int k = lane * 4 + j;
#pragma unroll
    for (int t = 0; t < 8; t++) acc[t] = fmaf(xs[j], Cs[CSW(k * 8 + t)], acc[t]);
  }
#pragma unroll
  for (int off = 32; off >= 1; off >>= 1)
#pragma unroll
    for (int t = 0; t < 8; t++) acc[t] += __shfl_xor(acc[t], off);
  if (lane == 0) {
#pragma unroll
    for (int h = 0; h < HH; h++) {
      o1[(size_t)n * HH + h] = acc[h];
      o2[(size_t)n * HH + h] = acc[4 + h];
    }
  }
}

// ---------------- CSR build ----------------
__global__ __launch_bounds__(256) void hist2(
    const int* __restrict__ d1, const int* __restrict__ d2,
    int* __restrict__ c1, int* __restrict__ c2) {
  int gid = blockIdx.x * 256 + threadIdx.x;
  if (gid < EE) atomicAdd(&c1[d1[gid]], 1);
  else if (gid < 2 * EE) atomicAdd(&c2[d2[gid - EE]], 1);
}

__global__ __launch_bounds__(256) void scan_chunk(
    const int* __restrict__ c1, const int* __restrict__ c2,
    int* __restrict__ rp1, int* __restrict__ rp2, int* __restrict__ bsum) {
  int rel = blockIdx.y;
  const int* counts = rel ? c2 : c1;
  int* rowptr = rel ? rp2 : rp1;
  int* bs = bsum + rel * 128;
  __shared__ int sd[256];
  int tid = threadIdx.x;
  int base = blockIdx.x * 1024 + tid * 4;
  int c[4];
#pragma unroll
  for (int j = 0; j < 4; j++) c[j] = (base + j < NN) ? counts[base + j] : 0;
  int tot = c[0] + c[1] + c[2] + c[3];
  sd[tid] = tot; __syncthreads();
  for (int o = 1; o < 256; o <<= 1) {
    int v = (tid >= o) ? sd[tid - o] : 0;
    __syncthreads();
    sd[tid] += v;
    __syncthreads();
  }
  int excl = sd[tid] - tot;
  int run = excl;
#pragma unroll
  for (int j = 0; j < 4; j++) {
    if (base + j < NN) rowptr[base + j] = run;
    run += c[j];
  }
  if (tid == 255) bs[blockIdx.x] = sd[255];
}

__global__ __launch_bounds__(128) void scan_bsum(int* __restrict__ bsum) {
  int rel = blockIdx.y;
  int* bs = bsum + rel * 128;
  __shared__ int sd[128];
  int tid = threadIdx.x;
  int v = (tid < NB_SCAN) ? bs[tid] : 0;
  sd[tid] = v; __syncthreads();
  for (int o = 1; o < 128; o <<= 1) {
    int t = (tid >= o) ? sd[tid - o] : 0;
    __syncthreads();
    sd[tid] += t;
    __syncthreads();
  }
  bs[tid] = sd[tid] - v;
}

__global__ __launch_bounds__(256) void addoff2(
    int* __restrict__ rp1, int* __restrict__ rp2,
    int* __restrict__ cur1, int* __restrict__ cur2,
    const int* __restrict__ bsum) {
  int rel = blockIdx.y;
  int* rowptr = rel ? rp2 : rp1;
  int* cur = rel ? cur2 : cur1;
  const int* bs = bsum + rel * 128;
  int i = blockIdx.x * 256 + threadIdx.x;
  if (i < NN) {
    int r = rowptr[i] + bs[i >> 10];
    rowptr[i] = r;
    cur[i] = r;
  }
  if (i == 0) rowptr[NN] = EE;
}

// ---------------- fill CSR: src id + per-edge exp coeffs (NO denominator atomics)
__global__ __launch_bounds__(256) void fill_s(
    const int* __restrict__ e1s, const int* __restrict__ e1d,
    const int* __restrict__ e2s, const int* __restrict__ e2d,
    const float* __restrict__ el1, const float* __restrict__ er1,
    const float* __restrict__ el2, const float* __restrict__ er2,
    int* __restrict__ cur1, int* __restrict__ cur2,
    int* __restrict__ adj1, int* __restrict__ adj2,
    float* __restrict__ wexp1, float* __restrict__ wexp2) {
  int gid = blockIdx.x * 256 + threadIdx.x;
  int rel = (gid >= EE);
  if (gid >= 2 * EE) return;
  int e = rel ? gid - EE : gid;
  const int* srcp = rel ? e2s : e1s;
  const int* dstp = rel ? e2d : e1d;
  const float* el = rel ? el2 : el1;
  const float* er = rel ? er2 : er1;
  int* cur = rel ? cur2 : cur1;
  int* adj = rel ? adj2 : adj1;
  float* wexp = rel ? wexp2 : wexp1;
  int si = srcp[e], di = dstp[e];
  int p = atomicAdd(&cur[di], 1);
  adj[p] = si;
  float4 l = *(const float4*)(el + (size_t)si * HH);
  float4 r = *(const float4*)(er + (size_t)di * HH);
  float v0 = l.x + r.x, v1 = l.y + r.y, v2 = l.z + r.z, v3 = l.w + r.w;
  v0 = v0 > 0.f ? v0 : SLOPE * v0; v1 = v1 > 0.f ? v1 : SLOPE * v1;
  v2 = v2 > 0.f ? v2 : SLOPE * v2; v3 = v3 > 0.f ? v3 : SLOPE * v3;
  *(float4*)(wexp + (size_t)p * HH) =
      make_float4(__expf(v0), __expf(v1), __expf(v2), __expf(v3));
}

// ---------------- MFMA GEMM: C[M x N] = A[M x 256] @ Wt[N x 256]^T
// 1-D grid, XCD-bijective swizzle, col fastest (A L2 reuse).
// ABF=1: bf16 A; staging via global_load_lds(16B), linear LDS dest +
// inverse-swizzled per-lane global source (XOR stays within each 128B K-window).
template <int ABF>
__global__ __launch_bounds__(256) void mfma_gemm(
    const void* __restrict__ Av, const short* __restrict__ Wt,
    void* __restrict__ Cout, int ldC, int M, int write_bf, int ncol) {
  __shared__ short As[128 * 64];
  __shared__ short Bs[128 * 64];
  int nwg = gridDim.x;
  int q = nwg >> 3, r = nwg & 7;
  int xcd = blockIdx.x & 7, seq = blockIdx.x >> 3;
  int lid = (xcd < r) ? (xcd * (q + 1) + seq) : (r * (q + 1) + (xcd - r) * q + seq);
  int row0 = (lid / ncol) * 128;
  int col0 = (lid % ncol) * 128;

  int tid = threadIdx.x;
  int lane = tid & 63, wid = tid >> 6;
  int wm = wid >> 1, wn = wid & 1;

  f32x4 acc[4][4];
#pragma unroll
  for (int i = 0; i < 4; i++)
#pragma unroll
    for (int j = 0; j < 4; j++) acc[i][j] = (f32x4){0.f, 0.f, 0.f, 0.f};

  int am = tid >> 1;
  int akh = (tid & 1) * 32;
  bool arow_ok = (row0 + am) < M;

  for (int k0 = 0; k0 < KIN; k0 += 64) {
    __syncthreads();
    if (ABF) {
      int rr8 = lane >> 3;
      int bby = (lane & 7) * 16;
#pragma unroll
      for (int c2 = 0; c2 < 4; c2++) {
        int rr = wid * 32 + c2 * 8 + rr8;
        int rg = row0 + rr; if (rg > M - 1) rg = M - 1;
        int sb = bby ^ ((rr & 7) << 4);
        gload_lds16((const char*)Av + (size_t)rg * (KIN * 2) + k0 * 2 + sb,
                    (char*)As + wid * 4096 + c2 * 1024);
      }
#pragma unroll
      for (int c2 = 0; c2 < 4; c2++) {
        int rr = wid * 32 + c2 * 8 + rr8;
        int sb = bby ^ ((rr & 7) << 4);
        gload_lds16((const char*)Wt + (size_t)(col0 + rr) * (KIN * 2) + k0 * 2 + sb,
                    (char*)Bs + wid * 4096 + c2 * 1024);
      }
    } else {
      const float* xp = (const float*)Av + (size_t)(row0 + am) * KIN + k0 + akh;
#pragma unroll
      for (int c = 0; c < 4; c++) {
        float4 v0, v1;
        if (arow_ok) {
          v0 = *(const float4*)(xp + c * 8);
          v1 = *(const float4*)(xp + c * 8 + 4);
        } else {
          v0 = make_float4(0.f, 0.f, 0.f, 0.f);
          v1 = v0;
        }
        bf16x8 pk;
        pk[0] = (short)f2bf(v0.x); pk[1] = (short)f2bf(v0.y);
        pk[2] = (short)f2bf(v0.z); pk[3] = (short)f2bf(v0.w);
        pk[4] = (short)f2bf(v1.x); pk[5] = (short)f2bf(v1.y);
        pk[6] = (short)f2bf(v1.z); pk[7] = (short)f2bf(v1.w);
        int kc = akh + c * 8;
        int ad = (am * 128 + kc * 2) ^ ((am & 7) << 4);
        *(bf16x8*)((char*)As + ad) = pk;
      }
      int bn = tid >> 1;
      int bkh = (tid & 1) * 32;
      const short* wp = Wt + (size_t)(col0 + bn) * KIN + k0 + bkh;
#pragma unroll
      for (int c = 0; c < 4; c++) {
        bf16x8 pv = *(const bf16x8*)(wp + c * 8);
        int kc = bkh + c * 8;
        int bd = (bn * 128 + kc * 2) ^ ((bn & 7) << 4);
        *(bf16x8*)((char*)Bs + bd) = pv;
      }
    }
    __syncthreads();
#pragma unroll
    for (int ks = 0; ks < 2; ks++) {
      int kb = ks * 32 + (lane >> 4) * 8;
      bf16x8 af[4], bfv[4];
#pragma unroll
      for (int mf = 0; mf < 4; mf++) {
        int rr = wm * 64 + mf * 16 + (lane & 15);
        int ad = (rr * 128 + kb * 2) ^ ((rr & 7) << 4);
        af[mf] = *(bf16x8*)((char*)As + ad);
      }
#pragma unroll
      for (int nf = 0; nf < 4; nf++) {
        int cc = wn * 64 + nf * 16 + (lane & 15);
        int bd = (cc * 128 + kb * 2) ^ ((cc & 7) << 4);
        bfv[nf] = *(bf16x8*)((char*)Bs + bd);
      }
#pragma unroll
      for (int mf = 0; mf < 4; mf++)
#pragma unroll
        for (int nf = 0; nf < 4; nf++)
          acc[mf][nf] = __builtin_amdgcn_mfma_f32_16x16x32_bf16(af[mf], bfv[nf], acc[mf][nf], 0, 0, 0);
    }
  }
  int lr = lane >> 4, lc = lane & 15;
#pragma unroll
  for (int mf = 0; mf < 4; mf++) {
#pragma unroll
    for (int r4 = 0; r4 < 4; r4++) {
      int row = row0 + wm * 64 + mf * 16 + lr * 4 + r4;
      if (row < M) {
#pragma unroll
        for (int nf = 0; nf < 4; nf++) {
          int col = col0 + wn * 64 + nf * 16 + lc;
          float v = acc[mf][nf][r4];
          if (write_bf) ((unsigned short*)Cout)[(size_t)row * ldC + col] = f2bf(v);
          else ((float*)Cout)[(size_t)row * ldC + col] = v;
        }
      }
    }
  }
}

// ---------------- single-pass agg + mean + residual + LN + GELU (one wave/dst)
__global__ __launch_bounds__(256) void agg2(
    const int* __restrict__ rowptr, const int* __restrict__ adj,
    const float* __restrict__ wexp,
    const unsigned short* __restrict__ fsb,
    const float* __restrict__ bm,
    const float* __restrict__ g, const float* __restrict__ be,
    float* __restrict__ out, int M) {
  int wave = threadIdx.x >> 6, lane = threadIdx.x & 63;
  int n = blockIdx.x * 4 + wave;
  if (n >= M) return;
  int beg = rowptr[n], end = rowptr[n + 1];
  int lh = lane >> 4, lc = lane & 15;
  float sh = 0.f;
  float m[8] = {0.f, 0.f, 0.f, 0.f, 0.f, 0.f, 0.f, 0.f};
  for (int t = beg; t < end; t++) {
    int si = adj[t];
    float wh = wexp[(size_t)t * HH + lh];
    sh += wh;
    uint4 u = *(const uint4*)(fsb + (size_t)si * HD + lane * 8);
    m[0] = fmaf(wh, bf_lo(u.x), m[0]); m[1] = fmaf(wh, bf_hi(u.x), m[1]);
    m[2] = fmaf(wh, bf_lo(u.y), m[2]); m[3] = fmaf(wh, bf_hi(u.y), m[3]);
    m[4] = fmaf(wh, bf_lo(u.z), m[4]); m[5] = fmaf(wh, bf_hi(u.z), m[5]);
    m[6] = fmaf(wh, bf_lo(u.w), m[6]); m[7] = fmaf(wh, bf_hi(u.w), m[7]);
  }
  float rsh = sh > 0.f ? 0.25f / sh : 0.f;
#pragma unroll
  for (int j = 0; j < 8; j++) m[j] *= rsh;
#pragma unroll
  for (int j = 0; j < 8; j++) {
    m[j] += __shfl_xor(m[j], 16);
    m[j] += __shfl_xor(m[j], 32);
  }
  const float4* bmp = (const float4*)(bm + lc * 8);
  float4 b0 = bmp[0], b1 = bmp[1];
  const float4* orow = (const float4*)(out + (size_t)n * DD + lc * 8);
  float4 p0 = orow[0], p1 = orow[1];
  float c[8];
  c[0] = m[0] + b0.x + p0.x; c[1] = m[1] + b0.y + p0.y;
  c[2] = m[2] + b0.z + p0.z; c[3] = m[3] + b0.w + p0.w;
  c[4] = m[4] + b1.x + p1.x; c[5] = m[5] + b1.y + p1.y;
  c[6] = m[6] + b1.z + p1.z; c[7] = m[7] + b1.w + p1.w;
  float ss = c[0] + c[1] + c[2] + c[3] + c[4] + c[5] + c[6] + c[7];
  ss += __shfl_xor(ss, 1); ss += __shfl_xor(ss, 2);
  ss += __shfl_xor(ss, 4); ss += __shfl_xor(ss, 8);
  float mu = ss * (1.f / 128.f);
  float vv = 0.f;
#pragma unroll
  for (int j = 0; j < 8; j++) { float d = c[j] - mu; vv = fmaf(d, d, vv); }
  vv += __shfl_xor(vv, 1); vv += __shfl_xor(vv, 2);
  vv += __shfl_xor(vv, 4); vv += __shfl_xor(vv, 8);
  float inv = rsqrtf(vv * (1.f / 128.f) + LN_EPS);
  const float4* gp = (const float4*)(g + lc * 8);
  const float4* bep = (const float4*)(be + lc * 8);
  float4 g0 = gp[0], g1 = gp[1];
  float4 e0 = bep[0], e1 = bep[1];
  float gv[8] = {g0.x, g0.y, g0.z, g0.w, g1.x, g1.y, g1.z, g1.w};
  float ev[8] = {e0.x, e0.y, e0.z, e0.w, e1.x, e1.y, e1.z, e1.w};
  float o[8];
#pragma unroll
  for (int j = 0; j < 8; j++) {
    float y = (c[j] - mu) * inv * gv[j] + ev[j];
    o[j] = gelu_fast(y);
  }
  if (lane < 16) {
    float4* op = (float4*)(out + (size_t)n * DD + lane * 8);
    op[0] = make_float4(o[0], o[1], o[2], o[3]);
    op[1] = make_float4(o[4], o[5], o[6], o[7]);
  }
}

extern "C" void kernel_launch(void* const* d_in, const int* in_sizes, int n_in,
                              void* d_out, int out_size, void* d_ws, size_t ws_size,
                              hipStream_t stream) {
  const float* feat_host = (const float*)d_in[0];
  const float* feat_flow = (const float*)d_in[1];
  const float* W1  = (const float*)d_in[2];
  const float* al1 = (const float*)d_in[3];
  const float* ar1 = (const float*)d_in[4];
  const float* b1  = (const float*)d_in[5];
  const float* W2  = (const float*)d_in[6];
  const float* al2 = (const float*)d_in[7];
  const float* ar2 = (const float*)d_in[8];
  const float* b2  = (const float*)d_in[9];
  const float* pWh = (const float*)d_in[10];
  const float* pbh = (const float*)d_in[11];
  const float* pWf = (const float*)d_in[12];
  const float* pbf = (const float*)d_in[13];
  const float* gh  = (const float*)d_in[14];
  const float* beh = (const float*)d_in[15];
  const float* gf  = (const float*)d_in[16];
  const float* bef = (const float*)d_in[17];
  const int* e1s = (const int*)d_in[18];
  const int* e1d = (const int*)d_in[19];
  const int* e2s = (const int*)d_in[20];
  const int* e2d = (const int*)d_in[21];

  float* out = (float*)d_out;
  float* host_out = out;                       // [NN,128]
  float* flow_out = out + (size_t)NN * DD;     // [NN,128]

  float* ws = (float*)d_ws;
  size_t off = 0;
  unsigned short* fsb = (unsigned short*)(ws + off); off += (size_t)NN * 256;  // NN x 512 bf16
  short* W1t  = (short*)(ws + off); off += (512 * 256) / 2;
  short* W2t  = (short*)(ws + off); off += (512 * 256) / 2;
  short* pWht = (short*)(ws + off); off += (128 * 256) / 2;
  short* pWft = (short*)(ws + off); off += (128 * 256) / 2;
  float* el1b = ws + off; off += (size_t)NN * HH;
  float* er1b = ws + off; off += (size_t)NN * HH;
  float* el2b = ws + off; off += (size_t)NN * HH;
  float* er2b = ws + off; off += (size_t)NN * HH;
  float* Cbuf = ws + off; off += 4096;
  short* CtH  = (short*)(ws + off); off += 2048;     // 16x256 bf16
  short* CtF  = (short*)(ws + off); off += 2048;
  float* bm   = ws + off; off += 256;          // bm1 | bm2
  float* wexp1 = ws + off; off += (size_t)EE * HH;   // per-slot exp coeffs
  float* wexp2 = ws + off; off += (size_t)EE * HH;
  // CSR
  int* rp1  = (int*)(ws + off);      // NN+1
  int* rp2  = rp1 + (NN + 1);
  int* adj1 = rp2 + (NN + 1);        // EE (src ids)
  int* adj2 = adj1 + EE;
  int* bsum = adj2 + EE;             // 256
  int* cur1 = bsum + 256;            // NN } contiguous memset region (2*NN)
  int* cur2 = cur1 + NN;             // NN }
  off += (size_t)(2 * (NN + 1) + 2 * EE + 256 + 2 * NN + 4);
  // optional bf16 feature copies
  size_t base_bytes = (off + 1024) * sizeof(float);
  size_t featb_bytes = (size_t)NN * KIN * 2 * 2;
  bool use_featb = ws_size >= base_bytes + featb_bytes;
  short* fhb = nullptr;
  short* ffb = nullptr;
  if (use_featb) {
    fhb = (short*)(ws + off); off += (size_t)NN * KIN / 2;
    ffb = (short*)(ws + off); off += (size_t)NN * KIN / 2;
  }

  dim3 blk(256);
  int gx = (NN + 127) / 128;                 // 782 row tiles
  int pm_g = (NN + 63) / 64;                 // prep_mfma blocks (64 rows each)
  int sk_g = (NN + 3) / 4;
  int ag_g = (NN + 3) / 4;
  int ee2_g = (2 * EE + 255) / 256;
  int nn_g = (NN + 255) / 256;

  // ---- prep
  convw<<<512, blk, 0, stream>>>(W1, W2, pWh, pWf, W1t, W2t, pWht, pWft);
  make_c<<<dim3(1, 4), blk, 0, stream>>>(W1, al1, ar1, W2, al2, ar2, Cbuf, CtH, CtF);
  make_bm<<<1, blk, 0, stream>>>(b1, pbf, b2, pbh, bm);
  if (use_featb) {
    // fused: f32->bf16 convert + el/er skinny dots via MFMA (both matrices)
    prep_mfma<<<dim3(pm_g, 2), blk, 0, stream>>>(
        feat_host, feat_flow, CtH, CtF, fhb, ffb,
        el1b, er2b, er1b, el2b, NN);
  } else {
    skinny8<<<sk_g, blk, 0, stream>>>(feat_host, Cbuf + 0,    Cbuf + 3072, el1b, er2b, NN);
    skinny8<<<sk_g, blk, 0, stream>>>(feat_flow, Cbuf + 1024, Cbuf + 2048, er1b, el2b, NN);
  }

  // ---- CSR + per-edge coeffs (no denominator atomics)
  hipMemsetAsync(cur1, 0, (size_t)2 * NN * sizeof(int), stream);
  hist2<<<ee2_g, blk, 0, stream>>>(e1d, e2d, cur1, cur2);
  scan_chunk<<<dim3(NB_SCAN, 2), blk, 0, stream>>>(cur1, cur2, rp1, rp2, bsum);
  scan_bsum<<<dim3(1, 2), 128, 0, stream>>>(bsum);
  addoff2<<<dim3(nn_g, 2), blk, 0, stream>>>(rp1, rp2, cur1, cur2, bsum);
  fill_s<<<ee2_g, blk, 0, stream>>>(e1s, e1d, e2s, e2d, el1b, er1b, el2b, er2b,
                                    cur1, cur2, adj1, adj2, wexp1, wexp2);

  // ---- relation 1: host -> flow (dst = flow, out = flow_out)
  if (use_featb) {
    mfma_gemm<1><<<gx, blk, 0, stream>>>(ffb, pWft, flow_out, DD, NN, 0, 1);
    mfma_gemm<1><<<gx * 4, blk, 0, stream>>>(fhb, W1t, fsb, HD, NN, 1, 4);
  } else {
    mfma_gemm<0><<<gx, blk, 0, stream>>>(feat_flow, pWft, flow_out, DD, NN, 0, 1);
    mfma_gemm<0><<<gx * 4, blk, 0, stream>>>(feat_host, W1t, fsb, HD, NN, 1, 4);
  }
  agg2<<<ag_g, blk, 0, stream>>>(rp1, adj1, wexp1, fsb, bm, gf, bef, flow_out, NN);

  // ---- relation 2: flow -> host (dst = host, out = host_out)
  if (use_featb) {
    mfma_gemm<1><<<gx, blk, 0, stream>>>(fhb, pWht, host_out, DD, NN, 0, 1);
    mfma_gemm<1><<<gx * 4, blk, 0, stream>>>(ffb, W2t, fsb, HD, NN, 1, 4);
  } else {
    mfma_gemm<0><<<gx, blk, 0, stream>>>(feat_host, pWht, host_out, DD, NN, 0, 1);
    mfma_gemm<0><<<gx * 4, blk, 0, stream>>>(feat_flow, W2t, fsb, HD, NN, 1, 4);
  }
  agg2<<<ag_g, blk, 0, stream>>>(rp2, adj2, wexp2, fsb, bm + 128, gh, beh, host_out, NN);
}

// Round 13
// 476.335 us; speedup vs baseline: 4.1396x; 1.0003x over previous
//
#include <hip/hip_runtime.h>
#include <math.h>

#define NN 100000      // nodes per type
#define EE 200000      // edges per relation
#define HH 4
#define DD 128
#define HD 512         // H*D
#define KIN 256        // input feature dim
#define LN_EPS 1e-5f
#define SLOPE 0.2f
#define NB_SCAN 98     // ceil(NN/1024)

// LDS bank-conflict swizzle for the Cs[2048] table (skinny8 fallback).
#define CSW(a) ((a) ^ (((a) >> 5) & 31))

typedef short bf16x8 __attribute__((ext_vector_type(8)));
typedef unsigned short u16x4 __attribute__((ext_vector_type(4)));
typedef float f32x4 __attribute__((ext_vector_type(4)));

typedef __attribute__((address_space(3))) unsigned int lds_uint;
typedef const __attribute__((address_space(1))) unsigned int glb_uint;

static __device__ __forceinline__ void gload_lds16(const void* g, void* l) {
  __builtin_amdgcn_global_load_lds((glb_uint*)g, (lds_uint*)l, 16, 0, 0);
}

static __device__ __forceinline__ unsigned short f2bf(float x) {
  unsigned int u = __float_as_uint(x);
  u += 0x7fffu + ((u >> 16) & 1u);   // RNE
  return (unsigned short)(u >> 16);
}
static __device__ __forceinline__ float bf_lo(unsigned int u) {
  return __uint_as_float(u << 16);
}
static __device__ __forceinline__ float bf_hi(unsigned int u) {
  return __uint_as_float(u & 0xffff0000u);
}

// Branch-free erf, Abramowitz-Stegun 7.1.26 (max err 1.5e-7).
static __device__ __forceinline__ float erf_fast(float x) {
  float ax = fabsf(x);
  float t = __builtin_amdgcn_rcpf(fmaf(0.3275911f, ax, 1.0f));
  float p = fmaf(1.061405429f, t, -1.453152027f);
  p = fmaf(p, t, 1.421413741f);
  p = fmaf(p, t, -0.284496736f);
  p = fmaf(p, t, 0.254829592f);
  p = p * t;
  float r = 1.0f - p * __expf(-ax * ax);
  return copysignf(r, x);
}
static __device__ __forceinline__ float gelu_fast(float y) {
  return 0.5f * y * (1.0f + erf_fast(y * 0.70710678118f));
}

// ---------------- convert + transpose weights to bf16 [N][K]
__global__ __launch_bounds__(256) void convw(
    const float* __restrict__ W1, const float* __restrict__ W2,
    const float* __restrict__ pWh, const float* __restrict__ pWf,
    short* __restrict__ W1t, short* __restrict__ W2t,
    short* __restrict__ pWht, short* __restrict__ pWft) {
  int idx = blockIdx.x * 256 + threadIdx.x;
  if (idx < 512 * 256) {
    int n = idx >> 8, k = idx & 255;
    W1t[idx] = (short)f2bf(W1[(size_t)k * HD + n]);
    W2t[idx] = (short)f2bf(W2[(size_t)k * HD + n]);
  }
  if (idx < 128 * 256) {
    int n = idx >> 8, k = idx & 255;
    pWht[idx] = (short)f2bf(pWh[(size_t)k * DD + n]);
    pWft[idx] = (short)f2bf(pWf[(size_t)k * DD + n]);
  }
}

// ---------------- build C[k,h] = sum_d W[k,h*128+d]*a[h*128+d]  (f32 + bf16 Ct)
// Ct layout [16][256] bf16 (row = output col of the skinny MFMA):
//   CtH rows 0-3 = W1*al1 (el1), rows 4-7 = W2*ar2 (er2), rows 8-15 = 0
//   CtF rows 0-3 = W1*ar1 (er1), rows 4-7 = W2*al2 (el2), rows 8-15 = 0
__global__ __launch_bounds__(256) void make_c(
    const float* __restrict__ W1, const float* __restrict__ al1, const float* __restrict__ ar1,
    const float* __restrict__ W2, const float* __restrict__ al2, const float* __restrict__ ar2,
    float* __restrict__ Cout, short* __restrict__ CtH, short* __restrict__ CtF) {
  int which = blockIdx.y;
  const float* W = (which < 2) ? W1 : W2;
  const float* a = (which == 0) ? al1 : (which == 1) ? ar1 : (which == 2) ? al2 : ar2;
  int k = threadIdx.x;
  float* C = Cout + (size_t)which * 1024;
#pragma unroll
  for (int h = 0; h < HH; h++) {
    float s = 0.f;
    for (int d = 0; d < DD; d++) s = fmaf(W[(size_t)k * HD + h * DD + d], a[h * DD + d], s);
    C[k * HH + h] = s;
    short b = (short)f2bf(s);
    if (which == 0)      CtH[h * KIN + k] = b;
    else if (which == 3) CtH[(4 + h) * KIN + k] = b;
    else if (which == 1) CtF[h * KIN + k] = b;
    else                 CtF[(4 + h) * KIN + k] = b;
  }
  if (which == 0) {
#pragma unroll
    for (int j = 0; j < 8; j++) CtH[(8 + j) * KIN + k] = 0;
  } else if (which == 1) {
#pragma unroll
    for (int j = 0; j < 8; j++) CtF[(8 + j) * KIN + k] = 0;
  }
}

// ---------------- bm1[d] = 0.25*sum_h b1 + pbf ; bm2 likewise (b2, pbh)
__global__ __launch_bounds__(256) void make_bm(
    const float* __restrict__ b1, const float* __restrict__ pbf,
    const float* __restrict__ b2, const float* __restrict__ pbh,
    float* __restrict__ bm) {
  int d = threadIdx.x;
  if (d < 128) {
    bm[d] = 0.25f * (b1[d] + b1[128 + d] + b1[256 + d] + b1[384 + d]) + pbf[d];
  } else {
    int dd = d - 128;
    bm[d] = 0.25f * (b2[dd] + b2[128 + dd] + b2[256 + dd] + b2[384 + dd]) + pbh[dd];
  }
}

// ---------------- fused bf16 convert + el/er dots via MFMA (one wave per 16 rows)
// Phase 1: ALL 16 float4 loads issued (statically-indexed regs -> 16 in flight).
// Phase 2: convert + Xb store + MFMA chain.
__global__ __launch_bounds__(256) void prep_mfma(
    const float* __restrict__ XH, const float* __restrict__ XF,
    const short* __restrict__ CtH, const short* __restrict__ CtF,
    short* __restrict__ XbH, short* __restrict__ XbF,
    float* __restrict__ o1H, float* __restrict__ o2H,
    float* __restrict__ o1F, float* __restrict__ o2F, int M) {
  int which = blockIdx.y;
  const float* X = which ? XF : XH;
  const short* Ct = which ? CtF : CtH;
  short* Xb = which ? XbF : XbH;
  float* o1 = which ? o1F : o1H;
  float* o2 = which ? o2F : o2H;
  int tid = threadIdx.x, lane = tid & 63, wid = tid >> 6;
  int row0 = blockIdx.x * 64 + wid * 16;
  if (row0 >= M) return;
  int lr = lane & 15, lk = lane >> 4;
  int arow = row0 + lr;
  if (arow > M - 1) arow = M - 1;   // tail: duplicate row, same data rewritten (benign)
  const float* xp = X + (size_t)arow * KIN + lk * 8;
  // ---- phase 1: issue all loads
  float4 v[16];
#pragma unroll
  for (int kc = 0; kc < 8; kc++) {
    v[2 * kc]     = *(const float4*)(xp + kc * 32);
    v[2 * kc + 1] = *(const float4*)(xp + kc * 32 + 4);
  }
  // ---- B fragments
  bf16x8 bfrag[8];
#pragma unroll
  for (int kc = 0; kc < 8; kc++)
    bfrag[kc] = *(const bf16x8*)(Ct + lr * KIN + kc * 32 + lk * 8);
  // ---- phase 2: convert + store + MFMA
  short* xbp = Xb + (size_t)arow * KIN + lk * 8;
  f32x4 acc = (f32x4){0.f, 0.f, 0.f, 0.f};
#pragma unroll
  for (int kc = 0; kc < 8; kc++) {
    float4 v0 = v[2 * kc], v1 = v[2 * kc + 1];
    bf16x8 af;
    af[0] = (short)f2bf(v0.x); af[1] = (short)f2bf(v0.y);
    af[2] = (short)f2bf(v0.z); af[3] = (short)f2bf(v0.w);
    af[4] = (short)f2bf(v1.x); af[5] = (short)f2bf(v1.y);
    af[6] = (short)f2bf(v1.z); af[7] = (short)f2bf(v1.w);
    *(bf16x8*)(xbp + kc * 32) = af;
    acc = __builtin_amdgcn_mfma_f32_16x16x32_bf16(af, bfrag[kc], acc, 0, 0, 0);
  }
  if (lr < 8) {
    int rbase = row0 + lk * 4;
#pragma unroll
    for (int r = 0; r < 4; r++) {
      int row = rbase + r;
      if (row < M) {
        if (lr < 4) o1[(size_t)row * HH + lr] = acc[r];
        else        o2[(size_t)row * HH + (lr - 4)] = acc[r];
      }
    }
  }
}

// ---------------- fallback skinny (no bf16 feature copy)
__global__ __launch_bounds__(256) void skinny8(
    const float* __restrict__ X, const float* __restrict__ C1, const float* __restrict__ C2,
    float* __restrict__ o1, float* __restrict__ o2, int M) {
  __shared__ float Cs[KIN * 8];
  int tid = threadIdx.x;
  for (int i = tid; i < KIN * 4; i += 256) {
    int k = i >> 2, h = i & 3;
    Cs[CSW(k * 8 + h)] = C1[i];
    Cs[CSW(k * 8 + 4 + h)] = C2[i];
  }
  __syncthreads();
  int wave = tid >> 6, lane = tid & 63;
  int n = blockIdx.x * 4 + wave;
  if (n >= M) return;
  float4 xv = ((const float4*)(X + (size_t)n * KIN))[lane];
  float xs[4] = {xv.x, xv.y, xv.z, xv.w};
  float acc[8] = {0.f, 0.f, 0.f, 0.f, 0.f, 0.f, 0.f, 0.f};
#pragma unroll
  for (int j = 0; j < 4; j++) {
    int k = lane * 4 + j;
#pragma unroll
    for (int t = 0; t < 8; t++) acc[t] = fmaf(xs[j], Cs[CSW(k * 8 + t)], acc[t]);
  }
#pragma unroll
  for (int off = 32; off >= 1; off >>= 1)
#pragma unroll
    for (int t = 0; t < 8; t++) acc[t] += __shfl_xor(acc[t], off);
  if (lane == 0) {
#pragma unroll
    for (int h = 0; h < HH; h++) {
      o1[(size_t)n * HH + h] = acc[h];
      o2[(size_t)n * HH + h] = acc[4 + h];
    }
  }
}

// ---------------- CSR build ----------------
__global__ __launch_bounds__(256) void hist2(
    const int* __restrict__ d1, const int* __restrict__ d2,
    int* __restrict__ c1, int* __restrict__ c2) {
  int gid = blockIdx.x * 256 + threadIdx.x;
  if (gid < EE) atomicAdd(&c1[d1[gid]], 1);
  else if (gid < 2 * EE) atomicAdd(&c2[d2[gid - EE]], 1);
}

__global__ __launch_bounds__(256) void scan_chunk(
    const int* __restrict__ c1, const int* __restrict__ c2,
    int* __restrict__ rp1, int* __restrict__ rp2, int* __restrict__ bsum) {
  int rel = blockIdx.y;
  const int* counts = rel ? c2 : c1;
  int* rowptr = rel ? rp2 : rp1;
  int* bs = bsum + rel * 128;
  __shared__ int sd[256];
  int tid = threadIdx.x;
  int base = blockIdx.x * 1024 + tid * 4;
  int c[4];
#pragma unroll
  for (int j = 0; j < 4; j++) c[j] = (base + j < NN) ? counts[base + j] : 0;
  int tot = c[0] + c[1] + c[2] + c[3];
  sd[tid] = tot; __syncthreads();
  for (int o = 1; o < 256; o <<= 1) {
    int v = (tid >= o) ? sd[tid - o] : 0;
    __syncthreads();
    sd[tid] += v;
    __syncthreads();
  }
  int excl = sd[tid] - tot;
  int run = excl;
#pragma unroll
  for (int j = 0; j < 4; j++) {
    if (base + j < NN) rowptr[base + j] = run;
    run += c[j];
  }
  if (tid == 255) bs[blockIdx.x] = sd[255];
}

__global__ __launch_bounds__(128) void scan_bsum(int* __restrict__ bsum) {
  int rel = blockIdx.y;
  int* bs = bsum + rel * 128;
  __shared__ int sd[128];
  int tid = threadIdx.x;
  int v = (tid < NB_SCAN) ? bs[tid] : 0;
  sd[tid] = v; __syncthreads();
  for (int o = 1; o < 128; o <<= 1) {
    int t = (tid >= o) ? sd[tid - o] : 0;
    __syncthreads();
    sd[tid] += t;
    __syncthreads();
  }
  bs[tid] = sd[tid] - v;
}

__global__ __launch_bounds__(256) void addoff2(
    int* __restrict__ rp1, int* __restrict__ rp2,
    int* __restrict__ cur1, int* __restrict__ cur2,
    const int* __restrict__ bsum) {
  int rel = blockIdx.y;
  int* rowptr = rel ? rp2 : rp1;
  int* cur = rel ? cur2 : cur1;
  const int* bs = bsum + rel * 128;
  int i = blockIdx.x * 256 + threadIdx.x;
  if (i < NN) {
    int r = rowptr[i] + bs[i >> 10];
    rowptr[i] = r;
    cur[i] = r;
  }
  if (i == 0) rowptr[NN] = EE;
}

// ---------------- fill CSR: src id + per-edge exp coeffs (NO denominator atomics)
__global__ __launch_bounds__(256) void fill_s(
    const int* __restrict__ e1s, const int* __restrict__ e1d,
    const int* __restrict__ e2s, const int* __restrict__ e2d,
    const float* __restrict__ el1, const float* __restrict__ er1,
    const float* __restrict__ el2, const float* __restrict__ er2,
    int* __restrict__ cur1, int* __restrict__ cur2,
    int* __restrict__ adj1, int* __restrict__ adj2,
    float* __restrict__ wexp1, float* __restrict__ wexp2) {
  int gid = blockIdx.x * 256 + threadIdx.x;
  int rel = (gid >= EE);
  if (gid >= 2 * EE) return;
  int e = rel ? gid - EE : gid;
  const int* srcp = rel ? e2s : e1s;
  const int* dstp = rel ? e2d : e1d;
  const float* el = rel ? el2 : el1;
  const float* er = rel ? er2 : er1;
  int* cur = rel ? cur2 : cur1;
  int* adj = rel ? adj2 : adj1;
  float* wexp = rel ? wexp2 : wexp1;
  int si = srcp[e], di = dstp[e];
  int p = atomicAdd(&cur[di], 1);
  adj[p] = si;
  float4 l = *(const float4*)(el + (size_t)si * HH);
  float4 r = *(const float4*)(er + (size_t)di * HH);
  float v0 = l.x + r.x, v1 = l.y + r.y, v2 = l.z + r.z, v3 = l.w + r.w;
  v0 = v0 > 0.f ? v0 : SLOPE * v0; v1 = v1 > 0.f ? v1 : SLOPE * v1;
  v2 = v2 > 0.f ? v2 : SLOPE * v2; v3 = v3 > 0.f ? v3 : SLOPE * v3;
  *(float4*)(wexp + (size_t)p * HH) =
      make_float4(__expf(v0), __expf(v1), __expf(v2), __expf(v3));
}

// ---------------- MFMA GEMM: C[M x N] = A[M x 256] @ Wt[N x 256]^T
// 1-D grid, XCD-bijective swizzle, col fastest (A L2 reuse).
// ABF=1: bf16 A; staging via global_load_lds(16B), linear LDS dest +
// inverse-swizzled per-lane global source (XOR stays within each 128B K-window).
template <int ABF>
__global__ __launch_bounds__(256) void mfma_gemm(
    const void* __restrict__ Av, const short* __restrict__ Wt,
    void* __restrict__ Cout, int ldC, int M, int write_bf, int ncol) {
  __shared__ short As[128 * 64];
  __shared__ short Bs[128 * 64];
  int nwg = gridDim.x;
  int q = nwg >> 3, r = nwg & 7;
  int xcd = blockIdx.x & 7, seq = blockIdx.x >> 3;
  int lid = (xcd < r) ? (xcd * (q + 1) + seq) : (r * (q + 1) + (xcd - r) * q + seq);
  int row0 = (lid / ncol) * 128;
  int col0 = (lid % ncol) * 128;

  int tid = threadIdx.x;
  int lane = tid & 63, wid = tid >> 6;
  int wm = wid >> 1, wn = wid & 1;

  f32x4 acc[4][4];
#pragma unroll
  for (int i = 0; i < 4; i++)
#pragma unroll
    for (int j = 0; j < 4; j++) acc[i][j] = (f32x4){0.f, 0.f, 0.f, 0.f};

  int am = tid >> 1;
  int akh = (tid & 1) * 32;
  bool arow_ok = (row0 + am) < M;

  for (int k0 = 0; k0 < KIN; k0 += 64) {
    __syncthreads();
    if (ABF) {
      int rr8 = lane >> 3;
      int bby = (lane & 7) * 16;
#pragma unroll
      for (int c2 = 0; c2 < 4; c2++) {
        int rr = wid * 32 + c2 * 8 + rr8;
        int rg = row0 + rr; if (rg > M - 1) rg = M - 1;
        int sb = bby ^ ((rr & 7) << 4);
        gload_lds16((const char*)Av + (size_t)rg * (KIN * 2) + k0 * 2 + sb,
                    (char*)As + wid * 4096 + c2 * 1024);
      }
#pragma unroll
      for (int c2 = 0; c2 < 4; c2++) {
        int rr = wid * 32 + c2 * 8 + rr8;
        int sb = bby ^ ((rr & 7) << 4);
        gload_lds16((const char*)Wt + (size_t)(col0 + rr) * (KIN * 2) + k0 * 2 + sb,
                    (char*)Bs + wid * 4096 + c2 * 1024);
      }
    } else {
      const float* xp = (const float*)Av + (size_t)(row0 + am) * KIN + k0 + akh;
#pragma unroll
      for (int c = 0; c < 4; c++) {
        float4 v0, v1;
        if (arow_ok) {
          v0 = *(const float4*)(xp + c * 8);
          v1 = *(const float4*)(xp + c * 8 + 4);
        } else {
          v0 = make_float4(0.f, 0.f, 0.f, 0.f);
          v1 = v0;
        }
        bf16x8 pk;
        pk[0] = (short)f2bf(v0.x); pk[1] = (short)f2bf(v0.y);
        pk[2] = (short)f2bf(v0.z); pk[3] = (short)f2bf(v0.w);
        pk[4] = (short)f2bf(v1.x); pk[5] = (short)f2bf(v1.y);
        pk[6] = (short)f2bf(v1.z); pk[7] = (short)f2bf(v1.w);
        int kc = akh + c * 8;
        int ad = (am * 128 + kc * 2) ^ ((am & 7) << 4);
        *(bf16x8*)((char*)As + ad) = pk;
      }
      int bn = tid >> 1;
      int bkh = (tid & 1) * 32;
      const short* wp = Wt + (size_t)(col0 + bn) * KIN + k0 + bkh;
#pragma unroll
      for (int c = 0; c < 4; c++) {
        bf16x8 pv = *(const bf16x8*)(wp + c * 8);
        int kc = bkh + c * 8;
        int bd = (bn * 128 + kc * 2) ^ ((bn & 7) << 4);
        *(bf16x8*)((char*)Bs + bd) = pv;
      }
    }
    __syncthreads();
#pragma unroll
    for (int ks = 0; ks < 2; ks++) {
      int kb = ks * 32 + (lane >> 4) * 8;
      bf16x8 af[4], bfv[4];
#pragma unroll
      for (int mf = 0; mf < 4; mf++) {
        int rr = wm * 64 + mf * 16 + (lane & 15);
        int ad = (rr * 128 + kb * 2) ^ ((rr & 7) << 4);
        af[mf] = *(bf16x8*)((char*)As + ad);
      }
#pragma unroll
      for (int nf = 0; nf < 4; nf++) {
        int cc = wn * 64 + nf * 16 + (lane & 15);
        int bd = (cc * 128 + kb * 2) ^ ((cc & 7) << 4);
        bfv[nf] = *(bf16x8*)((char*)Bs + bd);
      }
#pragma unroll
      for (int mf = 0; mf < 4; mf++)
#pragma unroll
        for (int nf = 0; nf < 4; nf++)
          acc[mf][nf] = __builtin_amdgcn_mfma_f32_16x16x32_bf16(af[mf], bfv[nf], acc[mf][nf], 0, 0, 0);
    }
  }
  int lr = lane >> 4, lc = lane & 15;
#pragma unroll
  for (int mf = 0; mf < 4; mf++) {
#pragma unroll
    for (int r4 = 0; r4 < 4; r4++) {
      int row = row0 + wm * 64 + mf * 16 + lr * 4 + r4;
      if (row < M) {
#pragma unroll
        for (int nf = 0; nf < 4; nf++) {
          int col = col0 + wn * 64 + nf * 16 + lc;
          float v = acc[mf][nf][r4];
          if (write_bf) ((unsigned short*)Cout)[(size_t)row * ldC + col] = f2bf(v);
          else ((float*)Cout)[(size_t)row * ldC + col] = v;
        }
      }
    }
  }
}

// ---------------- single-pass agg + mean + residual + LN + GELU (one wave/dst)
__global__ __launch_bounds__(256) void agg2(
    const int* __restrict__ rowptr, const int* __restrict__ adj,
    const float* __restrict__ wexp,
    const unsigned short* __restrict__ fsb,
    const float* __restrict__ bm,
    const float* __restrict__ g, const float* __restrict__ be,
    float* __restrict__ out, int M) {
  int wave = threadIdx.x >> 6, lane = threadIdx.x & 63;
  int n = blockIdx.x * 4 + wave;
  if (n >= M) return;
  int beg = rowptr[n], end = rowptr[n + 1];
  int lh = lane >> 4, lc = lane & 15;
  float sh = 0.f;
  float m[8] = {0.f, 0.f, 0.f, 0.f, 0.f, 0.f, 0.f, 0.f};
  for (int t = beg; t < end; t++) {
    int si = adj[t];
    float wh = wexp[(size_t)t * HH + lh];
    sh += wh;
    uint4 u = *(const uint4*)(fsb + (size_t)si * HD + lane * 8);
    m[0] = fmaf(wh, bf_lo(u.x), m[0]); m[1] = fmaf(wh, bf_hi(u.x), m[1]);
    m[2] = fmaf(wh, bf_lo(u.y), m[2]); m[3] = fmaf(wh, bf_hi(u.y), m[3]);
    m[4] = fmaf(wh, bf_lo(u.z), m[4]); m[5] = fmaf(wh, bf_hi(u.z), m[5]);
    m[6] = fmaf(wh, bf_lo(u.w), m[6]); m[7] = fmaf(wh, bf_hi(u.w), m[7]);
  }
  float rsh = sh > 0.f ? 0.25f / sh : 0.f;
#pragma unroll
  for (int j = 0; j < 8; j++) m[j] *= rsh;
#pragma unroll
  for (int j = 0; j < 8; j++) {
    m[j] += __shfl_xor(m[j], 16);
    m[j] += __shfl_xor(m[j], 32);
  }
  const float4* bmp = (const float4*)(bm + lc * 8);
  float4 b0 = bmp[0], b1 = bmp[1];
  const float4* orow = (const float4*)(out + (size_t)n * DD + lc * 8);
  float4 p0 = orow[0], p1 = orow[1];
  float c[8];
  c[0] = m[0] + b0.x + p0.x; c[1] = m[1] + b0.y + p0.y;
  c[2] = m[2] + b0.z + p0.z; c[3] = m[3] + b0.w + p0.w;
  c[4] = m[4] + b1.x + p1.x; c[5] = m[5] + b1.y + p1.y;
  c[6] = m[6] + b1.z + p1.z; c[7] = m[7] + b1.w + p1.w;
  float ss = c[0] + c[1] + c[2] + c[3] + c[4] + c[5] + c[6] + c[7];
  ss += __shfl_xor(ss, 1); ss += __shfl_xor(ss, 2);
  ss += __shfl_xor(ss, 4); ss += __shfl_xor(ss, 8);
  float mu = ss * (1.f / 128.f);
  float vv = 0.f;
#pragma unroll
  for (int j = 0; j < 8; j++) { float d = c[j] - mu; vv = fmaf(d, d, vv); }
  vv += __shfl_xor(vv, 1); vv += __shfl_xor(vv, 2);
  vv += __shfl_xor(vv, 4); vv += __shfl_xor(vv, 8);
  float inv = rsqrtf(vv * (1.f / 128.f) + LN_EPS);
  const float4* gp = (const float4*)(g + lc * 8);
  const float4* bep = (const float4*)(be + lc * 8);
  float4 g0 = gp[0], g1 = gp[1];
  float4 e0 = bep[0], e1 = bep[1];
  float gv[8] = {g0.x, g0.y, g0.z, g0.w, g1.x, g1.y, g1.z, g1.w};
  float ev[8] = {e0.x, e0.y, e0.z, e0.w, e1.x, e1.y, e1.z, e1.w};
  float o[8];
#pragma unroll
  for (int j = 0; j < 8; j++) {
    float y = (c[j] - mu) * inv * gv[j] + ev[j];
    o[j] = gelu_fast(y);
  }
  if (lane < 16) {
    float4* op = (float4*)(out + (size_t)n * DD + lane * 8);
    op[0] = make_float4(o[0], o[1], o[2], o[3]);
    op[1] = make_float4(o[4], o[5], o[6], o[7]);
  }
}

extern "C" void kernel_launch(void* const* d_in, const int* in_sizes, int n_in,
                              void* d_out, int out_size, void* d_ws, size_t ws_size,
                              hipStream_t stream) {
  const float* feat_host = (const float*)d_in[0];
  const float* feat_flow = (const float*)d_in[1];
  const float* W1  = (const float*)d_in[2];
  const float* al1 = (const float*)d_in[3];
  const float* ar1 = (const float*)d_in[4];
  const float* b1  = (const float*)d_in[5];
  const float* W2  = (const float*)d_in[6];
  const float* al2 = (const float*)d_in[7];
  const float* ar2 = (const float*)d_in[8];
  const float* b2  = (const float*)d_in[9];
  const float* pWh = (const float*)d_in[10];
  const float* pbh = (const float*)d_in[11];
  const float* pWf = (const float*)d_in[12];
  const float* pbf = (const float*)d_in[13];
  const float* gh  = (const float*)d_in[14];
  const float* beh = (const float*)d_in[15];
  const float* gf  = (const float*)d_in[16];
  const float* bef = (const float*)d_in[17];
  const int* e1s = (const int*)d_in[18];
  const int* e1d = (const int*)d_in[19];
  const int* e2s = (const int*)d_in[20];
  const int* e2d = (const int*)d_in[21];

  float* out = (float*)d_out;
  float* host_out = out;                       // [NN,128]
  float* flow_out = out + (size_t)NN * DD;     // [NN,128]

  float* ws = (float*)d_ws;
  size_t off = 0;
  unsigned short* fsb = (unsigned short*)(ws + off); off += (size_t)NN * 256;  // NN x 512 bf16
  short* W1t  = (short*)(ws + off); off += (512 * 256) / 2;
  short* W2t  = (short*)(ws + off); off += (512 * 256) / 2;
  short* pWht = (short*)(ws + off); off += (128 * 256) / 2;
  short* pWft = (short*)(ws + off); off += (128 * 256) / 2;
  float* el1b = ws + off; off += (size_t)NN * HH;
  float* er1b = ws + off; off += (size_t)NN * HH;
  float* el2b = ws + off; off += (size_t)NN * HH;
  float* er2b = ws + off; off += (size_t)NN * HH;
  float* Cbuf = ws + off; off += 4096;
  short* CtH  = (short*)(ws + off); off += 2048;     // 16x256 bf16
  short* CtF  = (short*)(ws + off); off += 2048;
  float* bm   = ws + off; off += 256;          // bm1 | bm2
  float* wexp1 = ws + off; off += (size_t)EE * HH;   // per-slot exp coeffs
  float* wexp2 = ws + off; off += (size_t)EE * HH;
  // CSR
  int* rp1  = (int*)(ws + off);      // NN+1
  int* rp2  = rp1 + (NN + 1);
  int* adj1 = rp2 + (NN + 1);        // EE (src ids)
  int* adj2 = adj1 + EE;
  int* bsum = adj2 + EE;             // 256
  int* cur1 = bsum + 256;            // NN } contiguous memset region (2*NN)
  int* cur2 = cur1 + NN;             // NN }
  off += (size_t)(2 * (NN + 1) + 2 * EE + 256 + 2 * NN + 4);
  // optional bf16 feature copies
  size_t base_bytes = (off + 1024) * sizeof(float);
  size_t featb_bytes = (size_t)NN * KIN * 2 * 2;
  bool use_featb = ws_size >= base_bytes + featb_bytes;
  short* fhb = nullptr;
  short* ffb = nullptr;
  if (use_featb) {
    fhb = (short*)(ws + off); off += (size_t)NN * KIN / 2;
    ffb = (short*)(ws + off); off += (size_t)NN * KIN / 2;
  }

  dim3 blk(256);
  int gx = (NN + 127) / 128;                 // 782 row tiles
  int pm_g = (NN + 63) / 64;                 // prep_mfma blocks (64 rows each)
  int sk_g = (NN + 3) / 4;
  int ag_g = (NN + 3) / 4;
  int ee2_g = (2 * EE + 255) / 256;
  int nn_g = (NN + 255) / 256;

  // ---- prep
  convw<<<512, blk, 0, stream>>>(W1, W2, pWh, pWf, W1t, W2t, pWht, pWft);
  make_c<<<dim3(1, 4), blk, 0, stream>>>(W1, al1, ar1, W2, al2, ar2, Cbuf, CtH, CtF);
  make_bm<<<1, blk, 0, stream>>>(b1, pbf, b2, pbh, bm);
  if (use_featb) {
    // fused: f32->bf16 convert + el/er skinny dots via MFMA (both matrices)
    prep_mfma<<<dim3(pm_g, 2), blk, 0, stream>>>(
        feat_host, feat_flow, CtH, CtF, fhb, ffb,
        el1b, er2b, er1b, el2b, NN);
  } else {
    skinny8<<<sk_g, blk, 0, stream>>>(feat_host, Cbuf + 0,    Cbuf + 3072, el1b, er2b, NN);
    skinny8<<<sk_g, blk, 0, stream>>>(feat_flow, Cbuf + 1024, Cbuf + 2048, er1b, el2b, NN);
  }

  // ---- CSR + per-edge coeffs (no denominator atomics)
  hipMemsetAsync(cur1, 0, (size_t)2 * NN * sizeof(int), stream);
  hist2<<<ee2_g, blk, 0, stream>>>(e1d, e2d, cur1, cur2);
  scan_chunk<<<dim3(NB_SCAN, 2), blk, 0, stream>>>(cur1, cur2, rp1, rp2, bsum);
  scan_bsum<<<dim3(1, 2), 128, 0, stream>>>(bsum);
  addoff2<<<dim3(nn_g, 2), blk, 0, stream>>>(rp1, rp2, cur1, cur2, bsum);
  fill_s<<<ee2_g, blk, 0, stream>>>(e1s, e1d, e2s, e2d, el1b, er1b, el2b, er2b,
                                    cur1, cur2, adj1, adj2, wexp1, wexp2);

  // ---- relation 1: host -> flow (dst = flow, out = flow_out)
  if (use_featb) {
    mfma_gemm<1><<<gx, blk, 0, stream>>>(ffb, pWft, flow_out, DD, NN, 0, 1);
    mfma_gemm<1><<<gx * 4, blk, 0, stream>>>(fhb, W1t, fsb, HD, NN, 1, 4);
  } else {
    mfma_gemm<0><<<gx, blk, 0, stream>>>(feat_flow, pWft, flow_out, DD, NN, 0, 1);
    mfma_gemm<0><<<gx * 4, blk, 0, stream>>>(feat_host, W1t, fsb, HD, NN, 1, 4);
  }
  agg2<<<ag_g, blk, 0, stream>>>(rp1, adj1, wexp1, fsb, bm, gf, bef, flow_out, NN);

  // ---- relation 2: flow -> host (dst = host, out = host_out)
  if (use_featb) {
    mfma_gemm<1><<<gx, blk, 0, stream>>>(fhb, pWht, host_out, DD, NN, 0, 1);
    mfma_gemm<1><<<gx * 4, blk, 0, stream>>>(ffb, W2t, fsb, HD, NN, 1, 4);
  } else {
    mfma_gemm<0><<<gx, blk, 0, stream>>>(feat_host, pWht, host_out, DD, NN, 0, 1);
    mfma_gemm<0><<<gx * 4, blk, 0, stream>>>(feat_flow, W2t, fsb, HD, NN, 1, 4);
  }
  agg2<<<ag_g, blk, 0, stream>>>(rp2, adj2, wexp2, fsb, bm + 128, gh, beh, host_out, NN);
}

// Round 14
// 455.365 us; speedup vs baseline: 4.3302x; 1.0460x over previous
//
#include <hip/hip_runtime.h>
#include <math.h>

#define NN 100000      // nodes per type
#define EE 200000      // edges per relation
#define HH 4
#define DD 128
#define HD 512         // H*D
#define KIN 256        // input feature dim
#define LN_EPS 1e-5f
#define SLOPE 0.2f
#define NB_SCAN 98     // ceil(NN/1024)

// LDS bank-conflict swizzle for the Cs[2048] table (skinny8 fallback).
#define CSW(a) ((a) ^ (((a) >> 5) & 31))

typedef short bf16x8 __attribute__((ext_vector_type(8)));
typedef unsigned short u16x4 __attribute__((ext_vector_type(4)));
typedef float f32x4 __attribute__((ext_vector_type(4)));

typedef __attribute__((address_space(3))) unsigned int lds_uint;
typedef const __attribute__((address_space(1))) unsigned int glb_uint;

static __device__ __forceinline__ void gload_lds16(const void* g, void* l) {
  __builtin_amdgcn_global_load_lds((glb_uint*)g, (lds_uint*)l, 16, 0, 0);
}

static __device__ __forceinline__ unsigned short f2bf(float x) {
  unsigned int u = __float_as_uint(x);
  u += 0x7fffu + ((u >> 16) & 1u);   // RNE
  return (unsigned short)(u >> 16);
}
static __device__ __forceinline__ float bf_lo(unsigned int u) {
  return __uint_as_float(u << 16);
}
static __device__ __forceinline__ float bf_hi(unsigned int u) {
  return __uint_as_float(u & 0xffff0000u);
}

// Branch-free erf, Abramowitz-Stegun 7.1.26 (max err 1.5e-7).
static __device__ __forceinline__ float erf_fast(float x) {
  float ax = fabsf(x);
  float t = __builtin_amdgcn_rcpf(fmaf(0.3275911f, ax, 1.0f));
  float p = fmaf(1.061405429f, t, -1.453152027f);
  p = fmaf(p, t, 1.421413741f);
  p = fmaf(p, t, -0.284496736f);
  p = fmaf(p, t, 0.254829592f);
  p = p * t;
  float r = 1.0f - p * __expf(-ax * ax);
  return copysignf(r, x);
}
static __device__ __forceinline__ float gelu_fast(float y) {
  return 0.5f * y * (1.0f + erf_fast(y * 0.70710678118f));
}

// ---------------- convert + transpose weights to bf16 [N][K]
__global__ __launch_bounds__(256) void convw(
    const float* __restrict__ W1, const float* __restrict__ W2,
    const float* __restrict__ pWh, const float* __restrict__ pWf,
    short* __restrict__ W1t, short* __restrict__ W2t,
    short* __restrict__ pWht, short* __restrict__ pWft) {
  int idx = blockIdx.x * 256 + threadIdx.x;
  if (idx < 512 * 256) {
    int n = idx >> 8, k = idx & 255;
    W1t[idx] = (short)f2bf(W1[(size_t)k * HD + n]);
    W2t[idx] = (short)f2bf(W2[(size_t)k * HD + n]);
  }
  if (idx < 128 * 256) {
    int n = idx >> 8, k = idx & 255;
    pWht[idx] = (short)f2bf(pWh[(size_t)k * DD + n]);
    pWft[idx] = (short)f2bf(pWf[(size_t)k * DD + n]);
  }
}

// ---------------- build C[k,h] = sum_d W[k,h*128+d]*a[h*128+d]  (f32 + bf16 Ct)
// Ct layout [16][256] bf16 (row = output col of the skinny MFMA):
//   CtH rows 0-3 = W1*al1 (el1), rows 4-7 = W2*ar2 (er2), rows 8-15 = 0
//   CtF rows 0-3 = W1*ar1 (er1), rows 4-7 = W2*al2 (el2), rows 8-15 = 0
__global__ __launch_bounds__(256) void make_c(
    const float* __restrict__ W1, const float* __restrict__ al1, const float* __restrict__ ar1,
    const float* __restrict__ W2, const float* __restrict__ al2, const float* __restrict__ ar2,
    float* __restrict__ Cout, short* __restrict__ CtH, short* __restrict__ CtF) {
  int which = blockIdx.y;
  const float* W = (which < 2) ? W1 : W2;
  const float* a = (which == 0) ? al1 : (which == 1) ? ar1 : (which == 2) ? al2 : ar2;
  int k = threadIdx.x;
  float* C = Cout + (size_t)which * 1024;
#pragma unroll
  for (int h = 0; h < HH; h++) {
    float s = 0.f;
    for (int d = 0; d < DD; d++) s = fmaf(W[(size_t)k * HD + h * DD + d], a[h * DD + d], s);
    C[k * HH + h] = s;
    short b = (short)f2bf(s);
    if (which == 0)      CtH[h * KIN + k] = b;
    else if (which == 3) CtH[(4 + h) * KIN + k] = b;
    else if (which == 1) CtF[h * KIN + k] = b;
    else                 CtF[(4 + h) * KIN + k] = b;
  }
  if (which == 0) {
#pragma unroll
    for (int j = 0; j < 8; j++) CtH[(8 + j) * KIN + k] = 0;
  } else if (which == 1) {
#pragma unroll
    for (int j = 0; j < 8; j++) CtF[(8 + j) * KIN + k] = 0;
  }
}

// ---------------- bm1[d] = 0.25*sum_h b1 + pbf ; bm2 likewise (b2, pbh)
__global__ __launch_bounds__(256) void make_bm(
    const float* __restrict__ b1, const float* __restrict__ pbf,
    const float* __restrict__ b2, const float* __restrict__ pbh,
    float* __restrict__ bm) {
  int d = threadIdx.x;
  if (d < 128) {
    bm[d] = 0.25f * (b1[d] + b1[128 + d] + b1[256 + d] + b1[384 + d]) + pbf[d];
  } else {
    int dd = d - 128;
    bm[d] = 0.25f * (b2[dd] + b2[128 + dd] + b2[256 + dd] + b2[384 + dd]) + pbh[dd];
  }
}

// ---------------- fused bf16 convert + el/er dots via MFMA, coalesced staging
// Block = 256 thr (4 waves) = 64 rows.
// Stage 1 (coalesced): thread t, iter i handles 8 consecutive floats of the
//   64x256 row-panel; converts; stores bf16 to Xb (1KB/wave contiguous) and to
//   a swizzled LDS tile (chunk16 ^= row&7, rule-21 involution both sides).
// Stage 2: per-wave 16 rows, A-frags from LDS, 8x mfma_16x16x32 with Ct.
// Epilogue: acc -> LDS -> coalesced float4 writes of o1/o2 (one row per thread).
__global__ __launch_bounds__(256) void prep_mfma(
    const float* __restrict__ XH, const float* __restrict__ XF,
    const short* __restrict__ CtH, const short* __restrict__ CtF,
    short* __restrict__ XbH, short* __restrict__ XbF,
    float* __restrict__ o1H, float* __restrict__ o2H,
    float* __restrict__ o1F, float* __restrict__ o2F, int M) {
  __shared__ short Asm[64 * 256];   // 32 KB bf16 tile
  __shared__ float os[64 * 8];      // 2 KB acc staging
  int which = blockIdx.y;
  const float* X = which ? XF : XH;
  const short* Ct = which ? CtF : CtH;
  short* Xb = which ? XbF : XbH;
  float* o1 = which ? o1F : o1H;
  float* o2 = which ? o2F : o2H;
  int t = threadIdx.x, lane = t & 63, wid = t >> 6;
  int row0 = blockIdx.x * 64;

  // ---- stage 1: coalesced load/convert/store + LDS fill
  {
    int rsub = t >> 5;            // 0..7 row within the 8-row slice
    int c16 = t & 31;             // 16B chunk index within the row (0..31)
#pragma unroll
    for (int i = 0; i < 8; i++) {
      int r_loc = i * 8 + rsub;   // 0..63
      int grow = row0 + r_loc; if (grow > M - 1) grow = M - 1;
      const float* xp = X + (size_t)grow * KIN + c16 * 8;
      float4 v0 = *(const float4*)xp;
      float4 v1 = *(const float4*)(xp + 4);
      bf16x8 af;
      af[0] = (short)f2bf(v0.x); af[1] = (short)f2bf(v0.y);
      af[2] = (short)f2bf(v0.z); af[3] = (short)f2bf(v0.w);
      af[4] = (short)f2bf(v1.x); af[5] = (short)f2bf(v1.y);
      af[6] = (short)f2bf(v1.z); af[7] = (short)f2bf(v1.w);
      *(bf16x8*)(Xb + (size_t)grow * KIN + c16 * 8) = af;   // coalesced (dup rows benign)
      int swc = c16 ^ (r_loc & 7);                          // swizzled 16B chunk
      *(bf16x8*)((char*)Asm + r_loc * 512 + swc * 16) = af;
    }
  }
  // B fragments (global, L2-hot) — overlap with LDS drain
  int lr = lane & 15, lk = lane >> 4;
  bf16x8 bfrag[8];
#pragma unroll
  for (int kc = 0; kc < 8; kc++)
    bfrag[kc] = *(const bf16x8*)(Ct + lr * KIN + kc * 32 + lk * 8);
  __syncthreads();

  // ---- stage 2: MFMA per wave over rows wid*16..+16
  {
    int lrow = wid * 16 + lr;
    f32x4 acc = (f32x4){0.f, 0.f, 0.f, 0.f};
#pragma unroll
    for (int kc = 0; kc < 8; kc++) {
      int chunk = (lk + kc * 4) ^ (lrow & 7);   // byte-in-row/16 ^ row&7
      bf16x8 af = *(bf16x8*)((char*)Asm + lrow * 512 + chunk * 16);
      acc = __builtin_amdgcn_mfma_f32_16x16x32_bf16(af, bfrag[kc], acc, 0, 0, 0);
    }
    // D: col=lane&15 (=lr), row=lk*4+r within the wave's 16 rows
    if (lr < 8) {
#pragma unroll
      for (int r = 0; r < 4; r++)
        os[(wid * 16 + lk * 4 + r) * 8 + lr] = acc[r];
    }
  }
  __syncthreads();

  // ---- epilogue: coalesced o1/o2 writes (one row's 4 heads per thread)
  if (t < 64) {
    int row = row0 + t;
    if (row < M)
      *(float4*)(o1 + (size_t)row * HH) =
          make_float4(os[t * 8 + 0], os[t * 8 + 1], os[t * 8 + 2], os[t * 8 + 3]);
  } else if (t < 128) {
    int j = t - 64;
    int row = row0 + j;
    if (row < M)
      *(float4*)(o2 + (size_t)row * HH) =
          make_float4(os[j * 8 + 4], os[j * 8 + 5], os[j * 8 + 6], os[j * 8 + 7]);
  }
}

// ---------------- fallback skinny (no bf16 feature copy)
__global__ __launch_bounds__(256) void skinny8(
    const float* __restrict__ X, const float* __restrict__ C1, const float* __restrict__ C2,
    float* __restrict__ o1, float* __restrict__ o2, int M) {
  __shared__ float Cs[KIN * 8];
  int tid = threadIdx.x;
  for (int i = tid; i < KIN * 4; i += 256) {
    int k = i >> 2, h = i & 3;
    Cs[CSW(k * 8 + h)] = C1[i];
    Cs[CSW(k * 8 + 4 + h)] = C2[i];
  }
  __syncthreads();
  int wave = tid >> 6, lane = tid & 63;
  int n = blockIdx.x * 4 + wave;
  if (n >= M) return;
  float4 xv = ((const float4*)(X + (size_t)n * KIN))[lane];
  float xs[4] = {xv.x, xv.y, xv.z, xv.w};
  float acc[8] = {0.f, 0.f, 0.f, 0.f, 0.f, 0.f, 0.f, 0.f};
#pragma unroll
  for (int j = 0; j < 4; j++) {
    int k = lane * 4 + j;
#pragma unroll
    for (int t = 0; t < 8; t++) acc[t] = fmaf(xs[j], Cs[CSW(k * 8 + t)], acc[t]);
  }
#pragma unroll
  for (int off = 32; off >= 1; off >>= 1)
#pragma unroll
    for (int t = 0; t < 8; t++) acc[t] += __shfl_xor(acc[t], off);
  if (lane == 0) {
#pragma unroll
    for (int h = 0; h < HH; h++) {
      o1[(size_t)n * HH + h] = acc[h];
      o2[(size_t)n * HH + h] = acc[4 + h];
    }
  }
}

// ---------------- CSR build ----------------
__global__ __launch_bounds__(256) void hist2(
    const int* __restrict__ d1, const int* __restrict__ d2,
    int* __restrict__ c1, int* __restrict__ c2) {
  int gid = blockIdx.x * 256 + threadIdx.x;
  if (gid < EE) atomicAdd(&c1[d1[gid]], 1);
  else if (gid < 2 * EE) atomicAdd(&c2[d2[gid - EE]], 1);
}

__global__ __launch_bounds__(256) void scan_chunk(
    const int* __restrict__ c1, const int* __restrict__ c2,
    int* __restrict__ rp1, int* __restrict__ rp2, int* __restrict__ bsum) {
  int rel = blockIdx.y;
  const int* counts = rel ? c2 : c1;
  int* rowptr = rel ? rp2 : rp1;
  int* bs = bsum + rel * 128;
  __shared__ int sd[256];
  int tid = threadIdx.x;
  int base = blockIdx.x * 1024 + tid * 4;
  int c[4];
#pragma unroll
  for (int j = 0; j < 4; j++) c[j] = (base + j < NN) ? counts[base + j] : 0;
  int tot = c[0] + c[1] + c[2] + c[3];
  sd[tid] = tot; __syncthreads();
  for (int o = 1; o < 256; o <<= 1) {
    int v = (tid >= o) ? sd[tid - o] : 0;
    __syncthreads();
    sd[tid] += v;
    __syncthreads();
  }
  int excl = sd[tid] - tot;
  int run = excl;
#pragma unroll
  for (int j = 0; j < 4; j++) {
    if (base + j < NN) rowptr[base + j] = run;
    run += c[j];
  }
  if (tid == 255) bs[blockIdx.x] = sd[255];
}

__global__ __launch_bounds__(128) void scan_bsum(int* __restrict__ bsum) {
  int rel = blockIdx.y;
  int* bs = bsum + rel * 128;
  __shared__ int sd[128];
  int tid = threadIdx.x;
  int v = (tid < NB_SCAN) ? bs[tid] : 0;
  sd[tid] = v; __syncthreads();
  for (int o = 1; o < 128; o <<= 1) {
    int t = (tid >= o) ? sd[tid - o] : 0;
    __syncthreads();
    sd[tid] += t;
    __syncthreads();
  }
  bs[tid] = sd[tid] - v;
}

__global__ __launch_bounds__(256) void addoff2(
    int* __restrict__ rp1, int* __restrict__ rp2,
    int* __restrict__ cur1, int* __restrict__ cur2,
    const int* __restrict__ bsum) {
  int rel = blockIdx.y;
  int* rowptr = rel ? rp2 : rp1;
  int* cur = rel ? cur2 : cur1;
  const int* bs = bsum + rel * 128;
  int i = blockIdx.x * 256 + threadIdx.x;
  if (i < NN) {
    int r = rowptr[i] + bs[i >> 10];
    rowptr[i] = r;
    cur[i] = r;
  }
  if (i == 0) rowptr[NN] = EE;
}

// ---------------- fill CSR: src id + per-edge exp coeffs (NO denominator atomics)
__global__ __launch_bounds__(256) void fill_s(
    const int* __restrict__ e1s, const int* __restrict__ e1d,
    const int* __restrict__ e2s, const int* __restrict__ e2d,
    const float* __restrict__ el1, const float* __restrict__ er1,
    const float* __restrict__ el2, const float* __restrict__ er2,
    int* __restrict__ cur1, int* __restrict__ cur2,
    int* __restrict__ adj1, int* __restrict__ adj2,
    float* __restrict__ wexp1, float* __restrict__ wexp2) {
  int gid = blockIdx.x * 256 + threadIdx.x;
  int rel = (gid >= EE);
  if (gid >= 2 * EE) return;
  int e = rel ? gid - EE : gid;
  const int* srcp = rel ? e2s : e1s;
  const int* dstp = rel ? e2d : e1d;
  const float* el = rel ? el2 : el1;
  const float* er = rel ? er2 : er1;
  int* cur = rel ? cur2 : cur1;
  int* adj = rel ? adj2 : adj1;
  float* wexp = rel ? wexp2 : wexp1;
  int si = srcp[e], di = dstp[e];
  int p = atomicAdd(&cur[di], 1);
  adj[p] = si;
  float4 l = *(const float4*)(el + (size_t)si * HH);
  float4 r = *(const float4*)(er + (size_t)di * HH);
  float v0 = l.x + r.x, v1 = l.y + r.y, v2 = l.z + r.z, v3 = l.w + r.w;
  v0 = v0 > 0.f ? v0 : SLOPE * v0; v1 = v1 > 0.f ? v1 : SLOPE * v1;
  v2 = v2 > 0.f ? v2 : SLOPE * v2; v3 = v3 > 0.f ? v3 : SLOPE * v3;
  *(float4*)(wexp + (size_t)p * HH) =
      make_float4(__expf(v0), __expf(v1), __expf(v2), __expf(v3));
}

// ---------------- MFMA GEMM: C[M x N] = A[M x 256] @ Wt[N x 256]^T
// 1-D grid, XCD-bijective swizzle, col fastest (A L2 reuse).
// ABF=1: bf16 A; staging via global_load_lds(16B), linear LDS dest +
// inverse-swizzled per-lane global source (XOR stays within each 128B K-window).
template <int ABF>
__global__ __launch_bounds__(256) void mfma_gemm(
    const void* __restrict__ Av, const short* __restrict__ Wt,
    void* __restrict__ Cout, int ldC, int M, int write_bf, int ncol) {
  __shared__ short As[128 * 64];
  __shared__ short Bs[128 * 64];
  int nwg = gridDim.x;
  int q = nwg >> 3, r = nwg & 7;
  int xcd = blockIdx.x & 7, seq = blockIdx.x >> 3;
  int lid = (xcd < r) ? (xcd * (q + 1) + seq) : (r * (q + 1) + (xcd - r) * q + seq);
  int row0 = (lid / ncol) * 128;
  int col0 = (lid % ncol) * 128;

  int tid = threadIdx.x;
  int lane = tid & 63, wid = tid >> 6;
  int wm = wid >> 1, wn = wid & 1;

  f32x4 acc[4][4];
#pragma unroll
  for (int i = 0; i < 4; i++)
#pragma unroll
    for (int j = 0; j < 4; j++) acc[i][j] = (f32x4){0.f, 0.f, 0.f, 0.f};

  int am = tid >> 1;
  int akh = (tid & 1) * 32;
  bool arow_ok = (row0 + am) < M;

  for (int k0 = 0; k0 < KIN; k0 += 64) {
    __syncthreads();
    if (ABF) {
      int rr8 = lane >> 3;
      int bby = (lane & 7) * 16;
#pragma unroll
      for (int c2 = 0; c2 < 4; c2++) {
        int rr = wid * 32 + c2 * 8 + rr8;
        int rg = row0 + rr; if (rg > M - 1) rg = M - 1;
        int sb = bby ^ ((rr & 7) << 4);
        gload_lds16((const char*)Av + (size_t)rg * (KIN * 2) + k0 * 2 + sb,
                    (char*)As + wid * 4096 + c2 * 1024);
      }
#pragma unroll
      for (int c2 = 0; c2 < 4; c2++) {
        int rr = wid * 32 + c2 * 8 + rr8;
        int sb = bby ^ ((rr & 7) << 4);
        gload_lds16((const char*)Wt + (size_t)(col0 + rr) * (KIN * 2) + k0 * 2 + sb,
                    (char*)Bs + wid * 4096 + c2 * 1024);
      }
    } else {
      const float* xp = (const float*)Av + (size_t)(row0 + am) * KIN + k0 + akh;
#pragma unroll
      for (int c = 0; c < 4; c++) {
        float4 v0, v1;
        if (arow_ok) {
          v0 = *(const float4*)(xp + c * 8);
          v1 = *(const float4*)(xp + c * 8 + 4);
        } else {
          v0 = make_float4(0.f, 0.f, 0.f, 0.f);
          v1 = v0;
        }
        bf16x8 pk;
        pk[0] = (short)f2bf(v0.x); pk[1] = (short)f2bf(v0.y);
        pk[2] = (short)f2bf(v0.z); pk[3] = (short)f2bf(v0.w);
        pk[4] = (short)f2bf(v1.x); pk[5] = (short)f2bf(v1.y);
        pk[6] = (short)f2bf(v1.z); pk[7] = (short)f2bf(v1.w);
        int kc = akh + c * 8;
        int ad = (am * 128 + kc * 2) ^ ((am & 7) << 4);
        *(bf16x8*)((char*)As + ad) = pk;
      }
      int bn = tid >> 1;
      int bkh = (tid & 1) * 32;
      const short* wp = Wt + (size_t)(col0 + bn) * KIN + k0 + bkh;
#pragma unroll
      for (int c = 0; c < 4; c++) {
        bf16x8 pv = *(const bf16x8*)(wp + c * 8);
        int kc = bkh + c * 8;
        int bd = (bn * 128 + kc * 2) ^ ((bn & 7) << 4);
        *(bf16x8*)((char*)Bs + bd) = pv;
      }
    }
    __syncthreads();
#pragma unroll
    for (int ks = 0; ks < 2; ks++) {
      int kb = ks * 32 + (lane >> 4) * 8;
      bf16x8 af[4], bfv[4];
#pragma unroll
      for (int mf = 0; mf < 4; mf++) {
        int rr = wm * 64 + mf * 16 + (lane & 15);
        int ad = (rr * 128 + kb * 2) ^ ((rr & 7) << 4);
        af[mf] = *(bf16x8*)((char*)As + ad);
      }
#pragma unroll
      for (int nf = 0; nf < 4; nf++) {
        int cc = wn * 64 + nf * 16 + (lane & 15);
        int bd = (cc * 128 + kb * 2) ^ ((cc & 7) << 4);
        bfv[nf] = *(bf16x8*)((char*)Bs + bd);
      }
#pragma unroll
      for (int mf = 0; mf < 4; mf++)
#pragma unroll
        for (int nf = 0; nf < 4; nf++)
          acc[mf][nf] = __builtin_amdgcn_mfma_f32_16x16x32_bf16(af[mf], bfv[nf], acc[mf][nf], 0, 0, 0);
    }
  }
  int lr = lane >> 4, lc = lane & 15;
#pragma unroll
  for (int mf = 0; mf < 4; mf++) {
#pragma unroll
    for (int r4 = 0; r4 < 4; r4++) {
      int row = row0 + wm * 64 + mf * 16 + lr * 4 + r4;
      if (row < M) {
#pragma unroll
        for (int nf = 0; nf < 4; nf++) {
          int col = col0 + wn * 64 + nf * 16 + lc;
          float v = acc[mf][nf][r4];
          if (write_bf) ((unsigned short*)Cout)[(size_t)row * ldC + col] = f2bf(v);
          else ((float*)Cout)[(size_t)row * ldC + col] = v;
        }
      }
    }
  }
}

// ---------------- single-pass agg + mean + residual + LN + GELU (one wave/dst)
__global__ __launch_bounds__(256) void agg2(
    const int* __restrict__ rowptr, const int* __restrict__ adj,
    const float* __restrict__ wexp,
    const unsigned short* __restrict__ fsb,
    const float* __restrict__ bm,
    const float* __restrict__ g, const float* __restrict__ be,
    float* __restrict__ out, int M) {
  int wave = threadIdx.x >> 6, lane = threadIdx.x & 63;
  int n = blockIdx.x * 4 + wave;
  if (n >= M) return;
  int beg = rowptr[n], end = rowptr[n + 1];
  int lh = lane >> 4, lc = lane & 15;
  float sh = 0.f;
  float m[8] = {0.f, 0.f, 0.f, 0.f, 0.f, 0.f, 0.f, 0.f};
  for (int t = beg; t < end; t++) {
    int si = adj[t];
    float wh = wexp[(size_t)t * HH + lh];
    sh += wh;
    uint4 u = *(const uint4*)(fsb + (size_t)si * HD + lane * 8);
    m[0] = fmaf(wh, bf_lo(u.x), m[0]); m[1] = fmaf(wh, bf_hi(u.x), m[1]);
    m[2] = fmaf(wh, bf_lo(u.y), m[2]); m[3] = fmaf(wh, bf_hi(u.y), m[3]);
    m[4] = fmaf(wh, bf_lo(u.z), m[4]); m[5] = fmaf(wh, bf_hi(u.z), m[5]);
    m[6] = fmaf(wh, bf_lo(u.w), m[6]); m[7] = fmaf(wh, bf_hi(u.w), m[7]);
  }
  float rsh = sh > 0.f ? 0.25f / sh : 0.f;
#pragma unroll
  for (int j = 0; j < 8; j++) m[j] *= rsh;
#pragma unroll
  for (int j = 0; j < 8; j++) {
    m[j] += __shfl_xor(m[j], 16);
    m[j] += __shfl_xor(m[j], 32);
  }
  const float4* bmp = (const float4*)(bm + lc * 8);
  float4 b0 = bmp[0], b1 = bmp[1];
  const float4* orow = (const float4*)(out + (size_t)n * DD + lc * 8);
  float4 p0 = orow[0], p1 = orow[1];
  float c[8];
  c[0] = m[0] + b0.x + p0.x; c[1] = m[1] + b0.y + p0.y;
  c[2] = m[2] + b0.z + p0.z; c[3] = m[3] + b0.w + p0.w;
  c[4] = m[4] + b1.x + p1.x; c[5] = m[5] + b1.y + p1.y;
  c[6] = m[6] + b1.z + p1.z; c[7] = m[7] + b1.w + p1.w;
  float ss = c[0] + c[1] + c[2] + c[3] + c[4] + c[5] + c[6] + c[7];
  ss += __shfl_xor(ss, 1); ss += __shfl_xor(ss, 2);
  ss += __shfl_xor(ss, 4); ss += __shfl_xor(ss, 8);
  float mu = ss * (1.f / 128.f);
  float vv = 0.f;
#pragma unroll
  for (int j = 0; j < 8; j++) { float d = c[j] - mu; vv = fmaf(d, d, vv); }
  vv += __shfl_xor(vv, 1); vv += __shfl_xor(vv, 2);
  vv += __shfl_xor(vv, 4); vv += __shfl_xor(vv, 8);
  float inv = rsqrtf(vv * (1.f / 128.f) + LN_EPS);
  const float4* gp = (const float4*)(g + lc * 8);
  const float4* bep = (const float4*)(be + lc * 8);
  float4 g0 = gp[0], g1 = gp[1];
  float4 e0 = bep[0], e1 = bep[1];
  float gv[8] = {g0.x, g0.y, g0.z, g0.w, g1.x, g1.y, g1.z, g1.w};
  float ev[8] = {e0.x, e0.y, e0.z, e0.w, e1.x, e1.y, e1.z, e1.w};
  float o[8];
#pragma unroll
  for (int j = 0; j < 8; j++) {
    float y = (c[j] - mu) * inv * gv[j] + ev[j];
    o[j] = gelu_fast(y);
  }
  if (lane < 16) {
    float4* op = (float4*)(out + (size_t)n * DD + lane * 8);
    op[0] = make_float4(o[0], o[1], o[2], o[3]);
    op[1] = make_float4(o[4], o[5], o[6], o[7]);
  }
}

extern "C" void kernel_launch(void* const* d_in, const int* in_sizes, int n_in,
                              void* d_out, int out_size, void* d_ws, size_t ws_size,
                              hipStream_t stream) {
  const float* feat_host = (const float*)d_in[0];
  const float* feat_flow = (const float*)d_in[1];
  const float* W1  = (const float*)d_in[2];
  const float* al1 = (const float*)d_in[3];
  const float* ar1 = (const float*)d_in[4];
  const float* b1  = (const float*)d_in[5];
  const float* W2  = (const float*)d_in[6];
  const float* al2 = (const float*)d_in[7];
  const float* ar2 = (const float*)d_in[8];
  const float* b2  = (const float*)d_in[9];
  const float* pWh = (const float*)d_in[10];
  const float* pbh = (const float*)d_in[11];
  const float* pWf = (const float*)d_in[12];
  const float* pbf = (const float*)d_in[13];
  const float* gh  = (const float*)d_in[14];
  const float* beh = (const float*)d_in[15];
  const float* gf  = (const float*)d_in[16];
  const float* bef = (const float*)d_in[17];
  const int* e1s = (const int*)d_in[18];
  const int* e1d = (const int*)d_in[19];
  const int* e2s = (const int*)d_in[20];
  const int* e2d = (const int*)d_in[21];

  float* out = (float*)d_out;
  float* host_out = out;                       // [NN,128]
  float* flow_out = out + (size_t)NN * DD;     // [NN,128]

  float* ws = (float*)d_ws;
  size_t off = 0;
  unsigned short* fsb = (unsigned short*)(ws + off); off += (size_t)NN * 256;  // NN x 512 bf16
  short* W1t  = (short*)(ws + off); off += (512 * 256) / 2;
  short* W2t  = (short*)(ws + off); off += (512 * 256) / 2;
  short* pWht = (short*)(ws + off); off += (128 * 256) / 2;
  short* pWft = (short*)(ws + off); off += (128 * 256) / 2;
  float* el1b = ws + off; off += (size_t)NN * HH;
  float* er1b = ws + off; off += (size_t)NN * HH;
  float* el2b = ws + off; off += (size_t)NN * HH;
  float* er2b = ws + off; off += (size_t)NN * HH;
  float* Cbuf = ws + off; off += 4096;
  short* CtH  = (short*)(ws + off); off += 2048;     // 16x256 bf16
  short* CtF  = (short*)(ws + off); off += 2048;
  float* bm   = ws + off; off += 256;          // bm1 | bm2
  float* wexp1 = ws + off; off += (size_t)EE * HH;   // per-slot exp coeffs
  float* wexp2 = ws + off; off += (size_t)EE * HH;
  // CSR
  int* rp1  = (int*)(ws + off);      // NN+1
  int* rp2  = rp1 + (NN + 1);
  int* adj1 = rp2 + (NN + 1);        // EE (src ids)
  int* adj2 = adj1 + EE;
  int* bsum = adj2 + EE;             // 256
  int* cur1 = bsum + 256;            // NN } contiguous memset region (2*NN)
  int* cur2 = cur1 + NN;             // NN }
  off += (size_t)(2 * (NN + 1) + 2 * EE + 256 + 2 * NN + 4);
  // optional bf16 feature copies
  size_t base_bytes = (off + 1024) * sizeof(float);
  size_t featb_bytes = (size_t)NN * KIN * 2 * 2;
  bool use_featb = ws_size >= base_bytes + featb_bytes;
  short* fhb = nullptr;
  short* ffb = nullptr;
  if (use_featb) {
    fhb = (short*)(ws + off); off += (size_t)NN * KIN / 2;
    ffb = (short*)(ws + off); off += (size_t)NN * KIN / 2;
  }

  dim3 blk(256);
  int gx = (NN + 127) / 128;                 // 782 row tiles
  int pm_g = (NN + 63) / 64;                 // prep_mfma blocks (64 rows each)
  int sk_g = (NN + 3) / 4;
  int ag_g = (NN + 3) / 4;
  int ee2_g = (2 * EE + 255) / 256;
  int nn_g = (NN + 255) / 256;

  // ---- prep
  convw<<<512, blk, 0, stream>>>(W1, W2, pWh, pWf, W1t, W2t, pWht, pWft);
  make_c<<<dim3(1, 4), blk, 0, stream>>>(W1, al1, ar1, W2, al2, ar2, Cbuf, CtH, CtF);
  make_bm<<<1, blk, 0, stream>>>(b1, pbf, b2, pbh, bm);
  if (use_featb) {
    // fused: f32->bf16 convert + el/er skinny dots via MFMA (both matrices)
    prep_mfma<<<dim3(pm_g, 2), blk, 0, stream>>>(
        feat_host, feat_flow, CtH, CtF, fhb, ffb,
        el1b, er2b, er1b, el2b, NN);
  } else {
    skinny8<<<sk_g, blk, 0, stream>>>(feat_host, Cbuf + 0,    Cbuf + 3072, el1b, er2b, NN);
    skinny8<<<sk_g, blk, 0, stream>>>(feat_flow, Cbuf + 1024, Cbuf + 2048, er1b, el2b, NN);
  }

  // ---- CSR + per-edge coeffs (no denominator atomics)
  hipMemsetAsync(cur1, 0, (size_t)2 * NN * sizeof(int), stream);
  hist2<<<ee2_g, blk, 0, stream>>>(e1d, e2d, cur1, cur2);
  scan_chunk<<<dim3(NB_SCAN, 2), blk, 0, stream>>>(cur1, cur2, rp1, rp2, bsum);
  scan_bsum<<<dim3(1, 2), 128, 0, stream>>>(bsum);
  addoff2<<<dim3(nn_g, 2), blk, 0, stream>>>(rp1, rp2, cur1, cur2, bsum);
  fill_s<<<ee2_g, blk, 0, stream>>>(e1s, e1d, e2s, e2d, el1b, er1b, el2b, er2b,
                                    cur1, cur2, adj1, adj2, wexp1, wexp2);

  // ---- relation 1: host -> flow (dst = flow, out = flow_out)
  if (use_featb) {
    mfma_gemm<1><<<gx, blk, 0, stream>>>(ffb, pWft, flow_out, DD, NN, 0, 1);
    mfma_gemm<1><<<gx * 4, blk, 0, stream>>>(fhb, W1t, fsb, HD, NN, 1, 4);
  } else {
    mfma_gemm<0><<<gx, blk, 0, stream>>>(feat_flow, pWft, flow_out, DD, NN, 0, 1);
    mfma_gemm<0><<<gx * 4, blk, 0, stream>>>(feat_host, W1t, fsb, HD, NN, 1, 4);
  }
  agg2<<<ag_g, blk, 0, stream>>>(rp1, adj1, wexp1, fsb, bm, gf, bef, flow_out, NN);

  // ---- relation 2: flow -> host (dst = host, out = host_out)
  if (use_featb) {
    mfma_gemm<1><<<gx, blk, 0, stream>>>(fhb, pWht, host_out, DD, NN, 0, 1);
    mfma_gemm<1><<<gx * 4, blk, 0, stream>>>(ffb, W2t, fsb, HD, NN, 1, 4);
  } else {
    mfma_gemm<0><<<gx, blk, 0, stream>>>(feat_host, pWht, host_out, DD, NN, 0, 1);
    mfma_gemm<0><<<gx * 4, blk, 0, stream>>>(feat_flow, W2t, fsb, HD, NN, 1, 4);
  }
  agg2<<<ag_g, blk, 0, stream>>>(rp2, adj2, wexp2, fsb, bm + 128, gh, beh, host_out, NN);
}